// Round 5
// baseline (254.731 us; speedup 1.0000x reference)
//
#include <hip/hip_runtime.h>
#include <hip/hip_bf16.h>
#include <math.h>

#define BQ    4
#define LQ    2048
#define D_DIM 1024
#define NQ    2048
#define SMAX  1024
#define TOPK  8

typedef __attribute__((ext_vector_type(8))) short          short8;
typedef __attribute__((ext_vector_type(4))) float          f32x4;
typedef __attribute__((ext_vector_type(8))) unsigned short ushort8;
typedef __attribute__((ext_vector_type(4))) unsigned short ushort4v;

typedef __attribute__((address_space(3))) void as3_void;
typedef __attribute__((address_space(1))) void as1_void;

__device__ __forceinline__ void gload_lds16(const void* g, void* l) {
    __builtin_amdgcn_global_load_lds((const as1_void*)g, (as3_void*)l, 16, 0, 0);
}

__device__ __forceinline__ unsigned short f2bf(float f) {
    __hip_bfloat16 h = __float2bfloat16(f);
    return *reinterpret_cast<unsigned short*>(&h);
}
__device__ __forceinline__ float bf2f(unsigned short u) {
    __hip_bfloat16 h = *reinterpret_cast<__hip_bfloat16*>(&u);
    return __bfloat162float(h);
}

// ---------------------------------------------------------------------------
__global__ void k_convert_qptrs(const int* __restrict__ q_raw, int* __restrict__ q_out) {
    if (threadIdx.x == 0 && blockIdx.x == 0) {
        bool is64 = (q_raw[1] == 0);
        for (int i = 0; i <= BQ; ++i)
            q_out[i] = is64 ? q_raw[2 * i] : q_raw[i];
    }
}

__global__ __launch_bounds__(256) void k_cvt_bf16(
    const float* __restrict__ in, unsigned short* __restrict__ out, int n)
{
    int i = (blockIdx.x * 256 + threadIdx.x) * 8;
    if (i >= n) return;
    float4 v0 = *reinterpret_cast<const float4*>(in + i);
    float4 v1 = *reinterpret_cast<const float4*>(in + i + 4);
    ushort8 u;
    u[0] = f2bf(v0.x); u[1] = f2bf(v0.y); u[2] = f2bf(v0.z); u[3] = f2bf(v0.w);
    u[4] = f2bf(v1.x); u[5] = f2bf(v1.y); u[6] = f2bf(v1.z); u[7] = f2bf(v1.w);
    *reinterpret_cast<ushort8*>(out + i) = u;
}

__global__ __launch_bounds__(256) void k_cvt_split(
    const float* __restrict__ in, unsigned short* __restrict__ hi,
    unsigned short* __restrict__ lo, int n)
{
    int i = (blockIdx.x * 256 + threadIdx.x) * 8;
    if (i >= n) return;
    float4 v0 = *reinterpret_cast<const float4*>(in + i);
    float4 v1 = *reinterpret_cast<const float4*>(in + i + 4);
    float x[8] = {v0.x, v0.y, v0.z, v0.w, v1.x, v1.y, v1.z, v1.w};
    ushort8 h8, l8;
#pragma unroll
    for (int k = 0; k < 8; ++k) {
        unsigned short h = f2bf(x[k]);
        h8[k] = h;
        l8[k] = f2bf(x[k] - bf2f(h));
    }
    *reinterpret_cast<ushort8*>(hi + i) = h8;
    *reinterpret_cast<ushort8*>(lo + i) = l8;
}

// ---------------------------------------------------------------------------
// Split-bf16 GEMM (3-MFMA fp32 emulation), BM=128 x BN=64, BK=32,
// DOUBLE-BUFFERED: stage(t+1) issued before compute(t); single barrier/iter
// drains the prefetch after ~compute-length instead of before it.
// LDS per buf: AsH 8K | AsL 8K | BsH 4K | BsL 4K = 24 KB; x2 = 48 KB.
__global__ __launch_bounds__(256) void k_gemm_split(
    const unsigned short* __restrict__ Ah, const unsigned short* __restrict__ Al,
    const unsigned short* __restrict__ Wh, const unsigned short* __restrict__ Wl,
    const float* __restrict__ bias,
    unsigned short* __restrict__ Ch, unsigned short* __restrict__ Cl,
    int M, int N, int K)
{
    __shared__ __align__(16) char lds[2 * 24576];

    const int tid = threadIdx.x;
    const int ln  = tid & 63;
    const int wid = tid >> 6;
    const int fr  = ln & 15, fs = ln >> 4;
    const int brow = blockIdx.y * 128;
    const int bcol = blockIdx.x * 64;
    const int srow = tid >> 2;       // staging row 0..63
    const int sslt = tid & 3;        // staging 16B slot

    f32x4 acc[2][4] = {};

    auto stage = [&](int buf, int k0) {
        char* base = lds + buf * 24576;
#pragma unroll
        for (int i = 0; i < 2; ++i) {
            int r  = i * 64 + srow;
            int kk = (sslt ^ (r & 3)) << 3;
            size_t offA = (size_t)(brow + r) * K + k0 + kk;
            gload_lds16(Ah + offA, base + i * 4096 + wid * 1024);
            gload_lds16(Al + offA, base + 8192 + i * 4096 + wid * 1024);
        }
        int kkb = (sslt ^ (srow & 3)) << 3;
        size_t offW = (size_t)(bcol + srow) * K + k0 + kkb;
        gload_lds16(Wh + offW, base + 16384 + wid * 1024);
        gload_lds16(Wl + offW, base + 20480 + wid * 1024);
    };

    stage(0, 0);
    __syncthreads();

    const int NT = K / 32;
    for (int t = 0; t < NT; ++t) {
        int cur = t & 1;
        if (t + 1 < NT) stage(cur ^ 1, (t + 1) * 32);

        const char* base = lds + cur * 24576;
        short8 ah[2], al[2], bh[4], bl[4];
#pragma unroll
        for (int mi = 0; mi < 2; ++mi) {
            int r = wid * 32 + mi * 16 + fr;
            int o = r * 64 + ((fs ^ (r & 3)) << 4);
            ah[mi] = *reinterpret_cast<const short8*>(base + o);
            al[mi] = *reinterpret_cast<const short8*>(base + 8192 + o);
        }
#pragma unroll
        for (int ni = 0; ni < 4; ++ni) {
            int c = ni * 16 + fr;
            int o = c * 64 + ((fs ^ (c & 3)) << 4);
            bh[ni] = *reinterpret_cast<const short8*>(base + 16384 + o);
            bl[ni] = *reinterpret_cast<const short8*>(base + 20480 + o);
        }
#pragma unroll
        for (int mi = 0; mi < 2; ++mi)
#pragma unroll
            for (int ni = 0; ni < 4; ++ni)
                acc[mi][ni] = __builtin_amdgcn_mfma_f32_16x16x32_bf16(
                    ah[mi], bh[ni], acc[mi][ni], 0, 0, 0);
#pragma unroll
        for (int mi = 0; mi < 2; ++mi)
#pragma unroll
            for (int ni = 0; ni < 4; ++ni)
                acc[mi][ni] = __builtin_amdgcn_mfma_f32_16x16x32_bf16(
                    ah[mi], bl[ni], acc[mi][ni], 0, 0, 0);
#pragma unroll
        for (int mi = 0; mi < 2; ++mi)
#pragma unroll
            for (int ni = 0; ni < 4; ++ni)
                acc[mi][ni] = __builtin_amdgcn_mfma_f32_16x16x32_bf16(
                    al[mi], bh[ni], acc[mi][ni], 0, 0, 0);
        __syncthreads();
    }

    float bv[4];
#pragma unroll
    for (int ni = 0; ni < 4; ++ni)
        bv[ni] = bias ? bias[bcol + ni * 16 + fr] : 0.f;

#pragma unroll
    for (int mi = 0; mi < 2; ++mi) {
#pragma unroll
        for (int reg = 0; reg < 4; ++reg) {
            int row = brow + wid * 32 + mi * 16 + fs * 4 + reg;
#pragma unroll
            for (int ni = 0; ni < 4; ++ni) {
                int col = bcol + ni * 16 + fr;
                float v = acc[mi][ni][reg] + bv[ni];
                unsigned short h = f2bf(v);
                Ch[(size_t)row * N + col] = h;
                Cl[(size_t)row * N + col] = f2bf(v - bf2f(h));
            }
        }
    }
}

// ---------------------------------------------------------------------------
// Windowed split-bf16 logits, BM=64 x BN=64, double-buffered.
// ~1024 active blocks (4/CU). LDS per buf: 4 planes x 4 KB = 16 KB; x2 = 32 KB.
__global__ __launch_bounds__(256) void k_logits_split(
    const unsigned short* __restrict__ Th, const unsigned short* __restrict__ Tl,
    const unsigned short* __restrict__ Dh, const unsigned short* __restrict__ Dl,
    const int* __restrict__ qp, float* __restrict__ logits)
{
    const int b = blockIdx.z;
    const int start = qp[b], len = qp[b + 1] - start;
    const int bcol = blockIdx.x * 64;
    if (bcol >= len) return;
    const int brow = blockIdx.y * 64;

    __shared__ __align__(16) char lds[2 * 16384];

    const int tid = threadIdx.x;
    const int ln  = tid & 63;
    const int wid = tid >> 6;
    const int fr  = ln & 15, fs = ln >> 4;
    const int srow = tid >> 2;
    const int sslt = tid & 3;

    const size_t abase = (size_t)b * LQ + brow;

    f32x4 acc[4] = {};

    auto stage = [&](int buf, int k0) {
        char* base = lds + buf * 16384;
        int kka = (sslt ^ (srow & 3)) << 3;
        size_t offA = (abase + srow) * D_DIM + k0 + kka;
        gload_lds16(Th + offA, base + wid * 1024);
        gload_lds16(Tl + offA, base + 4096 + wid * 1024);
        int wr = start + bcol + srow; if (wr > NQ - 1) wr = NQ - 1;
        size_t offW = (size_t)wr * D_DIM + k0 + kka;
        gload_lds16(Dh + offW, base + 8192 + wid * 1024);
        gload_lds16(Dl + offW, base + 12288 + wid * 1024);
    };

    stage(0, 0);
    __syncthreads();

    const int NT = D_DIM / 32;
    for (int t = 0; t < NT; ++t) {
        int cur = t & 1;
        if (t + 1 < NT) stage(cur ^ 1, (t + 1) * 32);

        const char* base = lds + cur * 16384;
        short8 ah, al, bh[4], bl[4];
        {
            int r = wid * 16 + fr;
            int o = r * 64 + ((fs ^ (r & 3)) << 4);
            ah = *reinterpret_cast<const short8*>(base + o);
            al = *reinterpret_cast<const short8*>(base + 4096 + o);
        }
#pragma unroll
        for (int ni = 0; ni < 4; ++ni) {
            int c = ni * 16 + fr;
            int o = c * 64 + ((fs ^ (c & 3)) << 4);
            bh[ni] = *reinterpret_cast<const short8*>(base + 8192 + o);
            bl[ni] = *reinterpret_cast<const short8*>(base + 12288 + o);
        }
#pragma unroll
        for (int ni = 0; ni < 4; ++ni)
            acc[ni] = __builtin_amdgcn_mfma_f32_16x16x32_bf16(ah, bh[ni], acc[ni], 0, 0, 0);
#pragma unroll
        for (int ni = 0; ni < 4; ++ni)
            acc[ni] = __builtin_amdgcn_mfma_f32_16x16x32_bf16(ah, bl[ni], acc[ni], 0, 0, 0);
#pragma unroll
        for (int ni = 0; ni < 4; ++ni)
            acc[ni] = __builtin_amdgcn_mfma_f32_16x16x32_bf16(al, bh[ni], acc[ni], 0, 0, 0);
        __syncthreads();
    }

#pragma unroll
    for (int reg = 0; reg < 4; ++reg) {
        size_t row = (size_t)b * LQ + brow + wid * 16 + fs * 4 + reg;
#pragma unroll
        for (int ni = 0; ni < 4; ++ni) {
            int col = bcol + ni * 16 + fr;
            logits[row * SMAX + col] = acc[ni][reg];
        }
    }
}

// ---------------------------------------------------------------------------
// Plain bf16 GEMM, fp32 out, BM=128 x BN=64, double-buffered.
// LDS per buf: As 8K | Bs 4K = 12 KB; x2 = 24 KB.
__global__ __launch_bounds__(256) void k_gemm_bf16_f32out(
    const unsigned short* __restrict__ A, const unsigned short* __restrict__ W,
    const float* __restrict__ bias, float* __restrict__ C,
    int M, int N, int K)
{
    __shared__ __align__(16) char lds[2 * 12288];

    const int tid = threadIdx.x;
    const int ln  = tid & 63;
    const int wid = tid >> 6;
    const int fr  = ln & 15, fs = ln >> 4;
    const int brow = blockIdx.y * 128;
    const int bcol = blockIdx.x * 64;
    const int srow = tid >> 2;
    const int sslt = tid & 3;

    f32x4 acc[2][4] = {};

    auto stage = [&](int buf, int k0) {
        char* base = lds + buf * 12288;
#pragma unroll
        for (int i = 0; i < 2; ++i) {
            int r  = i * 64 + srow;
            int kk = (sslt ^ (r & 3)) << 3;
            gload_lds16(A + (size_t)(brow + r) * K + k0 + kk,
                        base + i * 4096 + wid * 1024);
        }
        int kkb = (sslt ^ (srow & 3)) << 3;
        gload_lds16(W + (size_t)(bcol + srow) * K + k0 + kkb,
                    base + 8192 + wid * 1024);
    };

    stage(0, 0);
    __syncthreads();

    const int NT = K / 32;
    for (int t = 0; t < NT; ++t) {
        int cur = t & 1;
        if (t + 1 < NT) stage(cur ^ 1, (t + 1) * 32);

        const char* base = lds + cur * 12288;
        short8 a[2], bfr[4];
#pragma unroll
        for (int mi = 0; mi < 2; ++mi) {
            int r = wid * 32 + mi * 16 + fr;
            a[mi] = *reinterpret_cast<const short8*>(base + r * 64 + ((fs ^ (r & 3)) << 4));
        }
#pragma unroll
        for (int ni = 0; ni < 4; ++ni) {
            int c = ni * 16 + fr;
            bfr[ni] = *reinterpret_cast<const short8*>(base + 8192 + c * 64 + ((fs ^ (c & 3)) << 4));
        }
#pragma unroll
        for (int mi = 0; mi < 2; ++mi)
#pragma unroll
            for (int ni = 0; ni < 4; ++ni)
                acc[mi][ni] = __builtin_amdgcn_mfma_f32_16x16x32_bf16(
                    a[mi], bfr[ni], acc[mi][ni], 0, 0, 0);
        __syncthreads();
    }

    float bv[4];
#pragma unroll
    for (int ni = 0; ni < 4; ++ni)
        bv[ni] = bias ? bias[bcol + ni * 16 + fr] : 0.f;

#pragma unroll
    for (int mi = 0; mi < 2; ++mi) {
#pragma unroll
        for (int reg = 0; reg < 4; ++reg) {
            int row = brow + wid * 32 + mi * 16 + fs * 4 + reg;
#pragma unroll
            for (int ni = 0; ni < 4; ++ni) {
                int col = bcol + ni * 16 + fr;
                C[(size_t)row * N + col] = acc[mi][ni][reg] + bv[ni];
            }
        }
    }
}

// ---------------------------------------------------------------------------
// Wave-per-row top-8 + softmax + mix. No barriers, no LDS.
__global__ __launch_bounds__(256) void k_topk_mix_wave(
    const float* __restrict__ logits, const float* __restrict__ Z,
    const int* __restrict__ qp, unsigned short* __restrict__ mix)
{
    const int ln  = threadIdx.x & 63;
    const int row = blockIdx.x * 4 + (threadIdx.x >> 6);   // (b*L + l)
    const int b   = row >> 11;                              // L = 2048
    const int start = qp[b], len = qp[b + 1] - start;

    const float* lrow = logits + (size_t)row * SMAX;

    float v[16];
#pragma unroll
    for (int c = 0; c < 4; ++c) {
        float4 q = reinterpret_cast<const float4*>(lrow)[c * 64 + ln];
        int s0 = c * 256 + ln * 4;
        v[c * 4 + 0] = (s0 + 0 < len) ? q.x : -INFINITY;
        v[c * 4 + 1] = (s0 + 1 < len) ? q.y : -INFINITY;
        v[c * 4 + 2] = (s0 + 2 < len) ? q.z : -INFINITY;
        v[c * 4 + 3] = (s0 + 3 < len) ? q.w : -INFINITY;
    }

    float wv[TOPK]; int wi[TOPK];
#pragma unroll
    for (int it = 0; it < TOPK; ++it) {
        float bvv = v[0]; int bj = 0;
#pragma unroll
        for (int j = 1; j < 16; ++j)
            if (v[j] > bvv) { bvv = v[j]; bj = j; }
        int gidx = (bj >> 2) * 256 + ln * 4 + (bj & 3);
        float cv = bvv; int ci = gidx;
#pragma unroll
        for (int off = 32; off > 0; off >>= 1) {
            float ov = __shfl_xor(cv, off);
            int   oi = __shfl_xor(ci, off);
            if (ov > cv || (ov == cv && oi < ci)) { cv = ov; ci = oi; }
        }
        wv[it] = cv; wi[it] = ci;
#pragma unroll
        for (int j = 0; j < 16; ++j) {
            int sj = (j >> 2) * 256 + ln * 4 + (j & 3);
            if (sj == ci) v[j] = -INFINITY;
        }
    }

    float m = wv[0], denom = 0.f;
    float g[TOPK];
#pragma unroll
    for (int k = 0; k < TOPK; ++k) { g[k] = expf(wv[k] - m); denom += g[k]; }
    float inv = 1.f / denom;

    float4 acc[4] = {{0,0,0,0},{0,0,0,0},{0,0,0,0},{0,0,0,0}};
#pragma unroll
    for (int k = 0; k < TOPK; ++k) {
        int si = wi[k] >= 0 ? wi[k] : 0;
        const float4* zr = reinterpret_cast<const float4*>(Z + (size_t)(start + si) * D_DIM);
        float wgt = g[k] * inv;
#pragma unroll
        for (int c = 0; c < 4; ++c) {
            float4 z = zr[c * 64 + ln];
            acc[c].x = fmaf(wgt, z.x, acc[c].x);
            acc[c].y = fmaf(wgt, z.y, acc[c].y);
            acc[c].z = fmaf(wgt, z.z, acc[c].z);
            acc[c].w = fmaf(wgt, z.w, acc[c].w);
        }
    }
    unsigned short* mrow = mix + (size_t)row * D_DIM;
#pragma unroll
    for (int c = 0; c < 4; ++c) {
        ushort4v o;
        o[0] = f2bf(acc[c].x); o[1] = f2bf(acc[c].y);
        o[2] = f2bf(acc[c].z); o[3] = f2bf(acc[c].w);
        *reinterpret_cast<ushort4v*>(mrow + (c * 64 + ln) * 4) = o;
    }
}

// ---------------------------------------------------------------------------
extern "C" void kernel_launch(void* const* d_in, const int* in_sizes, int n_in,
                              void* d_out, int out_size, void* d_ws, size_t ws_size,
                              hipStream_t stream) {
    const float* token_states = (const float*)d_in[0];
    const float* Z_sets       = (const float*)d_in[1];
    const float* desc_q       = (const float*)d_in[2];
    const int*   q_raw        = (const int*)d_in[3];
    const float* Wg_w  = (const float*)d_in[4];
    const float* Wg_b  = (const float*)d_in[5];
    const float* Wd_w  = (const float*)d_in[6];
    const float* Wd_b  = (const float*)d_in[7];
    const float* out_w = (const float*)d_in[8];
    const float* out_b = (const float*)d_in[9];
    float* out = (float*)d_out;

    const size_t NTOK = (size_t)BQ * LQ * D_DIM;
    const size_t NDES = (size_t)NQ * D_DIM;
    const size_t NW   = (size_t)D_DIM * D_DIM;

    char* ws = (char*)d_ws;
    int* qp = (int*)ws;
    unsigned short* tokenH = (unsigned short*)(ws + 256);
    unsigned short* tokenL = tokenH + NTOK;
    unsigned short* descH  = tokenL + NTOK;
    unsigned short* descL  = descH + NDES;
    unsigned short* wgH    = descL + NDES;
    unsigned short* wgL    = wgH + NW;
    unsigned short* wdH    = wgL + NW;
    unsigned short* wdL    = wdH + NW;
    unsigned short* owb    = wdL + NW;
    unsigned short* TprojH = owb + NW;
    unsigned short* TprojL = TprojH + NTOK;
    unsigned short* DprojH = TprojL + NTOK;
    unsigned short* DprojL = DprojH + NDES;
    float* logit          = (float*)tokenH;   // alias: token planes dead after Tproj GEMM
    unsigned short* mixb  = TprojH;           // alias: TprojH dead after logits GEMM

    k_convert_qptrs<<<1, 64, 0, stream>>>(q_raw, qp);

    k_cvt_split<<<NTOK / 2048, 256, 0, stream>>>(token_states, tokenH, tokenL, (int)NTOK);
    k_cvt_split<<<NDES / 2048, 256, 0, stream>>>(desc_q, descH, descL, (int)NDES);
    k_cvt_split<<<NW / 2048, 256, 0, stream>>>(Wg_w, wgH, wgL, (int)NW);
    k_cvt_split<<<NW / 2048, 256, 0, stream>>>(Wd_w, wdH, wdL, (int)NW);
    k_cvt_bf16<<<NW / 2048, 256, 0, stream>>>(out_w, owb, (int)NW);

    // Tproj = token @ Wg^T + b  (split out): grid (1024/64, 8192/128) = (16, 64)
    k_gemm_split<<<dim3(D_DIM / 64, (BQ * LQ) / 128), 256, 0, stream>>>(
        tokenH, tokenL, wgH, wgL, Wg_b, TprojH, TprojL, BQ * LQ, D_DIM, D_DIM);

    // Dproj = desc @ Wd^T + b  (split out): grid (16, 16)
    k_gemm_split<<<dim3(D_DIM / 64, NQ / 128), 256, 0, stream>>>(
        descH, descL, wdH, wdL, Wd_b, DprojH, DprojL, NQ, D_DIM, D_DIM);

    // logits (fp32, windowed): grid (16, 32, 4), ~1024 active blocks
    k_logits_split<<<dim3(SMAX / 64, LQ / 64, BQ), 256, 0, stream>>>(
        TprojH, TprojL, DprojH, DprojL, qp, logit);

    // top-8 + softmax + Z mix (bf16)
    k_topk_mix_wave<<<(BQ * LQ) / 4, 256, 0, stream>>>(logit, Z_sets, qp, mixb);

    // out = mix @ out_w^T + b (fp32): grid (16, 64)
    k_gemm_bf16_f32out<<<dim3(D_DIM / 64, (BQ * LQ) / 128), 256, 0, stream>>>(
        mixb, owb, out_b, out, BQ * LQ, D_DIM, D_DIM);
}

// Round 6
// 225.572 us; speedup vs baseline: 1.1293x; 1.1293x over previous
//
#include <hip/hip_runtime.h>
#include <hip/hip_bf16.h>
#include <math.h>

#define BQ    4
#define LQ    2048
#define D_DIM 1024
#define NQ    2048
#define SMAX  1024
#define TOPK  8

typedef __attribute__((ext_vector_type(8))) short          short8;
typedef __attribute__((ext_vector_type(4))) float          f32x4;
typedef __attribute__((ext_vector_type(8))) unsigned short ushort8;
typedef __attribute__((ext_vector_type(4))) unsigned short ushort4v;

typedef __attribute__((address_space(3))) void as3_void;
typedef __attribute__((address_space(1))) void as1_void;

__device__ __forceinline__ void gload_lds16(const void* g, void* l) {
    __builtin_amdgcn_global_load_lds((const as1_void*)g, (as3_void*)l, 16, 0, 0);
}

__device__ __forceinline__ unsigned short f2bf(float f) {
    __hip_bfloat16 h = __float2bfloat16(f);
    return *reinterpret_cast<unsigned short*>(&h);
}
__device__ __forceinline__ float bf2f(unsigned short u) {
    __hip_bfloat16 h = *reinterpret_cast<__hip_bfloat16*>(&u);
    return __bfloat162float(h);
}

// Counted waits (T4): vmcnt stays >0 in the main loop so prefetch loads
// span barriers. "memory" clobber pins LDS reads/writes on each side.
#define WAIT_VM0   asm volatile("s_waitcnt vmcnt(0)" ::: "memory")
#define WAIT_VM3   asm volatile("s_waitcnt vmcnt(3)" ::: "memory")
#define WAIT_VM4   asm volatile("s_waitcnt vmcnt(4)" ::: "memory")
#define WAIT_VM6   asm volatile("s_waitcnt vmcnt(6)" ::: "memory")
#define WAIT_LGKM0 asm volatile("s_waitcnt lgkmcnt(0)" ::: "memory")

// ---------------------------------------------------------------------------
__global__ void k_convert_qptrs(const int* __restrict__ q_raw, int* __restrict__ q_out) {
    if (threadIdx.x == 0 && blockIdx.x == 0) {
        bool is64 = (q_raw[1] == 0);
        for (int i = 0; i <= BQ; ++i)
            q_out[i] = is64 ? q_raw[2 * i] : q_raw[i];
    }
}

__global__ __launch_bounds__(256) void k_cvt_bf16(
    const float* __restrict__ in, unsigned short* __restrict__ out, int n)
{
    int i = (blockIdx.x * 256 + threadIdx.x) * 8;
    if (i >= n) return;
    float4 v0 = *reinterpret_cast<const float4*>(in + i);
    float4 v1 = *reinterpret_cast<const float4*>(in + i + 4);
    ushort8 u;
    u[0] = f2bf(v0.x); u[1] = f2bf(v0.y); u[2] = f2bf(v0.z); u[3] = f2bf(v0.w);
    u[4] = f2bf(v1.x); u[5] = f2bf(v1.y); u[6] = f2bf(v1.z); u[7] = f2bf(v1.w);
    *reinterpret_cast<ushort8*>(out + i) = u;
}

__global__ __launch_bounds__(256) void k_cvt_split(
    const float* __restrict__ in, unsigned short* __restrict__ hi,
    unsigned short* __restrict__ lo, int n)
{
    int i = (blockIdx.x * 256 + threadIdx.x) * 8;
    if (i >= n) return;
    float4 v0 = *reinterpret_cast<const float4*>(in + i);
    float4 v1 = *reinterpret_cast<const float4*>(in + i + 4);
    float x[8] = {v0.x, v0.y, v0.z, v0.w, v1.x, v1.y, v1.z, v1.w};
    ushort8 h8, l8;
#pragma unroll
    for (int k = 0; k < 8; ++k) {
        unsigned short h = f2bf(x[k]);
        h8[k] = h;
        l8[k] = f2bf(x[k] - bf2f(h));
    }
    *reinterpret_cast<ushort8*>(hi + i) = h8;
    *reinterpret_cast<ushort8*>(lo + i) = l8;
}

// ---------------------------------------------------------------------------
// Split-bf16 GEMM, BM=128 x BN=64, BK=32, counted-vmcnt 2-deep pipeline.
// LDS/buf: Ah 8K | Al 8K | Wh 4K | Wl 4K = 24 KB; x2 = 48 KB. L=6 loads/stage.
__global__ __launch_bounds__(256) void k_gemm_split(
    const unsigned short* __restrict__ Ah, const unsigned short* __restrict__ Al,
    const unsigned short* __restrict__ Wh, const unsigned short* __restrict__ Wl,
    const float* __restrict__ bias,
    unsigned short* __restrict__ Ch, unsigned short* __restrict__ Cl,
    int M, int N, int K)
{
    __shared__ __align__(16) char lds[2 * 24576];

    // XCD-chunked bijective swizzle (nbx == 16 at all call sites; total % 8 == 0)
    const int total = gridDim.x * gridDim.y;
    const int d = blockIdx.x + gridDim.x * blockIdx.y;
    const int logical = (d & 7) * (total >> 3) + (d >> 3);
    const int bcol = (logical & 15) * 64;
    const int brow = (logical >> 4) * 128;

    const int tid = threadIdx.x;
    const int ln  = tid & 63;
    const int wid = tid >> 6;
    const int fr  = ln & 15, fs = ln >> 4;
    const int srow = tid >> 2;       // 0..63
    const int sslt = tid & 3;

    const int kk0 = (sslt ^ (srow & 3)) << 3;
    const size_t offA0 = (size_t)(brow + srow) * K + kk0;     // +64*K for rows 64..127
    const size_t offW0 = (size_t)(bcol + srow) * K + kk0;

    auto stage = [&](char* base, int k0) {
        gload_lds16(Ah + offA0 + k0,          base + wid * 1024);
        gload_lds16(Ah + offA0 + 64 * K + k0, base + 4096 + wid * 1024);
        gload_lds16(Al + offA0 + k0,          base + 8192 + wid * 1024);
        gload_lds16(Al + offA0 + 64 * K + k0, base + 12288 + wid * 1024);
        gload_lds16(Wh + offW0 + k0,          base + 16384 + wid * 1024);
        gload_lds16(Wl + offW0 + k0,          base + 20480 + wid * 1024);
    };

    f32x4 acc[2][4] = {};

    stage(lds, 0);
    stage(lds + 24576, 32);

    const int NT = K / 32;
    for (int t = 0; t < NT; ++t) {
        if (t < NT - 1) { WAIT_VM6; } else { WAIT_VM0; }
        __builtin_amdgcn_s_barrier();

        char* base = lds + (t & 1) * 24576;
        short8 ahf[2], alf[2], bhf[4], blf[4];
#pragma unroll
        for (int mi = 0; mi < 2; ++mi) {
            int r = wid * 32 + mi * 16 + fr;
            int o = r * 64 + ((fs ^ (r & 3)) << 4);
            ahf[mi] = *reinterpret_cast<const short8*>(base + o);
            alf[mi] = *reinterpret_cast<const short8*>(base + 8192 + o);
        }
#pragma unroll
        for (int ni = 0; ni < 4; ++ni) {
            int c = ni * 16 + fr;
            int o = c * 64 + ((fs ^ (c & 3)) << 4);
            bhf[ni] = *reinterpret_cast<const short8*>(base + 16384 + o);
            blf[ni] = *reinterpret_cast<const short8*>(base + 20480 + o);
        }
#pragma unroll
        for (int mi = 0; mi < 2; ++mi)
#pragma unroll
            for (int ni = 0; ni < 4; ++ni)
                acc[mi][ni] = __builtin_amdgcn_mfma_f32_16x16x32_bf16(
                    ahf[mi], bhf[ni], acc[mi][ni], 0, 0, 0);
#pragma unroll
        for (int mi = 0; mi < 2; ++mi)
#pragma unroll
            for (int ni = 0; ni < 4; ++ni)
                acc[mi][ni] = __builtin_amdgcn_mfma_f32_16x16x32_bf16(
                    ahf[mi], blf[ni], acc[mi][ni], 0, 0, 0);
#pragma unroll
        for (int mi = 0; mi < 2; ++mi)
#pragma unroll
            for (int ni = 0; ni < 4; ++ni)
                acc[mi][ni] = __builtin_amdgcn_mfma_f32_16x16x32_bf16(
                    alf[mi], bhf[ni], acc[mi][ni], 0, 0, 0);

        WAIT_LGKM0;
        __builtin_amdgcn_s_barrier();
        if (t + 2 < NT) stage(base, (t + 2) * 32);
    }

    float bv[4];
#pragma unroll
    for (int ni = 0; ni < 4; ++ni)
        bv[ni] = bias ? bias[bcol + ni * 16 + fr] : 0.f;

#pragma unroll
    for (int mi = 0; mi < 2; ++mi) {
#pragma unroll
        for (int reg = 0; reg < 4; ++reg) {
            int row = brow + wid * 32 + mi * 16 + fs * 4 + reg;
#pragma unroll
            for (int ni = 0; ni < 4; ++ni) {
                int col = bcol + ni * 16 + fr;
                float v = acc[mi][ni][reg] + bv[ni];
                unsigned short h = f2bf(v);
                Ch[(size_t)row * N + col] = h;
                Cl[(size_t)row * N + col] = f2bf(v - bf2f(h));
            }
        }
    }
}

// ---------------------------------------------------------------------------
// Windowed split-bf16 logits, BM=64 x BN=64, counted-vmcnt pipeline, L=4.
// LDS/buf: 4 planes x 4 KB = 16 KB; x2 = 32 KB.
__global__ __launch_bounds__(256) void k_logits_split(
    const unsigned short* __restrict__ Th, const unsigned short* __restrict__ Tl,
    const unsigned short* __restrict__ Dh, const unsigned short* __restrict__ Dl,
    const int* __restrict__ qp, float* __restrict__ logits)
{
    // XCD-chunked swizzle over fixed grid (16, 32, 4) = 2048 blocks
    const int d = blockIdx.x + 16 * (blockIdx.y + 32 * blockIdx.z);
    const int logical = (d & 7) * 256 + (d >> 3);
    const int b    = logical >> 9;
    const int brow = ((logical >> 4) & 31) * 64;
    const int bcol = (logical & 15) * 64;

    const int start = qp[b], len = qp[b + 1] - start;
    if (bcol >= len) return;            // block-uniform: barrier-safe

    __shared__ __align__(16) char lds[2 * 16384];

    const int tid = threadIdx.x;
    const int ln  = tid & 63;
    const int wid = tid >> 6;
    const int fr  = ln & 15, fs = ln >> 4;
    const int srow = tid >> 2;
    const int sslt = tid & 3;

    const int kka = (sslt ^ (srow & 3)) << 3;
    const size_t offA0 = ((size_t)b * LQ + brow + srow) * D_DIM + kka;
    int wr = start + bcol + srow; if (wr > NQ - 1) wr = NQ - 1;
    const size_t offW0 = (size_t)wr * D_DIM + kka;

    auto stage = [&](char* base, int k0) {
        gload_lds16(Th + offA0 + k0, base + wid * 1024);
        gload_lds16(Tl + offA0 + k0, base + 4096 + wid * 1024);
        gload_lds16(Dh + offW0 + k0, base + 8192 + wid * 1024);
        gload_lds16(Dl + offW0 + k0, base + 12288 + wid * 1024);
    };

    f32x4 acc[4] = {};

    stage(lds, 0);
    stage(lds + 16384, 32);

    const int NT = D_DIM / 32;   // 32
    for (int t = 0; t < NT; ++t) {
        if (t < NT - 1) { WAIT_VM4; } else { WAIT_VM0; }
        __builtin_amdgcn_s_barrier();

        char* base = lds + (t & 1) * 16384;
        short8 ah, al, bh[4], bl[4];
        {
            int r = wid * 16 + fr;
            int o = r * 64 + ((fs ^ (r & 3)) << 4);
            ah = *reinterpret_cast<const short8*>(base + o);
            al = *reinterpret_cast<const short8*>(base + 4096 + o);
        }
#pragma unroll
        for (int ni = 0; ni < 4; ++ni) {
            int c = ni * 16 + fr;
            int o = c * 64 + ((fs ^ (c & 3)) << 4);
            bh[ni] = *reinterpret_cast<const short8*>(base + 8192 + o);
            bl[ni] = *reinterpret_cast<const short8*>(base + 12288 + o);
        }
#pragma unroll
        for (int ni = 0; ni < 4; ++ni)
            acc[ni] = __builtin_amdgcn_mfma_f32_16x16x32_bf16(ah, bh[ni], acc[ni], 0, 0, 0);
#pragma unroll
        for (int ni = 0; ni < 4; ++ni)
            acc[ni] = __builtin_amdgcn_mfma_f32_16x16x32_bf16(ah, bl[ni], acc[ni], 0, 0, 0);
#pragma unroll
        for (int ni = 0; ni < 4; ++ni)
            acc[ni] = __builtin_amdgcn_mfma_f32_16x16x32_bf16(al, bh[ni], acc[ni], 0, 0, 0);

        WAIT_LGKM0;
        __builtin_amdgcn_s_barrier();
        if (t + 2 < NT) stage(base, (t + 2) * 32);
    }

#pragma unroll
    for (int reg = 0; reg < 4; ++reg) {
        size_t row = (size_t)b * LQ + brow + wid * 16 + fs * 4 + reg;
#pragma unroll
        for (int ni = 0; ni < 4; ++ni) {
            int col = bcol + ni * 16 + fr;
            logits[row * SMAX + col] = acc[ni][reg];
        }
    }
}

// ---------------------------------------------------------------------------
// Plain bf16 GEMM, fp32 out, BM=128 x BN=64, counted-vmcnt pipeline, L=3.
// LDS/buf: As 8K | Bs 4K = 12 KB; x2 = 24 KB.
__global__ __launch_bounds__(256) void k_gemm_bf16_f32out(
    const unsigned short* __restrict__ A, const unsigned short* __restrict__ W,
    const float* __restrict__ bias, float* __restrict__ C,
    int M, int N, int K)
{
    __shared__ __align__(16) char lds[2 * 12288];

    const int total = gridDim.x * gridDim.y;
    const int d = blockIdx.x + gridDim.x * blockIdx.y;
    const int logical = (d & 7) * (total >> 3) + (d >> 3);
    const int bcol = (logical & 15) * 64;
    const int brow = (logical >> 4) * 128;

    const int tid = threadIdx.x;
    const int ln  = tid & 63;
    const int wid = tid >> 6;
    const int fr  = ln & 15, fs = ln >> 4;
    const int srow = tid >> 2;
    const int sslt = tid & 3;

    const int kk0 = (sslt ^ (srow & 3)) << 3;
    const size_t offA0 = (size_t)(brow + srow) * K + kk0;
    const size_t offW0 = (size_t)(bcol + srow) * K + kk0;

    auto stage = [&](char* base, int k0) {
        gload_lds16(A + offA0 + k0,          base + wid * 1024);
        gload_lds16(A + offA0 + 64 * K + k0, base + 4096 + wid * 1024);
        gload_lds16(W + offW0 + k0,          base + 8192 + wid * 1024);
    };

    f32x4 acc[2][4] = {};

    stage(lds, 0);
    stage(lds + 12288, 32);

    const int NT = K / 32;
    for (int t = 0; t < NT; ++t) {
        if (t < NT - 1) { WAIT_VM3; } else { WAIT_VM0; }
        __builtin_amdgcn_s_barrier();

        char* base = lds + (t & 1) * 12288;
        short8 a[2], bfr[4];
#pragma unroll
        for (int mi = 0; mi < 2; ++mi) {
            int r = wid * 32 + mi * 16 + fr;
            a[mi] = *reinterpret_cast<const short8*>(base + r * 64 + ((fs ^ (r & 3)) << 4));
        }
#pragma unroll
        for (int ni = 0; ni < 4; ++ni) {
            int c = ni * 16 + fr;
            bfr[ni] = *reinterpret_cast<const short8*>(base + 8192 + c * 64 + ((fs ^ (c & 3)) << 4));
        }
#pragma unroll
        for (int mi = 0; mi < 2; ++mi)
#pragma unroll
            for (int ni = 0; ni < 4; ++ni)
                acc[mi][ni] = __builtin_amdgcn_mfma_f32_16x16x32_bf16(
                    a[mi], bfr[ni], acc[mi][ni], 0, 0, 0);

        WAIT_LGKM0;
        __builtin_amdgcn_s_barrier();
        if (t + 2 < NT) stage(base, (t + 2) * 32);
    }

    float bv[4];
#pragma unroll
    for (int ni = 0; ni < 4; ++ni)
        bv[ni] = bias ? bias[bcol + ni * 16 + fr] : 0.f;

#pragma unroll
    for (int mi = 0; mi < 2; ++mi) {
#pragma unroll
        for (int reg = 0; reg < 4; ++reg) {
            int row = brow + wid * 32 + mi * 16 + fs * 4 + reg;
#pragma unroll
            for (int ni = 0; ni < 4; ++ni) {
                int col = bcol + ni * 16 + fr;
                C[(size_t)row * N + col] = acc[mi][ni][reg] + bv[ni];
            }
        }
    }
}

// ---------------------------------------------------------------------------
// Wave-per-row top-8 + softmax + mix. No barriers, no LDS.
__global__ __launch_bounds__(256) void k_topk_mix_wave(
    const float* __restrict__ logits, const float* __restrict__ Z,
    const int* __restrict__ qp, unsigned short* __restrict__ mix)
{
    const int ln  = threadIdx.x & 63;
    const int row = blockIdx.x * 4 + (threadIdx.x >> 6);   // (b*L + l)
    const int b   = row >> 11;                              // L = 2048
    const int start = qp[b], len = qp[b + 1] - start;

    const float* lrow = logits + (size_t)row * SMAX;

    float v[16];
#pragma unroll
    for (int c = 0; c < 4; ++c) {
        float4 q = reinterpret_cast<const float4*>(lrow)[c * 64 + ln];
        int s0 = c * 256 + ln * 4;
        v[c * 4 + 0] = (s0 + 0 < len) ? q.x : -INFINITY;
        v[c * 4 + 1] = (s0 + 1 < len) ? q.y : -INFINITY;
        v[c * 4 + 2] = (s0 + 2 < len) ? q.z : -INFINITY;
        v[c * 4 + 3] = (s0 + 3 < len) ? q.w : -INFINITY;
    }

    float wv[TOPK]; int wi[TOPK];
#pragma unroll
    for (int it = 0; it < TOPK; ++it) {
        float bvv = v[0]; int bj = 0;
#pragma unroll
        for (int j = 1; j < 16; ++j)
            if (v[j] > bvv) { bvv = v[j]; bj = j; }
        int gidx = (bj >> 2) * 256 + ln * 4 + (bj & 3);
        float cv = bvv; int ci = gidx;
#pragma unroll
        for (int off = 32; off > 0; off >>= 1) {
            float ov = __shfl_xor(cv, off);
            int   oi = __shfl_xor(ci, off);
            if (ov > cv || (ov == cv && oi < ci)) { cv = ov; ci = oi; }
        }
        wv[it] = cv; wi[it] = ci;
#pragma unroll
        for (int j = 0; j < 16; ++j) {
            int sj = (j >> 2) * 256 + ln * 4 + (j & 3);
            if (sj == ci) v[j] = -INFINITY;
        }
    }

    float m = wv[0], denom = 0.f;
    float g[TOPK];
#pragma unroll
    for (int k = 0; k < TOPK; ++k) { g[k] = expf(wv[k] - m); denom += g[k]; }
    float inv = 1.f / denom;

    float4 acc[4] = {{0,0,0,0},{0,0,0,0},{0,0,0,0},{0,0,0,0}};
#pragma unroll
    for (int k = 0; k < TOPK; ++k) {
        int si = wi[k] >= 0 ? wi[k] : 0;
        const float4* zr = reinterpret_cast<const float4*>(Z + (size_t)(start + si) * D_DIM);
        float wgt = g[k] * inv;
#pragma unroll
        for (int c = 0; c < 4; ++c) {
            float4 z = zr[c * 64 + ln];
            acc[c].x = fmaf(wgt, z.x, acc[c].x);
            acc[c].y = fmaf(wgt, z.y, acc[c].y);
            acc[c].z = fmaf(wgt, z.z, acc[c].z);
            acc[c].w = fmaf(wgt, z.w, acc[c].w);
        }
    }
    unsigned short* mrow = mix + (size_t)row * D_DIM;
#pragma unroll
    for (int c = 0; c < 4; ++c) {
        ushort4v o;
        o[0] = f2bf(acc[c].x); o[1] = f2bf(acc[c].y);
        o[2] = f2bf(acc[c].z); o[3] = f2bf(acc[c].w);
        *reinterpret_cast<ushort4v*>(mrow + (c * 64 + ln) * 4) = o;
    }
}

// ---------------------------------------------------------------------------
extern "C" void kernel_launch(void* const* d_in, const int* in_sizes, int n_in,
                              void* d_out, int out_size, void* d_ws, size_t ws_size,
                              hipStream_t stream) {
    const float* token_states = (const float*)d_in[0];
    const float* Z_sets       = (const float*)d_in[1];
    const float* desc_q       = (const float*)d_in[2];
    const int*   q_raw        = (const int*)d_in[3];
    const float* Wg_w  = (const float*)d_in[4];
    const float* Wg_b  = (const float*)d_in[5];
    const float* Wd_w  = (const float*)d_in[6];
    const float* Wd_b  = (const float*)d_in[7];
    const float* out_w = (const float*)d_in[8];
    const float* out_b = (const float*)d_in[9];
    float* out = (float*)d_out;

    const size_t NTOK = (size_t)BQ * LQ * D_DIM;
    const size_t NDES = (size_t)NQ * D_DIM;
    const size_t NW   = (size_t)D_DIM * D_DIM;

    char* ws = (char*)d_ws;
    int* qp = (int*)ws;
    unsigned short* tokenH = (unsigned short*)(ws + 256);
    unsigned short* tokenL = tokenH + NTOK;
    unsigned short* descH  = tokenL + NTOK;
    unsigned short* descL  = descH + NDES;
    unsigned short* wgH    = descL + NDES;
    unsigned short* wgL    = wgH + NW;
    unsigned short* wdH    = wgL + NW;
    unsigned short* wdL    = wdH + NW;
    unsigned short* owb    = wdL + NW;
    unsigned short* TprojH = owb + NW;
    unsigned short* TprojL = TprojH + NTOK;
    unsigned short* DprojH = TprojL + NTOK;
    unsigned short* DprojL = DprojH + NDES;
    float* logit          = (float*)tokenH;   // alias: token planes dead after Tproj GEMM
    unsigned short* mixb  = TprojH;           // alias: TprojH dead after logits GEMM

    k_convert_qptrs<<<1, 64, 0, stream>>>(q_raw, qp);

    k_cvt_split<<<NTOK / 2048, 256, 0, stream>>>(token_states, tokenH, tokenL, (int)NTOK);
    k_cvt_split<<<NDES / 2048, 256, 0, stream>>>(desc_q, descH, descL, (int)NDES);
    k_cvt_split<<<NW / 2048, 256, 0, stream>>>(Wg_w, wgH, wgL, (int)NW);
    k_cvt_split<<<NW / 2048, 256, 0, stream>>>(Wd_w, wdH, wdL, (int)NW);
    k_cvt_bf16<<<NW / 2048, 256, 0, stream>>>(out_w, owb, (int)NW);

    // Tproj = token @ Wg^T + b  (split out): grid (16, 64)
    k_gemm_split<<<dim3(D_DIM / 64, (BQ * LQ) / 128), 256, 0, stream>>>(
        tokenH, tokenL, wgH, wgL, Wg_b, TprojH, TprojL, BQ * LQ, D_DIM, D_DIM);

    // Dproj = desc @ Wd^T + b  (split out): grid (16, 16)
    k_gemm_split<<<dim3(D_DIM / 64, NQ / 128), 256, 0, stream>>>(
        descH, descL, wdH, wdL, Wd_b, DprojH, DprojL, NQ, D_DIM, D_DIM);

    // logits (fp32, windowed): grid (16, 32, 4)
    k_logits_split<<<dim3(SMAX / 64, LQ / 64, BQ), 256, 0, stream>>>(
        TprojH, TprojL, DprojH, DprojL, qp, logit);

    // top-8 + softmax + Z mix (bf16)
    k_topk_mix_wave<<<(BQ * LQ) / 4, 256, 0, stream>>>(logit, Z_sets, qp, mixb);

    // out = mix @ out_w^T + b (fp32): grid (16, 64)
    k_gemm_bf16_f32out<<<dim3(D_DIM / 64, (BQ * LQ) / 128), 256, 0, stream>>>(
        mixb, owb, out_b, out, BQ * LQ, D_DIM, D_DIM);
}

// Round 7
// 208.209 us; speedup vs baseline: 1.2234x; 1.0834x over previous
//
#include <hip/hip_runtime.h>
#include <hip/hip_bf16.h>
#include <math.h>

#define BQ    4
#define LQ    2048
#define D_DIM 1024
#define NQ    2048
#define SMAX  1024
#define TOPK  8

typedef __attribute__((ext_vector_type(8))) short          short8;
typedef __attribute__((ext_vector_type(4))) float          f32x4;
typedef __attribute__((ext_vector_type(8))) unsigned short ushort8;
typedef __attribute__((ext_vector_type(4))) unsigned short ushort4v;

typedef __attribute__((address_space(3))) void as3_void;
typedef __attribute__((address_space(1))) void as1_void;

__device__ __forceinline__ void gload_lds16(const void* g, void* l) {
    __builtin_amdgcn_global_load_lds((const as1_void*)g, (as3_void*)l, 16, 0, 0);
}

__device__ __forceinline__ unsigned short f2bf(float f) {
    __hip_bfloat16 h = __float2bfloat16(f);
    return *reinterpret_cast<unsigned short*>(&h);
}
__device__ __forceinline__ float bf2f(unsigned short u) {
    __hip_bfloat16 h = *reinterpret_cast<__hip_bfloat16*>(&u);
    return __bfloat162float(h);
}

// slot-XOR swizzle: row r's 16B k-slot permutation. (r^(r>>2))&3 spreads
// rows {0,4,8,12} too (old r&3 left them colliding -> 4-way ds_read conflict).
__device__ __forceinline__ int swz(int r) { return (r ^ (r >> 2)) & 3; }

// Counted waits (T4): vmcnt stays >0 in the main loop so prefetch loads
// span barriers.
#define WAIT_VM0   asm volatile("s_waitcnt vmcnt(0)" ::: "memory")
#define WAIT_VM4   asm volatile("s_waitcnt vmcnt(4)" ::: "memory")
#define WAIT_VM6   asm volatile("s_waitcnt vmcnt(6)" ::: "memory")
#define WAIT_VM8   asm volatile("s_waitcnt vmcnt(8)" ::: "memory")
#define WAIT_LGKM0 asm volatile("s_waitcnt lgkmcnt(0)" ::: "memory")

// ---------------------------------------------------------------------------
__global__ void k_convert_qptrs(const int* __restrict__ q_raw, int* __restrict__ q_out) {
    if (threadIdx.x == 0 && blockIdx.x == 0) {
        bool is64 = (q_raw[1] == 0);
        for (int i = 0; i <= BQ; ++i)
            q_out[i] = is64 ? q_raw[2 * i] : q_raw[i];
    }
}

__global__ __launch_bounds__(256) void k_cvt_bf16(
    const float* __restrict__ in, unsigned short* __restrict__ out, int n)
{
    int i = (blockIdx.x * 256 + threadIdx.x) * 8;
    if (i >= n) return;
    float4 v0 = *reinterpret_cast<const float4*>(in + i);
    float4 v1 = *reinterpret_cast<const float4*>(in + i + 4);
    ushort8 u;
    u[0] = f2bf(v0.x); u[1] = f2bf(v0.y); u[2] = f2bf(v0.z); u[3] = f2bf(v0.w);
    u[4] = f2bf(v1.x); u[5] = f2bf(v1.y); u[6] = f2bf(v1.z); u[7] = f2bf(v1.w);
    *reinterpret_cast<ushort8*>(out + i) = u;
}

__global__ __launch_bounds__(256) void k_cvt_split(
    const float* __restrict__ in, unsigned short* __restrict__ hi,
    unsigned short* __restrict__ lo, int n)
{
    int i = (blockIdx.x * 256 + threadIdx.x) * 8;
    if (i >= n) return;
    float4 v0 = *reinterpret_cast<const float4*>(in + i);
    float4 v1 = *reinterpret_cast<const float4*>(in + i + 4);
    float x[8] = {v0.x, v0.y, v0.z, v0.w, v1.x, v1.y, v1.z, v1.w};
    ushort8 h8, l8;
#pragma unroll
    for (int k = 0; k < 8; ++k) {
        unsigned short h = f2bf(x[k]);
        h8[k] = h;
        l8[k] = f2bf(x[k] - bf2f(h));
    }
    *reinterpret_cast<ushort8*>(hi + i) = h8;
    *reinterpret_cast<ushort8*>(lo + i) = l8;
}

// ---------------------------------------------------------------------------
// Split-bf16 GEMM (3-MFMA fp32 emulation), BM=128 x BN (64 or 128), BK=32,
// counted-vmcnt 2-deep pipeline, setprio around MFMA cluster.
// BN=128: 4 waves x 64x64, 48 MFMA : 8 loads/iter, LDS 2x32K (2 blk/CU).
// BN=64 : 4 waves x 32x64, 24 MFMA : 6 loads/iter, LDS 2x24K.
template <int BN>
__global__ __launch_bounds__(256) void k_gemm_split(
    const unsigned short* __restrict__ Ah, const unsigned short* __restrict__ Al,
    const unsigned short* __restrict__ Wh, const unsigned short* __restrict__ Wl,
    const float* __restrict__ bias,
    unsigned short* __restrict__ Ch, unsigned short* __restrict__ Cl,
    int M, int N, int K)
{
    constexpr int WB   = BN * 64;            // bytes per W plane
    constexpr int BUF  = 16384 + 2 * WB;     // bytes per LDS buffer
    constexpr int MI   = (BN == 128) ? 4 : 2;
    __shared__ __align__(16) char lds[2 * BUF];

    // XCD-chunked bijective swizzle (grid totals are multiples of 8)
    const int nbx = gridDim.x;
    const int total = nbx * gridDim.y;
    const int d = blockIdx.x + nbx * blockIdx.y;
    const int logical = (d & 7) * (total >> 3) + (d >> 3);
    const int bcol = (logical % nbx) * BN;
    const int brow = (logical / nbx) * 128;

    const int tid = threadIdx.x;
    const int ln  = tid & 63;
    const int wid = tid >> 6;
    const int fr  = ln & 15, fs = ln >> 4;
    const int arow0 = (BN == 128) ? (wid >> 1) * 64 : wid * 32;
    const int bcol0 = (BN == 128) ? (wid & 1) * 64 : 0;
    const int srow = tid >> 2;       // 0..63
    const int sslt = tid & 3;

    const int kk0 = (sslt ^ swz(srow)) << 3;
    const size_t offA0 = (size_t)(brow + srow) * K + kk0;
    const size_t offW0 = (size_t)(bcol + srow) * K + kk0;

    auto stage = [&](char* base, int k0) {
        gload_lds16(Ah + offA0 + k0,          base + wid * 1024);
        gload_lds16(Ah + offA0 + 64 * K + k0, base + 4096 + wid * 1024);
        gload_lds16(Al + offA0 + k0,          base + 8192 + wid * 1024);
        gload_lds16(Al + offA0 + 64 * K + k0, base + 12288 + wid * 1024);
        gload_lds16(Wh + offW0 + k0,          base + 16384 + wid * 1024);
        if (BN == 128)
            gload_lds16(Wh + offW0 + 64 * K + k0, base + 16384 + 4096 + wid * 1024);
        gload_lds16(Wl + offW0 + k0,          base + 16384 + WB + wid * 1024);
        if (BN == 128)
            gload_lds16(Wl + offW0 + 64 * K + k0, base + 16384 + WB + 4096 + wid * 1024);
    };

    f32x4 acc[MI][4] = {};

    stage(lds, 0);
    stage(lds + BUF, 32);

    const int NT = K / 32;
    for (int t = 0; t < NT; ++t) {
        if (t < NT - 1) {
            if (BN == 128) { WAIT_VM8; } else { WAIT_VM6; }
        } else { WAIT_VM0; }
        __builtin_amdgcn_s_barrier();

        char* base = lds + (t & 1) * BUF;
        short8 ahf[MI], alf[MI], bhf[4], blf[4];
#pragma unroll
        for (int mi = 0; mi < MI; ++mi) {
            int r = arow0 + mi * 16 + fr;
            int o = r * 64 + ((fs ^ swz(r)) << 4);
            ahf[mi] = *reinterpret_cast<const short8*>(base + o);
            alf[mi] = *reinterpret_cast<const short8*>(base + 8192 + o);
        }
#pragma unroll
        for (int ni = 0; ni < 4; ++ni) {
            int c = bcol0 + ni * 16 + fr;
            int o = c * 64 + ((fs ^ swz(c)) << 4);
            bhf[ni] = *reinterpret_cast<const short8*>(base + 16384 + o);
            blf[ni] = *reinterpret_cast<const short8*>(base + 16384 + WB + o);
        }
        __builtin_amdgcn_s_setprio(1);
#pragma unroll
        for (int mi = 0; mi < MI; ++mi)
#pragma unroll
            for (int ni = 0; ni < 4; ++ni)
                acc[mi][ni] = __builtin_amdgcn_mfma_f32_16x16x32_bf16(
                    ahf[mi], bhf[ni], acc[mi][ni], 0, 0, 0);
#pragma unroll
        for (int mi = 0; mi < MI; ++mi)
#pragma unroll
            for (int ni = 0; ni < 4; ++ni)
                acc[mi][ni] = __builtin_amdgcn_mfma_f32_16x16x32_bf16(
                    ahf[mi], blf[ni], acc[mi][ni], 0, 0, 0);
#pragma unroll
        for (int mi = 0; mi < MI; ++mi)
#pragma unroll
            for (int ni = 0; ni < 4; ++ni)
                acc[mi][ni] = __builtin_amdgcn_mfma_f32_16x16x32_bf16(
                    alf[mi], bhf[ni], acc[mi][ni], 0, 0, 0);
        __builtin_amdgcn_s_setprio(0);

        WAIT_LGKM0;
        __builtin_amdgcn_s_barrier();
        if (t + 2 < NT) stage(base, (t + 2) * 32);
    }

    float bv[4];
#pragma unroll
    for (int ni = 0; ni < 4; ++ni)
        bv[ni] = bias ? bias[bcol + bcol0 + ni * 16 + fr] : 0.f;

#pragma unroll
    for (int mi = 0; mi < MI; ++mi) {
#pragma unroll
        for (int reg = 0; reg < 4; ++reg) {
            int row = brow + arow0 + mi * 16 + fs * 4 + reg;
#pragma unroll
            for (int ni = 0; ni < 4; ++ni) {
                int col = bcol + bcol0 + ni * 16 + fr;
                float v = acc[mi][ni][reg] + bv[ni];
                unsigned short h = f2bf(v);
                Ch[(size_t)row * N + col] = h;
                Cl[(size_t)row * N + col] = f2bf(v - bf2f(h));
            }
        }
    }
}

// ---------------------------------------------------------------------------
// Windowed split-bf16 logits, BM=64 x BN=64, counted-vmcnt pipeline, L=4.
__global__ __launch_bounds__(256) void k_logits_split(
    const unsigned short* __restrict__ Th, const unsigned short* __restrict__ Tl,
    const unsigned short* __restrict__ Dh, const unsigned short* __restrict__ Dl,
    const int* __restrict__ qp, float* __restrict__ logits)
{
    // XCD-chunked swizzle over fixed grid (16, 32, 4) = 2048 blocks
    const int d = blockIdx.x + 16 * (blockIdx.y + 32 * blockIdx.z);
    const int logical = (d & 7) * 256 + (d >> 3);
    const int b    = logical >> 9;
    const int brow = ((logical >> 4) & 31) * 64;
    const int bcol = (logical & 15) * 64;

    const int start = qp[b], len = qp[b + 1] - start;
    if (bcol >= len) return;            // block-uniform: barrier-safe

    __shared__ __align__(16) char lds[2 * 16384];

    const int tid = threadIdx.x;
    const int ln  = tid & 63;
    const int wid = tid >> 6;
    const int fr  = ln & 15, fs = ln >> 4;
    const int srow = tid >> 2;
    const int sslt = tid & 3;

    const int kka = (sslt ^ swz(srow)) << 3;
    const size_t offA0 = ((size_t)b * LQ + brow + srow) * D_DIM + kka;
    int wr = start + bcol + srow; if (wr > NQ - 1) wr = NQ - 1;
    const size_t offW0 = (size_t)wr * D_DIM + kka;

    auto stage = [&](char* base, int k0) {
        gload_lds16(Th + offA0 + k0, base + wid * 1024);
        gload_lds16(Tl + offA0 + k0, base + 4096 + wid * 1024);
        gload_lds16(Dh + offW0 + k0, base + 8192 + wid * 1024);
        gload_lds16(Dl + offW0 + k0, base + 12288 + wid * 1024);
    };

    f32x4 acc[4] = {};

    stage(lds, 0);
    stage(lds + 16384, 32);

    const int NT = D_DIM / 32;   // 32
    for (int t = 0; t < NT; ++t) {
        if (t < NT - 1) { WAIT_VM4; } else { WAIT_VM0; }
        __builtin_amdgcn_s_barrier();

        char* base = lds + (t & 1) * 16384;
        short8 ah, al, bh[4], bl[4];
        {
            int r = wid * 16 + fr;
            int o = r * 64 + ((fs ^ swz(r)) << 4);
            ah = *reinterpret_cast<const short8*>(base + o);
            al = *reinterpret_cast<const short8*>(base + 4096 + o);
        }
#pragma unroll
        for (int ni = 0; ni < 4; ++ni) {
            int c = ni * 16 + fr;
            int o = c * 64 + ((fs ^ swz(c)) << 4);
            bh[ni] = *reinterpret_cast<const short8*>(base + 8192 + o);
            bl[ni] = *reinterpret_cast<const short8*>(base + 12288 + o);
        }
        __builtin_amdgcn_s_setprio(1);
#pragma unroll
        for (int ni = 0; ni < 4; ++ni)
            acc[ni] = __builtin_amdgcn_mfma_f32_16x16x32_bf16(ah, bh[ni], acc[ni], 0, 0, 0);
#pragma unroll
        for (int ni = 0; ni < 4; ++ni)
            acc[ni] = __builtin_amdgcn_mfma_f32_16x16x32_bf16(ah, bl[ni], acc[ni], 0, 0, 0);
#pragma unroll
        for (int ni = 0; ni < 4; ++ni)
            acc[ni] = __builtin_amdgcn_mfma_f32_16x16x32_bf16(al, bh[ni], acc[ni], 0, 0, 0);
        __builtin_amdgcn_s_setprio(0);

        WAIT_LGKM0;
        __builtin_amdgcn_s_barrier();
        if (t + 2 < NT) stage(base, (t + 2) * 32);
    }

#pragma unroll
    for (int reg = 0; reg < 4; ++reg) {
        size_t row = (size_t)b * LQ + brow + wid * 16 + fs * 4 + reg;
#pragma unroll
        for (int ni = 0; ni < 4; ++ni) {
            int col = bcol + ni * 16 + fr;
            logits[row * SMAX + col] = acc[ni][reg];
        }
    }
}

// ---------------------------------------------------------------------------
// Plain bf16 GEMM, fp32 out, BM=128 x BN=128, counted-vmcnt pipeline, L=4.
// LDS/buf: As 8K | Bs 8K = 16 KB; x2 = 32 KB.
__global__ __launch_bounds__(256) void k_gemm_bf16_f32out(
    const unsigned short* __restrict__ A, const unsigned short* __restrict__ W,
    const float* __restrict__ bias, float* __restrict__ C,
    int M, int N, int K)
{
    __shared__ __align__(16) char lds[2 * 16384];

    const int nbx = gridDim.x;
    const int total = nbx * gridDim.y;
    const int d = blockIdx.x + nbx * blockIdx.y;
    const int logical = (d & 7) * (total >> 3) + (d >> 3);
    const int bcol = (logical % nbx) * 128;
    const int brow = (logical / nbx) * 128;

    const int tid = threadIdx.x;
    const int ln  = tid & 63;
    const int wid = tid >> 6;
    const int wm  = wid >> 1, wn = wid & 1;
    const int fr  = ln & 15, fs = ln >> 4;
    const int srow = tid >> 2;
    const int sslt = tid & 3;

    const int kk0 = (sslt ^ swz(srow)) << 3;
    const size_t offA0 = (size_t)(brow + srow) * K + kk0;
    const size_t offW0 = (size_t)(bcol + srow) * K + kk0;

    auto stage = [&](char* base, int k0) {
        gload_lds16(A + offA0 + k0,          base + wid * 1024);
        gload_lds16(A + offA0 + 64 * K + k0, base + 4096 + wid * 1024);
        gload_lds16(W + offW0 + k0,          base + 8192 + wid * 1024);
        gload_lds16(W + offW0 + 64 * K + k0, base + 12288 + wid * 1024);
    };

    f32x4 acc[4][4] = {};

    stage(lds, 0);
    stage(lds + 16384, 32);

    const int NT = K / 32;
    for (int t = 0; t < NT; ++t) {
        if (t < NT - 1) { WAIT_VM4; } else { WAIT_VM0; }
        __builtin_amdgcn_s_barrier();

        char* base = lds + (t & 1) * 16384;
        short8 a[4], bfr[4];
#pragma unroll
        for (int mi = 0; mi < 4; ++mi) {
            int r = wm * 64 + mi * 16 + fr;
            a[mi] = *reinterpret_cast<const short8*>(base + r * 64 + ((fs ^ swz(r)) << 4));
        }
#pragma unroll
        for (int ni = 0; ni < 4; ++ni) {
            int c = wn * 64 + ni * 16 + fr;
            bfr[ni] = *reinterpret_cast<const short8*>(base + 8192 + c * 64 + ((fs ^ swz(c)) << 4));
        }
        __builtin_amdgcn_s_setprio(1);
#pragma unroll
        for (int mi = 0; mi < 4; ++mi)
#pragma unroll
            for (int ni = 0; ni < 4; ++ni)
                acc[mi][ni] = __builtin_amdgcn_mfma_f32_16x16x32_bf16(
                    a[mi], bfr[ni], acc[mi][ni], 0, 0, 0);
        __builtin_amdgcn_s_setprio(0);

        WAIT_LGKM0;
        __builtin_amdgcn_s_barrier();
        if (t + 2 < NT) stage(base, (t + 2) * 32);
    }

    float bv[4];
#pragma unroll
    for (int ni = 0; ni < 4; ++ni)
        bv[ni] = bias ? bias[bcol + wn * 64 + ni * 16 + fr] : 0.f;

#pragma unroll
    for (int mi = 0; mi < 4; ++mi) {
#pragma unroll
        for (int reg = 0; reg < 4; ++reg) {
            int row = brow + wm * 64 + mi * 16 + fs * 4 + reg;
#pragma unroll
            for (int ni = 0; ni < 4; ++ni) {
                int col = bcol + wn * 64 + ni * 16 + fr;
                C[(size_t)row * N + col] = acc[mi][ni][reg] + bv[ni];
            }
        }
    }
}

// ---------------------------------------------------------------------------
// Wave-per-row top-8 + softmax + mix. No barriers, no LDS.
__global__ __launch_bounds__(256) void k_topk_mix_wave(
    const float* __restrict__ logits, const float* __restrict__ Z,
    const int* __restrict__ qp, unsigned short* __restrict__ mix)
{
    const int ln  = threadIdx.x & 63;
    const int row = blockIdx.x * 4 + (threadIdx.x >> 6);   // (b*L + l)
    const int b   = row >> 11;                              // L = 2048
    const int start = qp[b], len = qp[b + 1] - start;

    const float* lrow = logits + (size_t)row * SMAX;

    float v[16];
#pragma unroll
    for (int c = 0; c < 4; ++c) {
        float4 q = reinterpret_cast<const float4*>(lrow)[c * 64 + ln];
        int s0 = c * 256 + ln * 4;
        v[c * 4 + 0] = (s0 + 0 < len) ? q.x : -INFINITY;
        v[c * 4 + 1] = (s0 + 1 < len) ? q.y : -INFINITY;
        v[c * 4 + 2] = (s0 + 2 < len) ? q.z : -INFINITY;
        v[c * 4 + 3] = (s0 + 3 < len) ? q.w : -INFINITY;
    }

    float wv[TOPK]; int wi[TOPK];
#pragma unroll
    for (int it = 0; it < TOPK; ++it) {
        float bvv = v[0]; int bj = 0;
#pragma unroll
        for (int j = 1; j < 16; ++j)
            if (v[j] > bvv) { bvv = v[j]; bj = j; }
        int gidx = (bj >> 2) * 256 + ln * 4 + (bj & 3);
        float cv = bvv; int ci = gidx;
#pragma unroll
        for (int off = 32; off > 0; off >>= 1) {
            float ov = __shfl_xor(cv, off);
            int   oi = __shfl_xor(ci, off);
            if (ov > cv || (ov == cv && oi < ci)) { cv = ov; ci = oi; }
        }
        wv[it] = cv; wi[it] = ci;
#pragma unroll
        for (int j = 0; j < 16; ++j) {
            int sj = (j >> 2) * 256 + ln * 4 + (j & 3);
            if (sj == ci) v[j] = -INFINITY;
        }
    }

    float m = wv[0], denom = 0.f;
    float g[TOPK];
#pragma unroll
    for (int k = 0; k < TOPK; ++k) { g[k] = expf(wv[k] - m); denom += g[k]; }
    float inv = 1.f / denom;

    float4 acc[4] = {{0,0,0,0},{0,0,0,0},{0,0,0,0},{0,0,0,0}};
#pragma unroll
    for (int k = 0; k < TOPK; ++k) {
        int si = wi[k] >= 0 ? wi[k] : 0;
        const float4* zr = reinterpret_cast<const float4*>(Z + (size_t)(start + si) * D_DIM);
        float wgt = g[k] * inv;
#pragma unroll
        for (int c = 0; c < 4; ++c) {
            float4 z = zr[c * 64 + ln];
            acc[c].x = fmaf(wgt, z.x, acc[c].x);
            acc[c].y = fmaf(wgt, z.y, acc[c].y);
            acc[c].z = fmaf(wgt, z.z, acc[c].z);
            acc[c].w = fmaf(wgt, z.w, acc[c].w);
        }
    }
    unsigned short* mrow = mix + (size_t)row * D_DIM;
#pragma unroll
    for (int c = 0; c < 4; ++c) {
        ushort4v o;
        o[0] = f2bf(acc[c].x); o[1] = f2bf(acc[c].y);
        o[2] = f2bf(acc[c].z); o[3] = f2bf(acc[c].w);
        *reinterpret_cast<ushort4v*>(mrow + (c * 64 + ln) * 4) = o;
    }
}

// ---------------------------------------------------------------------------
extern "C" void kernel_launch(void* const* d_in, const int* in_sizes, int n_in,
                              void* d_out, int out_size, void* d_ws, size_t ws_size,
                              hipStream_t stream) {
    const float* token_states = (const float*)d_in[0];
    const float* Z_sets       = (const float*)d_in[1];
    const float* desc_q       = (const float*)d_in[2];
    const int*   q_raw        = (const int*)d_in[3];
    const float* Wg_w  = (const float*)d_in[4];
    const float* Wg_b  = (const float*)d_in[5];
    const float* Wd_w  = (const float*)d_in[6];
    const float* Wd_b  = (const float*)d_in[7];
    const float* out_w = (const float*)d_in[8];
    const float* out_b = (const float*)d_in[9];
    float* out = (float*)d_out;

    const size_t NTOK = (size_t)BQ * LQ * D_DIM;
    const size_t NDES = (size_t)NQ * D_DIM;
    const size_t NW   = (size_t)D_DIM * D_DIM;

    char* ws = (char*)d_ws;
    int* qp = (int*)ws;
    unsigned short* tokenH = (unsigned short*)(ws + 256);
    unsigned short* tokenL = tokenH + NTOK;
    unsigned short* descH  = tokenL + NTOK;
    unsigned short* descL  = descH + NDES;
    unsigned short* wgH    = descL + NDES;
    unsigned short* wgL    = wgH + NW;
    unsigned short* wdH    = wgL + NW;
    unsigned short* wdL    = wdH + NW;
    unsigned short* owb    = wdL + NW;
    unsigned short* TprojH = owb + NW;
    unsigned short* TprojL = TprojH + NTOK;
    unsigned short* DprojH = TprojL + NTOK;
    unsigned short* DprojL = DprojH + NDES;
    float* logit          = (float*)tokenH;   // alias: token planes dead after Tproj GEMM
    unsigned short* mixb  = TprojH;           // alias: TprojH dead after logits GEMM

    k_convert_qptrs<<<1, 64, 0, stream>>>(q_raw, qp);

    k_cvt_split<<<NTOK / 2048, 256, 0, stream>>>(token_states, tokenH, tokenL, (int)NTOK);
    k_cvt_split<<<NDES / 2048, 256, 0, stream>>>(desc_q, descH, descL, (int)NDES);
    k_cvt_split<<<NW / 2048, 256, 0, stream>>>(Wg_w, wgH, wgL, (int)NW);
    k_cvt_split<<<NW / 2048, 256, 0, stream>>>(Wd_w, wdH, wdL, (int)NW);
    k_cvt_bf16<<<NW / 2048, 256, 0, stream>>>(out_w, owb, (int)NW);

    // Tproj = token @ Wg^T + b  (split out): BN=128, grid (8, 64) = 512 = 2/CU
    k_gemm_split<128><<<dim3(D_DIM / 128, (BQ * LQ) / 128), 256, 0, stream>>>(
        tokenH, tokenL, wgH, wgL, Wg_b, TprojH, TprojL, BQ * LQ, D_DIM, D_DIM);

    // Dproj = desc @ Wd^T + b  (split out): BN=64, grid (16, 16) = 256 = 1/CU
    k_gemm_split<64><<<dim3(D_DIM / 64, NQ / 128), 256, 0, stream>>>(
        descH, descL, wdH, wdL, Wd_b, DprojH, DprojL, NQ, D_DIM, D_DIM);

    // logits (fp32, windowed): grid (16, 32, 4)
    k_logits_split<<<dim3(SMAX / 64, LQ / 64, BQ), 256, 0, stream>>>(
        TprojH, TprojL, DprojH, DprojL, qp, logit);

    // top-8 + softmax + Z mix (bf16)
    k_topk_mix_wave<<<(BQ * LQ) / 4, 256, 0, stream>>>(logit, Z_sets, qp, mixb);

    // out = mix @ out_w^T + b (fp32): BN=128, grid (8, 64)
    k_gemm_bf16_f32out<<<dim3(D_DIM / 128, (BQ * LQ) / 128), 256, 0, stream>>>(
        mixb, owb, out_b, out, BQ * LQ, D_DIM, D_DIM);
}

// Round 8
// 192.851 us; speedup vs baseline: 1.3209x; 1.0796x over previous
//
#include <hip/hip_runtime.h>
#include <hip/hip_bf16.h>
#include <math.h>

#define BQ    4
#define LQ    2048
#define D_DIM 1024
#define NQ    2048
#define SMAX  1024
#define TOPK  8

typedef __attribute__((ext_vector_type(8))) short          short8;
typedef __attribute__((ext_vector_type(4))) float          f32x4;
typedef __attribute__((ext_vector_type(8))) unsigned short ushort8;
typedef __attribute__((ext_vector_type(4))) unsigned short ushort4v;

typedef __attribute__((address_space(3))) void as3_void;
typedef __attribute__((address_space(1))) void as1_void;

__device__ __forceinline__ void gload_lds16(const void* g, void* l) {
    __builtin_amdgcn_global_load_lds((const as1_void*)g, (as3_void*)l, 16, 0, 0);
}

__device__ __forceinline__ unsigned short f2bf(float f) {
    __hip_bfloat16 h = __float2bfloat16(f);
    return *reinterpret_cast<unsigned short*>(&h);
}
__device__ __forceinline__ float bf2f(unsigned short u) {
    __hip_bfloat16 h = *reinterpret_cast<__hip_bfloat16*>(&u);
    return __bfloat162float(h);
}

// slot-XOR swizzle: conflict-free within each 8-consecutive-lane b128 group.
__device__ __forceinline__ int swz(int r) { return (r ^ (r >> 2)) & 3; }

#define WAIT_VM0   asm volatile("s_waitcnt vmcnt(0)" ::: "memory")
#define WAIT_VM4   asm volatile("s_waitcnt vmcnt(4)" ::: "memory")
#define WAIT_VM6   asm volatile("s_waitcnt vmcnt(6)" ::: "memory")
#define WAIT_VM8   asm volatile("s_waitcnt vmcnt(8)" ::: "memory")
#define WAIT_LGKM0 asm volatile("s_waitcnt lgkmcnt(0)" ::: "memory")

// ---------------------------------------------------------------------------
// One launch: all fp32->split-bf16 conversions + plain owb cvt + qptrs.
// Regions (2048 elems/block): [0,4096) token | [4096,5120) desc |
// [5120,5632) Wg | [5632,6144) Wd | [6144,6656) out_w(plain).
__global__ __launch_bounds__(256) void k_cvt_all(
    const float* __restrict__ token_states, const float* __restrict__ desc_q,
    const float* __restrict__ Wg_w, const float* __restrict__ Wd_w,
    const float* __restrict__ out_w, const int* __restrict__ q_raw,
    unsigned short* __restrict__ tokenH, unsigned short* __restrict__ tokenL,
    unsigned short* __restrict__ descH,  unsigned short* __restrict__ descL,
    unsigned short* __restrict__ wgH,    unsigned short* __restrict__ wgL,
    unsigned short* __restrict__ wdH,    unsigned short* __restrict__ wdL,
    unsigned short* __restrict__ owb,    int* __restrict__ qp)
{
    const int blk = blockIdx.x;
    if (blk == 0 && threadIdx.x == 0) {
        bool is64 = (q_raw[1] == 0);
        for (int i = 0; i <= BQ; ++i)
            qp[i] = is64 ? q_raw[2 * i] : q_raw[i];
    }

    const float* in; unsigned short *hi, *lo = nullptr; int local;
    if (blk < 4096)      { in = token_states; hi = tokenH; lo = tokenL; local = blk; }
    else if (blk < 5120) { in = desc_q; hi = descH; lo = descL; local = blk - 4096; }
    else if (blk < 5632) { in = Wg_w;   hi = wgH;   lo = wgL;   local = blk - 5120; }
    else if (blk < 6144) { in = Wd_w;   hi = wdH;   lo = wdL;   local = blk - 5632; }
    else                 { in = out_w;  hi = owb;               local = blk - 6144; }

    int i = (local * 256 + threadIdx.x) * 8;
    float4 v0 = *reinterpret_cast<const float4*>(in + i);
    float4 v1 = *reinterpret_cast<const float4*>(in + i + 4);
    float x[8] = {v0.x, v0.y, v0.z, v0.w, v1.x, v1.y, v1.z, v1.w};
    ushort8 h8, l8;
#pragma unroll
    for (int k = 0; k < 8; ++k) {
        unsigned short h = f2bf(x[k]);
        h8[k] = h;
        l8[k] = f2bf(x[k] - bf2f(h));
    }
    *reinterpret_cast<ushort8*>(hi + i) = h8;
    if (lo) *reinterpret_cast<ushort8*>(lo + i) = l8;
}

// ---------------------------------------------------------------------------
// Fused Tproj+Dproj split-bf16 GEMM (3-MFMA fp32 emulation).
// BM=128 x BN=128, BK=32, counted-vmcnt 2-deep pipeline, setprio.
// grid (8, 80): row-tiles 0..63 -> token@Wg -> Tproj; 64..79 -> desc@Wd -> Dproj.
__global__ __launch_bounds__(256) void k_proj_split(
    const unsigned short* __restrict__ tokenH, const unsigned short* __restrict__ tokenL,
    const unsigned short* __restrict__ descH,  const unsigned short* __restrict__ descL,
    const unsigned short* __restrict__ wgH, const unsigned short* __restrict__ wgL,
    const unsigned short* __restrict__ wdH, const unsigned short* __restrict__ wdL,
    const float* __restrict__ Wg_b, const float* __restrict__ Wd_b,
    unsigned short* __restrict__ TprojH, unsigned short* __restrict__ TprojL,
    unsigned short* __restrict__ DprojH, unsigned short* __restrict__ DprojL)
{
    constexpr int K = D_DIM, N = D_DIM;
    __shared__ __align__(16) char lds[2 * 32768];

    // XCD-chunked bijective swizzle over 640 blocks
    const int d = blockIdx.x + 8 * blockIdx.y;
    const int logical = (d & 7) * 80 + (d >> 3);
    const int bcol = (logical & 7) * 128;
    const int bt   = logical >> 3;            // 0..79

    const unsigned short *Ah, *Al, *Wh, *Wl;
    const float* bias;
    unsigned short *Ch, *Cl;
    int brow;
    if (bt < 64) { Ah = tokenH; Al = tokenL; Wh = wgH; Wl = wgL; bias = Wg_b;
                   Ch = TprojH; Cl = TprojL; brow = bt * 128; }
    else         { Ah = descH;  Al = descL;  Wh = wdH; Wl = wdL; bias = Wd_b;
                   Ch = DprojH; Cl = DprojL; brow = (bt - 64) * 128; }

    const int tid = threadIdx.x;
    const int ln  = tid & 63;
    const int wid = tid >> 6;
    const int wm  = wid >> 1, wn = wid & 1;
    const int fr  = ln & 15, fs = ln >> 4;
    const int srow = tid >> 2;
    const int sslt = tid & 3;

    const int kk0 = (sslt ^ swz(srow)) << 3;
    const size_t offA0 = (size_t)(brow + srow) * K + kk0;
    const size_t offW0 = (size_t)(bcol + srow) * K + kk0;

    auto stage = [&](char* base, int k0) {
        gload_lds16(Ah + offA0 + k0,          base + wid * 1024);
        gload_lds16(Ah + offA0 + 64 * K + k0, base + 4096 + wid * 1024);
        gload_lds16(Al + offA0 + k0,          base + 8192 + wid * 1024);
        gload_lds16(Al + offA0 + 64 * K + k0, base + 12288 + wid * 1024);
        gload_lds16(Wh + offW0 + k0,          base + 16384 + wid * 1024);
        gload_lds16(Wh + offW0 + 64 * K + k0, base + 20480 + wid * 1024);
        gload_lds16(Wl + offW0 + k0,          base + 24576 + wid * 1024);
        gload_lds16(Wl + offW0 + 64 * K + k0, base + 28672 + wid * 1024);
    };

    f32x4 acc[4][4] = {};

    stage(lds, 0);
    stage(lds + 32768, 32);

    const int NT = K / 32;
    for (int t = 0; t < NT; ++t) {
        if (t < NT - 1) { WAIT_VM8; } else { WAIT_VM0; }
        __builtin_amdgcn_s_barrier();

        char* base = lds + (t & 1) * 32768;
        short8 ahf[4], alf[4], bhf[4], blf[4];
#pragma unroll
        for (int mi = 0; mi < 4; ++mi) {
            int r = wm * 64 + mi * 16 + fr;
            int o = r * 64 + ((fs ^ swz(r)) << 4);
            ahf[mi] = *reinterpret_cast<const short8*>(base + o);
            alf[mi] = *reinterpret_cast<const short8*>(base + 8192 + o);
        }
#pragma unroll
        for (int ni = 0; ni < 4; ++ni) {
            int c = wn * 64 + ni * 16 + fr;
            int o = c * 64 + ((fs ^ swz(c)) << 4);
            bhf[ni] = *reinterpret_cast<const short8*>(base + 16384 + o);
            blf[ni] = *reinterpret_cast<const short8*>(base + 24576 + o);
        }
        __builtin_amdgcn_s_setprio(1);
#pragma unroll
        for (int mi = 0; mi < 4; ++mi)
#pragma unroll
            for (int ni = 0; ni < 4; ++ni)
                acc[mi][ni] = __builtin_amdgcn_mfma_f32_16x16x32_bf16(
                    ahf[mi], bhf[ni], acc[mi][ni], 0, 0, 0);
#pragma unroll
        for (int mi = 0; mi < 4; ++mi)
#pragma unroll
            for (int ni = 0; ni < 4; ++ni)
                acc[mi][ni] = __builtin_amdgcn_mfma_f32_16x16x32_bf16(
                    ahf[mi], blf[ni], acc[mi][ni], 0, 0, 0);
#pragma unroll
        for (int mi = 0; mi < 4; ++mi)
#pragma unroll
            for (int ni = 0; ni < 4; ++ni)
                acc[mi][ni] = __builtin_amdgcn_mfma_f32_16x16x32_bf16(
                    alf[mi], bhf[ni], acc[mi][ni], 0, 0, 0);
        __builtin_amdgcn_s_setprio(0);

        WAIT_LGKM0;
        __builtin_amdgcn_s_barrier();
        if (t + 2 < NT) stage(base, (t + 2) * 32);
    }

    float bv[4];
#pragma unroll
    for (int ni = 0; ni < 4; ++ni)
        bv[ni] = bias[bcol + wn * 64 + ni * 16 + fr];

#pragma unroll
    for (int mi = 0; mi < 4; ++mi) {
#pragma unroll
        for (int reg = 0; reg < 4; ++reg) {
            int row = brow + wm * 64 + mi * 16 + fs * 4 + reg;
#pragma unroll
            for (int ni = 0; ni < 4; ++ni) {
                int col = bcol + wn * 64 + ni * 16 + fr;
                float v = acc[mi][ni][reg] + bv[ni];
                unsigned short h = f2bf(v);
                Ch[(size_t)row * N + col] = h;
                Cl[(size_t)row * N + col] = f2bf(v - bf2f(h));
            }
        }
    }
}

// ---------------------------------------------------------------------------
// Windowed split-bf16 logits, BM=128 x BN=64: 4 waves x (32 rows x 64 cols),
// 24 MFMA : 12 ds_read per wave-iter. Counted-vmcnt pipeline (L=6), setprio.
// LDS/buf: A 2x8K + B 2x4K = 24 KB; x2 = 48 KB. grid (16,16,4) = 1024 blocks.
__global__ __launch_bounds__(256) void k_logits_split(
    const unsigned short* __restrict__ Th, const unsigned short* __restrict__ Tl,
    const unsigned short* __restrict__ Dh, const unsigned short* __restrict__ Dl,
    const int* __restrict__ qp, float* __restrict__ logits)
{
    const int d = blockIdx.x + 16 * (blockIdx.y + 16 * blockIdx.z);
    const int logical = (d & 7) * 128 + (d >> 3);
    const int b    = logical >> 8;
    const int brow = ((logical >> 4) & 15) * 128;
    const int bcol = (logical & 15) * 64;

    const int start = qp[b], len = qp[b + 1] - start;
    if (bcol >= len) return;            // block-uniform: barrier-safe

    __shared__ __align__(16) char lds[2 * 24576];

    const int tid = threadIdx.x;
    const int ln  = tid & 63;
    const int wid = tid >> 6;
    const int fr  = ln & 15, fs = ln >> 4;
    const int srow = tid >> 2;
    const int sslt = tid & 3;

    const int kka = (sslt ^ swz(srow)) << 3;
    const size_t offA0 = ((size_t)b * LQ + brow + srow) * D_DIM + kka;
    int wr = start + bcol + srow; if (wr > NQ - 1) wr = NQ - 1;
    const size_t offW0 = (size_t)wr * D_DIM + kka;

    auto stage = [&](char* base, int k0) {
        gload_lds16(Th + offA0 + k0,              base + wid * 1024);
        gload_lds16(Th + offA0 + 64 * D_DIM + k0, base + 4096 + wid * 1024);
        gload_lds16(Tl + offA0 + k0,              base + 8192 + wid * 1024);
        gload_lds16(Tl + offA0 + 64 * D_DIM + k0, base + 12288 + wid * 1024);
        gload_lds16(Dh + offW0 + k0,              base + 16384 + wid * 1024);
        gload_lds16(Dl + offW0 + k0,              base + 20480 + wid * 1024);
    };

    f32x4 acc[2][4] = {};

    stage(lds, 0);
    stage(lds + 24576, 32);

    const int NT = D_DIM / 32;   // 32
    for (int t = 0; t < NT; ++t) {
        if (t < NT - 1) { WAIT_VM6; } else { WAIT_VM0; }
        __builtin_amdgcn_s_barrier();

        char* base = lds + (t & 1) * 24576;
        short8 ah[2], al[2], bh[4], bl[4];
#pragma unroll
        for (int mi = 0; mi < 2; ++mi) {
            int r = wid * 32 + mi * 16 + fr;
            int o = r * 64 + ((fs ^ swz(r)) << 4);
            ah[mi] = *reinterpret_cast<const short8*>(base + o);
            al[mi] = *reinterpret_cast<const short8*>(base + 8192 + o);
        }
#pragma unroll
        for (int ni = 0; ni < 4; ++ni) {
            int c = ni * 16 + fr;
            int o = c * 64 + ((fs ^ swz(c)) << 4);
            bh[ni] = *reinterpret_cast<const short8*>(base + 16384 + o);
            bl[ni] = *reinterpret_cast<const short8*>(base + 20480 + o);
        }
        __builtin_amdgcn_s_setprio(1);
#pragma unroll
        for (int mi = 0; mi < 2; ++mi)
#pragma unroll
            for (int ni = 0; ni < 4; ++ni)
                acc[mi][ni] = __builtin_amdgcn_mfma_f32_16x16x32_bf16(
                    ah[mi], bh[ni], acc[mi][ni], 0, 0, 0);
#pragma unroll
        for (int mi = 0; mi < 2; ++mi)
#pragma unroll
            for (int ni = 0; ni < 4; ++ni)
                acc[mi][ni] = __builtin_amdgcn_mfma_f32_16x16x32_bf16(
                    ah[mi], bl[ni], acc[mi][ni], 0, 0, 0);
#pragma unroll
        for (int mi = 0; mi < 2; ++mi)
#pragma unroll
            for (int ni = 0; ni < 4; ++ni)
                acc[mi][ni] = __builtin_amdgcn_mfma_f32_16x16x32_bf16(
                    al[mi], bh[ni], acc[mi][ni], 0, 0, 0);
        __builtin_amdgcn_s_setprio(0);

        WAIT_LGKM0;
        __builtin_amdgcn_s_barrier();
        if (t + 2 < NT) stage(base, (t + 2) * 32);
    }

#pragma unroll
    for (int mi = 0; mi < 2; ++mi) {
#pragma unroll
        for (int reg = 0; reg < 4; ++reg) {
            size_t row = (size_t)b * LQ + brow + wid * 32 + mi * 16 + fs * 4 + reg;
#pragma unroll
            for (int ni = 0; ni < 4; ++ni) {
                int col = bcol + ni * 16 + fr;
                logits[row * SMAX + col] = acc[mi][ni][reg];
            }
        }
    }
}

// ---------------------------------------------------------------------------
// Plain bf16 GEMM, fp32 out, BM=128 x BN=128, counted-vmcnt pipeline, L=4.
__global__ __launch_bounds__(256) void k_gemm_bf16_f32out(
    const unsigned short* __restrict__ A, const unsigned short* __restrict__ W,
    const float* __restrict__ bias, float* __restrict__ C,
    int M, int N, int K)
{
    __shared__ __align__(16) char lds[2 * 16384];

    const int nbx = gridDim.x;
    const int total = nbx * gridDim.y;
    const int d = blockIdx.x + nbx * blockIdx.y;
    const int logical = (d & 7) * (total >> 3) + (d >> 3);
    const int bcol = (logical % nbx) * 128;
    const int brow = (logical / nbx) * 128;

    const int tid = threadIdx.x;
    const int ln  = tid & 63;
    const int wid = tid >> 6;
    const int wm  = wid >> 1, wn = wid & 1;
    const int fr  = ln & 15, fs = ln >> 4;
    const int srow = tid >> 2;
    const int sslt = tid & 3;

    const int kk0 = (sslt ^ swz(srow)) << 3;
    const size_t offA0 = (size_t)(brow + srow) * K + kk0;
    const size_t offW0 = (size_t)(bcol + srow) * K + kk0;

    auto stage = [&](char* base, int k0) {
        gload_lds16(A + offA0 + k0,          base + wid * 1024);
        gload_lds16(A + offA0 + 64 * K + k0, base + 4096 + wid * 1024);
        gload_lds16(W + offW0 + k0,          base + 8192 + wid * 1024);
        gload_lds16(W + offW0 + 64 * K + k0, base + 12288 + wid * 1024);
    };

    f32x4 acc[4][4] = {};

    stage(lds, 0);
    stage(lds + 16384, 32);

    const int NT = K / 32;
    for (int t = 0; t < NT; ++t) {
        if (t < NT - 1) { WAIT_VM4; } else { WAIT_VM0; }
        __builtin_amdgcn_s_barrier();

        char* base = lds + (t & 1) * 16384;
        short8 a[4], bfr[4];
#pragma unroll
        for (int mi = 0; mi < 4; ++mi) {
            int r = wm * 64 + mi * 16 + fr;
            a[mi] = *reinterpret_cast<const short8*>(base + r * 64 + ((fs ^ swz(r)) << 4));
        }
#pragma unroll
        for (int ni = 0; ni < 4; ++ni) {
            int c = wn * 64 + ni * 16 + fr;
            bfr[ni] = *reinterpret_cast<const short8*>(base + 8192 + c * 64 + ((fs ^ swz(c)) << 4));
        }
        __builtin_amdgcn_s_setprio(1);
#pragma unroll
        for (int mi = 0; mi < 4; ++mi)
#pragma unroll
            for (int ni = 0; ni < 4; ++ni)
                acc[mi][ni] = __builtin_amdgcn_mfma_f32_16x16x32_bf16(
                    a[mi], bfr[ni], acc[mi][ni], 0, 0, 0);
        __builtin_amdgcn_s_setprio(0);

        WAIT_LGKM0;
        __builtin_amdgcn_s_barrier();
        if (t + 2 < NT) stage(base, (t + 2) * 32);
    }

    float bv[4];
#pragma unroll
    for (int ni = 0; ni < 4; ++ni)
        bv[ni] = bias ? bias[bcol + wn * 64 + ni * 16 + fr] : 0.f;

#pragma unroll
    for (int mi = 0; mi < 4; ++mi) {
#pragma unroll
        for (int reg = 0; reg < 4; ++reg) {
            int row = brow + wm * 64 + mi * 16 + fs * 4 + reg;
#pragma unroll
            for (int ni = 0; ni < 4; ++ni) {
                int col = bcol + wn * 64 + ni * 16 + fr;
                C[(size_t)row * N + col] = acc[mi][ni][reg] + bv[ni];
            }
        }
    }
}

// ---------------------------------------------------------------------------
// Wave-per-row top-8 + softmax + mix. No barriers, no LDS.
__global__ __launch_bounds__(256) void k_topk_mix_wave(
    const float* __restrict__ logits, const float* __restrict__ Z,
    const int* __restrict__ qp, unsigned short* __restrict__ mix)
{
    const int ln  = threadIdx.x & 63;
    const int row = blockIdx.x * 4 + (threadIdx.x >> 6);   // (b*L + l)
    const int b   = row >> 11;                              // L = 2048
    const int start = qp[b], len = qp[b + 1] - start;

    const float* lrow = logits + (size_t)row * SMAX;

    float v[16];
#pragma unroll
    for (int c = 0; c < 4; ++c) {
        float4 q = reinterpret_cast<const float4*>(lrow)[c * 64 + ln];
        int s0 = c * 256 + ln * 4;
        v[c * 4 + 0] = (s0 + 0 < len) ? q.x : -INFINITY;
        v[c * 4 + 1] = (s0 + 1 < len) ? q.y : -INFINITY;
        v[c * 4 + 2] = (s0 + 2 < len) ? q.z : -INFINITY;
        v[c * 4 + 3] = (s0 + 3 < len) ? q.w : -INFINITY;
    }

    float wv[TOPK]; int wi[TOPK];
#pragma unroll
    for (int it = 0; it < TOPK; ++it) {
        float bvv = v[0]; int bj = 0;
#pragma unroll
        for (int j = 1; j < 16; ++j)
            if (v[j] > bvv) { bvv = v[j]; bj = j; }
        int gidx = (bj >> 2) * 256 + ln * 4 + (bj & 3);
        float cv = bvv; int ci = gidx;
#pragma unroll
        for (int off = 32; off > 0; off >>= 1) {
            float ov = __shfl_xor(cv, off);
            int   oi = __shfl_xor(ci, off);
            if (ov > cv || (ov == cv && oi < ci)) { cv = ov; ci = oi; }
        }
        wv[it] = cv; wi[it] = ci;
#pragma unroll
        for (int j = 0; j < 16; ++j) {
            int sj = (j >> 2) * 256 + ln * 4 + (j & 3);
            if (sj == ci) v[j] = -INFINITY;
        }
    }

    float m = wv[0], denom = 0.f;
    float g[TOPK];
#pragma unroll
    for (int k = 0; k < TOPK; ++k) { g[k] = expf(wv[k] - m); denom += g[k]; }
    float inv = 1.f / denom;

    float4 acc[4] = {{0,0,0,0},{0,0,0,0},{0,0,0,0},{0,0,0,0}};
#pragma unroll
    for (int k = 0; k < TOPK; ++k) {
        int si = wi[k] >= 0 ? wi[k] : 0;
        const float4* zr = reinterpret_cast<const float4*>(Z + (size_t)(start + si) * D_DIM);
        float wgt = g[k] * inv;
#pragma unroll
        for (int c = 0; c < 4; ++c) {
            float4 z = zr[c * 64 + ln];
            acc[c].x = fmaf(wgt, z.x, acc[c].x);
            acc[c].y = fmaf(wgt, z.y, acc[c].y);
            acc[c].z = fmaf(wgt, z.z, acc[c].z);
            acc[c].w = fmaf(wgt, z.w, acc[c].w);
        }
    }
    unsigned short* mrow = mix + (size_t)row * D_DIM;
#pragma unroll
    for (int c = 0; c < 4; ++c) {
        ushort4v o;
        o[0] = f2bf(acc[c].x); o[1] = f2bf(acc[c].y);
        o[2] = f2bf(acc[c].z); o[3] = f2bf(acc[c].w);
        *reinterpret_cast<ushort4v*>(mrow + (c * 64 + ln) * 4) = o;
    }
}

// ---------------------------------------------------------------------------
extern "C" void kernel_launch(void* const* d_in, const int* in_sizes, int n_in,
                              void* d_out, int out_size, void* d_ws, size_t ws_size,
                              hipStream_t stream) {
    const float* token_states = (const float*)d_in[0];
    const float* Z_sets       = (const float*)d_in[1];
    const float* desc_q       = (const float*)d_in[2];
    const int*   q_raw        = (const int*)d_in[3];
    const float* Wg_w  = (const float*)d_in[4];
    const float* Wg_b  = (const float*)d_in[5];
    const float* Wd_w  = (const float*)d_in[6];
    const float* Wd_b  = (const float*)d_in[7];
    const float* out_w = (const float*)d_in[8];
    const float* out_b = (const float*)d_in[9];
    float* out = (float*)d_out;

    const size_t NTOK = (size_t)BQ * LQ * D_DIM;
    const size_t NDES = (size_t)NQ * D_DIM;
    const size_t NW   = (size_t)D_DIM * D_DIM;

    char* ws = (char*)d_ws;
    int* qp = (int*)ws;
    unsigned short* tokenH = (unsigned short*)(ws + 256);
    unsigned short* tokenL = tokenH + NTOK;
    unsigned short* descH  = tokenL + NTOK;
    unsigned short* descL  = descH + NDES;
    unsigned short* wgH    = descL + NDES;
    unsigned short* wgL    = wgH + NW;
    unsigned short* wdH    = wgL + NW;
    unsigned short* wdL    = wdH + NW;
    unsigned short* owb    = wdL + NW;
    unsigned short* TprojH = owb + NW;
    unsigned short* TprojL = TprojH + NTOK;
    unsigned short* DprojH = TprojL + NTOK;
    unsigned short* DprojL = DprojH + NDES;
    float* logit          = (float*)tokenH;   // alias: token planes dead after proj GEMM
    unsigned short* mixb  = TprojH;           // alias: TprojH dead after logits GEMM

    // all conversions + qptrs in one launch: grid 6656
    k_cvt_all<<<6656, 256, 0, stream>>>(
        token_states, desc_q, Wg_w, Wd_w, out_w, q_raw,
        tokenH, tokenL, descH, descL, wgH, wgL, wdH, wdL, owb, qp);

    // fused Tproj+Dproj: grid (8, 80) = 640 blocks
    k_proj_split<<<dim3(8, 80), 256, 0, stream>>>(
        tokenH, tokenL, descH, descL, wgH, wgL, wdH, wdL,
        Wg_b, Wd_b, TprojH, TprojL, DprojH, DprojL);

    // logits (fp32, windowed): grid (16, 16, 4) = 1024 blocks
    k_logits_split<<<dim3(SMAX / 64, LQ / 128, BQ), 256, 0, stream>>>(
        TprojH, TprojL, DprojH, DprojL, qp, logit);

    // top-8 + softmax + Z mix (bf16)
    k_topk_mix_wave<<<(BQ * LQ) / 4, 256, 0, stream>>>(logit, Z_sets, qp, mixb);

    // out = mix @ out_w^T + b (fp32): grid (8, 64)
    k_gemm_bf16_f32out<<<dim3(D_DIM / 128, (BQ * LQ) / 128), 256, 0, stream>>>(
        mixb, owb, out_b, out, BQ * LQ, D_DIM, D_DIM);
}

// Round 9
// 188.496 us; speedup vs baseline: 1.3514x; 1.0231x over previous
//
#include <hip/hip_runtime.h>
#include <hip/hip_bf16.h>
#include <math.h>

#define BQ    4
#define LQ    2048
#define D_DIM 1024
#define NQ    2048
#define SMAX  1024
#define TOPK  8

typedef __attribute__((ext_vector_type(8))) short          short8;
typedef __attribute__((ext_vector_type(4))) float          f32x4;
typedef __attribute__((ext_vector_type(8))) unsigned short ushort8;
typedef __attribute__((ext_vector_type(4))) unsigned short ushort4v;

typedef __attribute__((address_space(3))) void as3_void;
typedef __attribute__((address_space(1))) void as1_void;

__device__ __forceinline__ void gload_lds16(const void* g, void* l) {
    __builtin_amdgcn_global_load_lds((const as1_void*)g, (as3_void*)l, 16, 0, 0);
}

__device__ __forceinline__ unsigned short f2bf(float f) {
    __hip_bfloat16 h = __float2bfloat16(f);
    return *reinterpret_cast<unsigned short*>(&h);
}
__device__ __forceinline__ float bf2f(unsigned short u) {
    unsigned int w = (unsigned int)u << 16;
    return *reinterpret_cast<float*>(&w);
}

// slot-XOR swizzle: conflict-free within each 8-consecutive-lane b128 group.
__device__ __forceinline__ int swz(int r) { return (r ^ (r >> 2)) & 3; }

#define WAIT_VM0   asm volatile("s_waitcnt vmcnt(0)" ::: "memory")
#define WAIT_VM4   asm volatile("s_waitcnt vmcnt(4)" ::: "memory")
#define WAIT_VM6   asm volatile("s_waitcnt vmcnt(6)" ::: "memory")
#define WAIT_VM8   asm volatile("s_waitcnt vmcnt(8)" ::: "memory")
#define WAIT_LGKM0 asm volatile("s_waitcnt lgkmcnt(0)" ::: "memory")

// ---------------------------------------------------------------------------
// One launch: all conversions + qptrs. Regions (2048 elems/block):
// [0,4096) token split | [4096,5120) desc split | [5120,5632) Wg split |
// [5632,6144) Wd split | [6144,6656) out_w plain | [6656,7680) Z plain.
__global__ __launch_bounds__(256) void k_cvt_all(
    const float* __restrict__ token_states, const float* __restrict__ desc_q,
    const float* __restrict__ Wg_w, const float* __restrict__ Wd_w,
    const float* __restrict__ out_w, const float* __restrict__ Z_sets,
    const int* __restrict__ q_raw,
    unsigned short* __restrict__ tokenH, unsigned short* __restrict__ tokenL,
    unsigned short* __restrict__ descH,  unsigned short* __restrict__ descL,
    unsigned short* __restrict__ wgH,    unsigned short* __restrict__ wgL,
    unsigned short* __restrict__ wdH,    unsigned short* __restrict__ wdL,
    unsigned short* __restrict__ owb,    unsigned short* __restrict__ Zb,
    int* __restrict__ qp)
{
    const int blk = blockIdx.x;
    if (blk == 0 && threadIdx.x == 0) {
        bool is64 = (q_raw[1] == 0);
        for (int i = 0; i <= BQ; ++i)
            qp[i] = is64 ? q_raw[2 * i] : q_raw[i];
    }

    const float* in; unsigned short *hi, *lo = nullptr; int local;
    if (blk < 4096)      { in = token_states; hi = tokenH; lo = tokenL; local = blk; }
    else if (blk < 5120) { in = desc_q; hi = descH; lo = descL; local = blk - 4096; }
    else if (blk < 5632) { in = Wg_w;   hi = wgH;   lo = wgL;   local = blk - 5120; }
    else if (blk < 6144) { in = Wd_w;   hi = wdH;   lo = wdL;   local = blk - 5632; }
    else if (blk < 6656) { in = out_w;  hi = owb;               local = blk - 6144; }
    else                 { in = Z_sets; hi = Zb;                local = blk - 6656; }

    int i = (local * 256 + threadIdx.x) * 8;
    float4 v0 = *reinterpret_cast<const float4*>(in + i);
    float4 v1 = *reinterpret_cast<const float4*>(in + i + 4);
    float x[8] = {v0.x, v0.y, v0.z, v0.w, v1.x, v1.y, v1.z, v1.w};
    ushort8 h8, l8;
#pragma unroll
    for (int k = 0; k < 8; ++k) {
        unsigned short h = f2bf(x[k]);
        h8[k] = h;
        l8[k] = f2bf(x[k] - bf2f(h));
    }
    *reinterpret_cast<ushort8*>(hi + i) = h8;
    if (lo) *reinterpret_cast<ushort8*>(lo + i) = l8;
}

// ---------------------------------------------------------------------------
// Split-bf16 GEMM (3-MFMA fp32 emulation), BM=128 x BN=128, BK=32,
// counted-vmcnt 2-deep pipeline, setprio. One GEMM per launch (unfused).
__global__ __launch_bounds__(256) void k_gemm_split(
    const unsigned short* __restrict__ Ah, const unsigned short* __restrict__ Al,
    const unsigned short* __restrict__ Wh, const unsigned short* __restrict__ Wl,
    const float* __restrict__ bias,
    unsigned short* __restrict__ Ch, unsigned short* __restrict__ Cl,
    int M, int N, int K)
{
    __shared__ __align__(16) char lds[2 * 32768];

    const int nbx = gridDim.x;
    const int total = nbx * gridDim.y;
    const int d = blockIdx.x + nbx * blockIdx.y;
    const int logical = (d & 7) * (total >> 3) + (d >> 3);
    const int bcol = (logical % nbx) * 128;
    const int brow = (logical / nbx) * 128;

    const int tid = threadIdx.x;
    const int ln  = tid & 63;
    const int wid = tid >> 6;
    const int wm  = wid >> 1, wn = wid & 1;
    const int fr  = ln & 15, fs = ln >> 4;
    const int srow = tid >> 2;
    const int sslt = tid & 3;

    const int kk0 = (sslt ^ swz(srow)) << 3;
    const size_t offA0 = (size_t)(brow + srow) * K + kk0;
    const size_t offW0 = (size_t)(bcol + srow) * K + kk0;

    auto stage = [&](char* base, int k0) {
        gload_lds16(Ah + offA0 + k0,          base + wid * 1024);
        gload_lds16(Ah + offA0 + 64 * K + k0, base + 4096 + wid * 1024);
        gload_lds16(Al + offA0 + k0,          base + 8192 + wid * 1024);
        gload_lds16(Al + offA0 + 64 * K + k0, base + 12288 + wid * 1024);
        gload_lds16(Wh + offW0 + k0,          base + 16384 + wid * 1024);
        gload_lds16(Wh + offW0 + 64 * K + k0, base + 20480 + wid * 1024);
        gload_lds16(Wl + offW0 + k0,          base + 24576 + wid * 1024);
        gload_lds16(Wl + offW0 + 64 * K + k0, base + 28672 + wid * 1024);
    };

    f32x4 acc[4][4] = {};

    stage(lds, 0);
    stage(lds + 32768, 32);

    const int NT = K / 32;
    for (int t = 0; t < NT; ++t) {
        if (t < NT - 1) { WAIT_VM8; } else { WAIT_VM0; }
        __builtin_amdgcn_s_barrier();

        char* base = lds + (t & 1) * 32768;
        short8 ahf[4], alf[4], bhf[4], blf[4];
#pragma unroll
        for (int mi = 0; mi < 4; ++mi) {
            int r = wm * 64 + mi * 16 + fr;
            int o = r * 64 + ((fs ^ swz(r)) << 4);
            ahf[mi] = *reinterpret_cast<const short8*>(base + o);
            alf[mi] = *reinterpret_cast<const short8*>(base + 8192 + o);
        }
#pragma unroll
        for (int ni = 0; ni < 4; ++ni) {
            int c = wn * 64 + ni * 16 + fr;
            int o = c * 64 + ((fs ^ swz(c)) << 4);
            bhf[ni] = *reinterpret_cast<const short8*>(base + 16384 + o);
            blf[ni] = *reinterpret_cast<const short8*>(base + 24576 + o);
        }
        __builtin_amdgcn_s_setprio(1);
#pragma unroll
        for (int mi = 0; mi < 4; ++mi)
#pragma unroll
            for (int ni = 0; ni < 4; ++ni)
                acc[mi][ni] = __builtin_amdgcn_mfma_f32_16x16x32_bf16(
                    ahf[mi], bhf[ni], acc[mi][ni], 0, 0, 0);
#pragma unroll
        for (int mi = 0; mi < 4; ++mi)
#pragma unroll
            for (int ni = 0; ni < 4; ++ni)
                acc[mi][ni] = __builtin_amdgcn_mfma_f32_16x16x32_bf16(
                    ahf[mi], blf[ni], acc[mi][ni], 0, 0, 0);
#pragma unroll
        for (int mi = 0; mi < 4; ++mi)
#pragma unroll
            for (int ni = 0; ni < 4; ++ni)
                acc[mi][ni] = __builtin_amdgcn_mfma_f32_16x16x32_bf16(
                    alf[mi], bhf[ni], acc[mi][ni], 0, 0, 0);
        __builtin_amdgcn_s_setprio(0);

        WAIT_LGKM0;
        __builtin_amdgcn_s_barrier();
        if (t + 2 < NT) stage(base, (t + 2) * 32);
    }

    float bv[4];
#pragma unroll
    for (int ni = 0; ni < 4; ++ni)
        bv[ni] = bias[bcol + wn * 64 + ni * 16 + fr];

#pragma unroll
    for (int mi = 0; mi < 4; ++mi) {
#pragma unroll
        for (int reg = 0; reg < 4; ++reg) {
            int row = brow + wm * 64 + mi * 16 + fs * 4 + reg;
#pragma unroll
            for (int ni = 0; ni < 4; ++ni) {
                int col = bcol + wn * 64 + ni * 16 + fr;
                float v = acc[mi][ni][reg] + bv[ni];
                unsigned short h = f2bf(v);
                Ch[(size_t)row * N + col] = h;
                Cl[(size_t)row * N + col] = f2bf(v - bf2f(h));
            }
        }
    }
}

// ---------------------------------------------------------------------------
// Windowed split-bf16 logits, BM=128 x BN=64, counted-vmcnt pipeline (L=6).
__global__ __launch_bounds__(256) void k_logits_split(
    const unsigned short* __restrict__ Th, const unsigned short* __restrict__ Tl,
    const unsigned short* __restrict__ Dh, const unsigned short* __restrict__ Dl,
    const int* __restrict__ qp, float* __restrict__ logits)
{
    const int d = blockIdx.x + 16 * (blockIdx.y + 16 * blockIdx.z);
    const int logical = (d & 7) * 128 + (d >> 3);
    const int b    = logical >> 8;
    const int brow = ((logical >> 4) & 15) * 128;
    const int bcol = (logical & 15) * 64;

    const int start = qp[b], len = qp[b + 1] - start;
    if (bcol >= len) return;            // block-uniform: barrier-safe

    __shared__ __align__(16) char lds[2 * 24576];

    const int tid = threadIdx.x;
    const int ln  = tid & 63;
    const int wid = tid >> 6;
    const int fr  = ln & 15, fs = ln >> 4;
    const int srow = tid >> 2;
    const int sslt = tid & 3;

    const int kka = (sslt ^ swz(srow)) << 3;
    const size_t offA0 = ((size_t)b * LQ + brow + srow) * D_DIM + kka;
    int wr = start + bcol + srow; if (wr > NQ - 1) wr = NQ - 1;
    const size_t offW0 = (size_t)wr * D_DIM + kka;

    auto stage = [&](char* base, int k0) {
        gload_lds16(Th + offA0 + k0,              base + wid * 1024);
        gload_lds16(Th + offA0 + 64 * D_DIM + k0, base + 4096 + wid * 1024);
        gload_lds16(Tl + offA0 + k0,              base + 8192 + wid * 1024);
        gload_lds16(Tl + offA0 + 64 * D_DIM + k0, base + 12288 + wid * 1024);
        gload_lds16(Dh + offW0 + k0,              base + 16384 + wid * 1024);
        gload_lds16(Dl + offW0 + k0,              base + 20480 + wid * 1024);
    };

    f32x4 acc[2][4] = {};

    stage(lds, 0);
    stage(lds + 24576, 32);

    const int NT = D_DIM / 32;
    for (int t = 0; t < NT; ++t) {
        if (t < NT - 1) { WAIT_VM6; } else { WAIT_VM0; }
        __builtin_amdgcn_s_barrier();

        char* base = lds + (t & 1) * 24576;
        short8 ah[2], al[2], bh[4], bl[4];
#pragma unroll
        for (int mi = 0; mi < 2; ++mi) {
            int r = wid * 32 + mi * 16 + fr;
            int o = r * 64 + ((fs ^ swz(r)) << 4);
            ah[mi] = *reinterpret_cast<const short8*>(base + o);
            al[mi] = *reinterpret_cast<const short8*>(base + 8192 + o);
        }
#pragma unroll
        for (int ni = 0; ni < 4; ++ni) {
            int c = ni * 16 + fr;
            int o = c * 64 + ((fs ^ swz(c)) << 4);
            bh[ni] = *reinterpret_cast<const short8*>(base + 16384 + o);
            bl[ni] = *reinterpret_cast<const short8*>(base + 20480 + o);
        }
        __builtin_amdgcn_s_setprio(1);
#pragma unroll
        for (int mi = 0; mi < 2; ++mi)
#pragma unroll
            for (int ni = 0; ni < 4; ++ni)
                acc[mi][ni] = __builtin_amdgcn_mfma_f32_16x16x32_bf16(
                    ah[mi], bh[ni], acc[mi][ni], 0, 0, 0);
#pragma unroll
        for (int mi = 0; mi < 2; ++mi)
#pragma unroll
            for (int ni = 0; ni < 4; ++ni)
                acc[mi][ni] = __builtin_amdgcn_mfma_f32_16x16x32_bf16(
                    ah[mi], bl[ni], acc[mi][ni], 0, 0, 0);
#pragma unroll
        for (int mi = 0; mi < 2; ++mi)
#pragma unroll
            for (int ni = 0; ni < 4; ++ni)
                acc[mi][ni] = __builtin_amdgcn_mfma_f32_16x16x32_bf16(
                    al[mi], bh[ni], acc[mi][ni], 0, 0, 0);
        __builtin_amdgcn_s_setprio(0);

        WAIT_LGKM0;
        __builtin_amdgcn_s_barrier();
        if (t + 2 < NT) stage(base, (t + 2) * 32);
    }

#pragma unroll
    for (int mi = 0; mi < 2; ++mi) {
#pragma unroll
        for (int reg = 0; reg < 4; ++reg) {
            size_t row = (size_t)b * LQ + brow + wid * 32 + mi * 16 + fs * 4 + reg;
#pragma unroll
            for (int ni = 0; ni < 4; ++ni) {
                int col = bcol + ni * 16 + fr;
                logits[row * SMAX + col] = acc[mi][ni][reg];
            }
        }
    }
}

// ---------------------------------------------------------------------------
// Plain bf16 GEMM, bf16 out, no bias: ZW = Z @ out_w^T.
// BM=128 x BN=128, counted-vmcnt pipeline, L=4.
__global__ __launch_bounds__(256) void k_gemm_bf16_bf16out(
    const unsigned short* __restrict__ A, const unsigned short* __restrict__ W,
    unsigned short* __restrict__ C, int M, int N, int K)
{
    __shared__ __align__(16) char lds[2 * 16384];

    const int nbx = gridDim.x;
    const int total = nbx * gridDim.y;
    const int d = blockIdx.x + nbx * blockIdx.y;
    const int logical = (d & 7) * (total >> 3) + (d >> 3);
    const int bcol = (logical % nbx) * 128;
    const int brow = (logical / nbx) * 128;

    const int tid = threadIdx.x;
    const int ln  = tid & 63;
    const int wid = tid >> 6;
    const int wm  = wid >> 1, wn = wid & 1;
    const int fr  = ln & 15, fs = ln >> 4;
    const int srow = tid >> 2;
    const int sslt = tid & 3;

    const int kk0 = (sslt ^ swz(srow)) << 3;
    const size_t offA0 = (size_t)(brow + srow) * K + kk0;
    const size_t offW0 = (size_t)(bcol + srow) * K + kk0;

    auto stage = [&](char* base, int k0) {
        gload_lds16(A + offA0 + k0,          base + wid * 1024);
        gload_lds16(A + offA0 + 64 * K + k0, base + 4096 + wid * 1024);
        gload_lds16(W + offW0 + k0,          base + 8192 + wid * 1024);
        gload_lds16(W + offW0 + 64 * K + k0, base + 12288 + wid * 1024);
    };

    f32x4 acc[4][4] = {};

    stage(lds, 0);
    stage(lds + 16384, 32);

    const int NT = K / 32;
    for (int t = 0; t < NT; ++t) {
        if (t < NT - 1) { WAIT_VM4; } else { WAIT_VM0; }
        __builtin_amdgcn_s_barrier();

        char* base = lds + (t & 1) * 16384;
        short8 a[4], bfr[4];
#pragma unroll
        for (int mi = 0; mi < 4; ++mi) {
            int r = wm * 64 + mi * 16 + fr;
            a[mi] = *reinterpret_cast<const short8*>(base + r * 64 + ((fs ^ swz(r)) << 4));
        }
#pragma unroll
        for (int ni = 0; ni < 4; ++ni) {
            int c = wn * 64 + ni * 16 + fr;
            bfr[ni] = *reinterpret_cast<const short8*>(base + 8192 + c * 64 + ((fs ^ swz(c)) << 4));
        }
        __builtin_amdgcn_s_setprio(1);
#pragma unroll
        for (int mi = 0; mi < 4; ++mi)
#pragma unroll
            for (int ni = 0; ni < 4; ++ni)
                acc[mi][ni] = __builtin_amdgcn_mfma_f32_16x16x32_bf16(
                    a[mi], bfr[ni], acc[mi][ni], 0, 0, 0);
        __builtin_amdgcn_s_setprio(0);

        WAIT_LGKM0;
        __builtin_amdgcn_s_barrier();
        if (t + 2 < NT) stage(base, (t + 2) * 32);
    }

#pragma unroll
    for (int mi = 0; mi < 4; ++mi) {
#pragma unroll
        for (int reg = 0; reg < 4; ++reg) {
            int row = brow + wm * 64 + mi * 16 + fs * 4 + reg;
#pragma unroll
            for (int ni = 0; ni < 4; ++ni) {
                int col = bcol + wn * 64 + ni * 16 + fr;
                C[(size_t)row * N + col] = f2bf(acc[mi][ni][reg]);
            }
        }
    }
}

// ---------------------------------------------------------------------------
// Wave-per-row top-8 + softmax + gather of PRE-PROJECTED ZW rows + out_b,
// writing final output fp32 directly (out-GEMM eliminated by linearity).
__global__ __launch_bounds__(256) void k_topk_out(
    const float* __restrict__ logits, const unsigned short* __restrict__ ZW,
    const float* __restrict__ out_b, const int* __restrict__ qp,
    float* __restrict__ out)
{
    const int ln  = threadIdx.x & 63;
    const int row = blockIdx.x * 4 + (threadIdx.x >> 6);   // (b*L + l)
    const int b   = row >> 11;                              // L = 2048
    const int start = qp[b], len = qp[b + 1] - start;

    const float* lrow = logits + (size_t)row * SMAX;

    float v[16];
#pragma unroll
    for (int c = 0; c < 4; ++c) {
        float4 q = reinterpret_cast<const float4*>(lrow)[c * 64 + ln];
        int s0 = c * 256 + ln * 4;
        v[c * 4 + 0] = (s0 + 0 < len) ? q.x : -INFINITY;
        v[c * 4 + 1] = (s0 + 1 < len) ? q.y : -INFINITY;
        v[c * 4 + 2] = (s0 + 2 < len) ? q.z : -INFINITY;
        v[c * 4 + 3] = (s0 + 3 < len) ? q.w : -INFINITY;
    }

    float wv[TOPK]; int wi[TOPK];
#pragma unroll
    for (int it = 0; it < TOPK; ++it) {
        float bvv = v[0]; int bj = 0;
#pragma unroll
        for (int j = 1; j < 16; ++j)
            if (v[j] > bvv) { bvv = v[j]; bj = j; }
        int gidx = (bj >> 2) * 256 + ln * 4 + (bj & 3);
        float cv = bvv; int ci = gidx;
#pragma unroll
        for (int off = 32; off > 0; off >>= 1) {
            float ov = __shfl_xor(cv, off);
            int   oi = __shfl_xor(ci, off);
            if (ov > cv || (ov == cv && oi < ci)) { cv = ov; ci = oi; }
        }
        wv[it] = cv; wi[it] = ci;
#pragma unroll
        for (int j = 0; j < 16; ++j) {
            int sj = (j >> 2) * 256 + ln * 4 + (j & 3);
            if (sj == ci) v[j] = -INFINITY;
        }
    }

    float m = wv[0], denom = 0.f;
    float g[TOPK];
#pragma unroll
    for (int k = 0; k < TOPK; ++k) { g[k] = expf(wv[k] - m); denom += g[k]; }
    float inv = 1.f / denom;

    // acc initialized with out_b
    float4 acc[4];
#pragma unroll
    for (int c = 0; c < 4; ++c)
        acc[c] = reinterpret_cast<const float4*>(out_b)[c * 64 + ln];

#pragma unroll
    for (int k = 0; k < TOPK; ++k) {
        int si = wi[k] >= 0 ? wi[k] : 0;
        const ushort4v* zr = reinterpret_cast<const ushort4v*>(
            ZW + (size_t)(start + si) * D_DIM);
        float wgt = g[k] * inv;
#pragma unroll
        for (int c = 0; c < 4; ++c) {
            ushort4v z = zr[c * 64 + ln];
            acc[c].x = fmaf(wgt, bf2f(z[0]), acc[c].x);
            acc[c].y = fmaf(wgt, bf2f(z[1]), acc[c].y);
            acc[c].z = fmaf(wgt, bf2f(z[2]), acc[c].z);
            acc[c].w = fmaf(wgt, bf2f(z[3]), acc[c].w);
        }
    }
    float* orow = out + (size_t)row * D_DIM;
#pragma unroll
    for (int c = 0; c < 4; ++c)
        reinterpret_cast<float4*>(orow)[c * 64 + ln] = acc[c];
}

// ---------------------------------------------------------------------------
extern "C" void kernel_launch(void* const* d_in, const int* in_sizes, int n_in,
                              void* d_out, int out_size, void* d_ws, size_t ws_size,
                              hipStream_t stream) {
    const float* token_states = (const float*)d_in[0];
    const float* Z_sets       = (const float*)d_in[1];
    const float* desc_q       = (const float*)d_in[2];
    const int*   q_raw        = (const int*)d_in[3];
    const float* Wg_w  = (const float*)d_in[4];
    const float* Wg_b  = (const float*)d_in[5];
    const float* Wd_w  = (const float*)d_in[6];
    const float* Wd_b  = (const float*)d_in[7];
    const float* out_w = (const float*)d_in[8];
    const float* out_b = (const float*)d_in[9];
    float* out = (float*)d_out;

    const size_t NTOK = (size_t)BQ * LQ * D_DIM;   // 8388608
    const size_t NDES = (size_t)NQ * D_DIM;        // 2097152
    const size_t NW   = (size_t)D_DIM * D_DIM;     // 1048576

    char* ws = (char*)d_ws;
    int* qp = (int*)ws;
    unsigned short* tokenH = (unsigned short*)(ws + 256);
    unsigned short* tokenL = tokenH + NTOK;
    unsigned short* descH  = tokenL + NTOK;
    unsigned short* descL  = descH + NDES;
    unsigned short* wgH    = descL + NDES;
    unsigned short* wgL    = wgH + NW;
    unsigned short* wdH    = wgL + NW;
    unsigned short* wdL    = wdH + NW;
    unsigned short* owb    = wdL + NW;
    unsigned short* TprojH = owb + NW;
    unsigned short* TprojL = TprojH + NTOK;
    unsigned short* DprojH = TprojL + NTOK;
    unsigned short* DprojL = DprojH + NDES;
    unsigned short* Zb     = DprojL + NDES;        // [2048][1024] bf16
    unsigned short* ZWb    = Zb + NDES;            // [2048][1024] bf16
    float* logit          = (float*)tokenH;        // alias: token planes dead after proj GEMMs

    // all conversions + qptrs in one launch: grid 7680
    k_cvt_all<<<7680, 256, 0, stream>>>(
        token_states, desc_q, Wg_w, Wd_w, out_w, Z_sets, q_raw,
        tokenH, tokenL, descH, descL, wgH, wgL, wdH, wdL, owb, Zb, qp);

    // Tproj = token @ Wg^T + b (split out): grid (8,64) = 512 = exactly 2/CU
    k_gemm_split<<<dim3(8, 64), 256, 0, stream>>>(
        tokenH, tokenL, wgH, wgL, Wg_b, TprojH, TprojL, BQ * LQ, D_DIM, D_DIM);

    // Dproj = desc @ Wd^T + b (split out): grid (8,16) = 128
    k_gemm_split<<<dim3(8, 16), 256, 0, stream>>>(
        descH, descL, wdH, wdL, Wd_b, DprojH, DprojL, NQ, D_DIM, D_DIM);

    // ZW = Z @ out_w^T (bf16, no bias): grid (8,16) = 128
    k_gemm_bf16_bf16out<<<dim3(8, 16), 256, 0, stream>>>(
        Zb, owb, ZWb, NQ, D_DIM, D_DIM);

    // logits (fp32, windowed): grid (16,16,4) = 1024 blocks
    k_logits_split<<<dim3(SMAX / 64, LQ / 128, BQ), 256, 0, stream>>>(
        TprojH, TprojL, DprojH, DprojL, qp, logit);

    // top-8 + softmax + ZW gather + bias -> final output
    k_topk_out<<<(BQ * LQ) / 4, 256, 0, stream>>>(logit, ZWb, out_b, qp, out);
}

// Round 11
// 174.106 us; speedup vs baseline: 1.4631x; 1.0826x over previous
//
#include <hip/hip_runtime.h>
#include <hip/hip_bf16.h>
#include <math.h>

#define BQ    4
#define LQ    2048
#define D_DIM 1024
#define NQ    2048
#define SMAX  1024
#define TOPK  8

typedef __attribute__((ext_vector_type(8))) short          short8;
typedef __attribute__((ext_vector_type(4))) float          f32x4;
typedef __attribute__((ext_vector_type(8))) unsigned short ushort8;
typedef __attribute__((ext_vector_type(4))) unsigned short ushort4v;

typedef __attribute__((address_space(3))) void as3_void;
typedef __attribute__((address_space(1))) void as1_void;

__device__ __forceinline__ void gload_lds16(const void* g, void* l) {
    __builtin_amdgcn_global_load_lds((const as1_void*)g, (as3_void*)l, 16, 0, 0);
}

__device__ __forceinline__ unsigned short f2bf(float f) {
    __hip_bfloat16 h = __float2bfloat16(f);
    return *reinterpret_cast<unsigned short*>(&h);
}
__device__ __forceinline__ float bf2f(unsigned short u) {
    unsigned int w = (unsigned int)u << 16;
    return *reinterpret_cast<float*>(&w);
}

// slot-XOR swizzle: conflict-free within each 8-consecutive-lane b128 group.
__device__ __forceinline__ int swz(int r) { return (r ^ (r >> 2)) & 3; }

#define WAIT_VM0   asm volatile("s_waitcnt vmcnt(0)" ::: "memory")
#define WAIT_VM4   asm volatile("s_waitcnt vmcnt(4)" ::: "memory")
#define WAIT_VM6   asm volatile("s_waitcnt vmcnt(6)" ::: "memory")
#define WAIT_VM8   asm volatile("s_waitcnt vmcnt(8)" ::: "memory")
#define WAIT_LGKM0 asm volatile("s_waitcnt lgkmcnt(0)" ::: "memory")

// ---------------------------------------------------------------------------
// One launch: all conversions + qptrs. Regions (2048 elems/block):
// [0,4096) token split | [4096,5120) desc split | [5120,5632) Wg split |
// [5632,6144) Wd split | [6144,6656) out_w plain | [6656,7680) Z plain.
__global__ __launch_bounds__(256) void k_cvt_all(
    const float* __restrict__ token_states, const float* __restrict__ desc_q,
    const float* __restrict__ Wg_w, const float* __restrict__ Wd_w,
    const float* __restrict__ out_w, const float* __restrict__ Z_sets,
    const int* __restrict__ q_raw,
    unsigned short* __restrict__ tokenH, unsigned short* __restrict__ tokenL,
    unsigned short* __restrict__ descH,  unsigned short* __restrict__ descL,
    unsigned short* __restrict__ wgH,    unsigned short* __restrict__ wgL,
    unsigned short* __restrict__ wdH,    unsigned short* __restrict__ wdL,
    unsigned short* __restrict__ owb,    unsigned short* __restrict__ Zb,
    int* __restrict__ qp)
{
    const int blk = blockIdx.x;
    if (blk == 0 && threadIdx.x == 0) {
        bool is64 = (q_raw[1] == 0);
        for (int i = 0; i <= BQ; ++i)
            qp[i] = is64 ? q_raw[2 * i] : q_raw[i];
    }

    const float* in; unsigned short *hi, *lo = nullptr; int local;
    if (blk < 4096)      { in = token_states; hi = tokenH; lo = tokenL; local = blk; }
    else if (blk < 5120) { in = desc_q; hi = descH; lo = descL; local = blk - 4096; }
    else if (blk < 5632) { in = Wg_w;   hi = wgH;   lo = wgL;   local = blk - 5120; }
    else if (blk < 6144) { in = Wd_w;   hi = wdH;   lo = wdL;   local = blk - 5632; }
    else if (blk < 6656) { in = out_w;  hi = owb;               local = blk - 6144; }
    else                 { in = Z_sets; hi = Zb;                local = blk - 6656; }

    int i = (local * 256 + threadIdx.x) * 8;
    float4 v0 = *reinterpret_cast<const float4*>(in + i);
    float4 v1 = *reinterpret_cast<const float4*>(in + i + 4);
    float x[8] = {v0.x, v0.y, v0.z, v0.w, v1.x, v1.y, v1.z, v1.w};
    ushort8 h8, l8;
#pragma unroll
    for (int k = 0; k < 8; ++k) {
        unsigned short h = f2bf(x[k]);
        h8[k] = h;
        l8[k] = f2bf(x[k] - bf2f(h));
    }
    *reinterpret_cast<ushort8*>(hi + i) = h8;
    if (lo) *reinterpret_cast<ushort8*>(lo + i) = l8;
}

// ---------------------------------------------------------------------------
// Split-bf16 GEMM (3-MFMA fp32 emulation), BM=128 x BN=128, BK=32,
// counted-vmcnt 2-deep pipeline, setprio. Split bf16 hi/lo output planes.
__global__ __launch_bounds__(256) void k_gemm_split(
    const unsigned short* __restrict__ Ah, const unsigned short* __restrict__ Al,
    const unsigned short* __restrict__ Wh, const unsigned short* __restrict__ Wl,
    const float* __restrict__ bias,
    unsigned short* __restrict__ Ch, unsigned short* __restrict__ Cl,
    int M, int N, int K)
{
    __shared__ __align__(16) char lds[2 * 32768];

    const int nbx = gridDim.x;
    const int total = nbx * gridDim.y;
    const int d = blockIdx.x + nbx * blockIdx.y;
    const int logical = (d & 7) * (total >> 3) + (d >> 3);
    const int bcol = (logical % nbx) * 128;
    const int brow = (logical / nbx) * 128;

    const int tid = threadIdx.x;
    const int ln  = tid & 63;
    const int wid = tid >> 6;
    const int wm  = wid >> 1, wn = wid & 1;
    const int fr  = ln & 15, fs = ln >> 4;
    const int srow = tid >> 2;
    const int sslt = tid & 3;

    const int kk0 = (sslt ^ swz(srow)) << 3;
    const size_t offA0 = (size_t)(brow + srow) * K + kk0;
    const size_t offW0 = (size_t)(bcol + srow) * K + kk0;

    auto stage = [&](char* base, int k0) {
        gload_lds16(Ah + offA0 + k0,          base + wid * 1024);
        gload_lds16(Ah + offA0 + 64 * K + k0, base + 4096 + wid * 1024);
        gload_lds16(Al + offA0 + k0,          base + 8192 + wid * 1024);
        gload_lds16(Al + offA0 + 64 * K + k0, base + 12288 + wid * 1024);
        gload_lds16(Wh + offW0 + k0,          base + 16384 + wid * 1024);
        gload_lds16(Wh + offW0 + 64 * K + k0, base + 20480 + wid * 1024);
        gload_lds16(Wl + offW0 + k0,          base + 24576 + wid * 1024);
        gload_lds16(Wl + offW0 + 64 * K + k0, base + 28672 + wid * 1024);
    };

    f32x4 acc[4][4] = {};

    stage(lds, 0);
    stage(lds + 32768, 32);

    const int NT = K / 32;
    for (int t = 0; t < NT; ++t) {
        if (t < NT - 1) { WAIT_VM8; } else { WAIT_VM0; }
        __builtin_amdgcn_s_barrier();

        char* base = lds + (t & 1) * 32768;
        short8 ahf[4], alf[4], bhf[4], blf[4];
#pragma unroll
        for (int mi = 0; mi < 4; ++mi) {
            int r = wm * 64 + mi * 16 + fr;
            int o = r * 64 + ((fs ^ swz(r)) << 4);
            ahf[mi] = *reinterpret_cast<const short8*>(base + o);
            alf[mi] = *reinterpret_cast<const short8*>(base + 8192 + o);
        }
#pragma unroll
        for (int ni = 0; ni < 4; ++ni) {
            int c = wn * 64 + ni * 16 + fr;
            int o = c * 64 + ((fs ^ swz(c)) << 4);
            bhf[ni] = *reinterpret_cast<const short8*>(base + 16384 + o);
            blf[ni] = *reinterpret_cast<const short8*>(base + 24576 + o);
        }
        __builtin_amdgcn_s_setprio(1);
#pragma unroll
        for (int mi = 0; mi < 4; ++mi)
#pragma unroll
            for (int ni = 0; ni < 4; ++ni)
                acc[mi][ni] = __builtin_amdgcn_mfma_f32_16x16x32_bf16(
                    ahf[mi], bhf[ni], acc[mi][ni], 0, 0, 0);
#pragma unroll
        for (int mi = 0; mi < 4; ++mi)
#pragma unroll
            for (int ni = 0; ni < 4; ++ni)
                acc[mi][ni] = __builtin_amdgcn_mfma_f32_16x16x32_bf16(
                    ahf[mi], blf[ni], acc[mi][ni], 0, 0, 0);
#pragma unroll
        for (int mi = 0; mi < 4; ++mi)
#pragma unroll
            for (int ni = 0; ni < 4; ++ni)
                acc[mi][ni] = __builtin_amdgcn_mfma_f32_16x16x32_bf16(
                    alf[mi], bhf[ni], acc[mi][ni], 0, 0, 0);
        __builtin_amdgcn_s_setprio(0);

        WAIT_LGKM0;
        __builtin_amdgcn_s_barrier();
        if (t + 2 < NT) stage(base, (t + 2) * 32);
    }

    float bv[4];
#pragma unroll
    for (int ni = 0; ni < 4; ++ni)
        bv[ni] = bias[bcol + wn * 64 + ni * 16 + fr];

#pragma unroll
    for (int mi = 0; mi < 4; ++mi) {
#pragma unroll
        for (int reg = 0; reg < 4; ++reg) {
            int row = brow + wm * 64 + mi * 16 + fs * 4 + reg;
#pragma unroll
            for (int ni = 0; ni < 4; ++ni) {
                int col = bcol + wn * 64 + ni * 16 + fr;
                float v = acc[mi][ni][reg] + bv[ni];
                unsigned short h = f2bf(v);
                Ch[(size_t)row * N + col] = h;
                Cl[(size_t)row * N + col] = f2bf(v - bf2f(h));
            }
        }
    }
}

// ---------------------------------------------------------------------------
// Merged Dproj (split-bf16 3-pass, split-bf16 out) + ZW (plain bf16) launch.
// 256 blocks: even d -> Dproj tile, odd d -> ZW tile (both 16x8 tile grids).
// Co-run across CUs instead of serializing as two <= half-machine launches.
__global__ __launch_bounds__(256) void k_dzw(
    const unsigned short* __restrict__ descH, const unsigned short* __restrict__ descL,
    const unsigned short* __restrict__ wdH,   const unsigned short* __restrict__ wdL,
    const float* __restrict__ Wd_b,
    unsigned short* __restrict__ DprojH, unsigned short* __restrict__ DprojL,
    const unsigned short* __restrict__ Zb, const unsigned short* __restrict__ owb,
    unsigned short* __restrict__ ZWb)
{
    constexpr int K = D_DIM, N = D_DIM;
    __shared__ __align__(16) char lds[2 * 32768];

    const int d = blockIdx.x;
    const int sub = d >> 1;
    const int bcol = (sub & 7) * 128;
    const int brow = (sub >> 3) * 128;

    const int tid = threadIdx.x;
    const int ln  = tid & 63;
    const int wid = tid >> 6;
    const int wm  = wid >> 1, wn = wid & 1;
    const int fr  = ln & 15, fs = ln >> 4;
    const int srow = tid >> 2;
    const int sslt = tid & 3;

    const int kk0 = (sslt ^ swz(srow)) << 3;
    const size_t offA0 = (size_t)(brow + srow) * K + kk0;
    const size_t offW0 = (size_t)(bcol + srow) * K + kk0;

    if ((d & 1) == 0) {
        // ---- Dproj: split 3-pass, split-bf16 out ----
        auto stage = [&](char* base, int k0) {
            gload_lds16(descH + offA0 + k0,          base + wid * 1024);
            gload_lds16(descH + offA0 + 64 * K + k0, base + 4096 + wid * 1024);
            gload_lds16(descL + offA0 + k0,          base + 8192 + wid * 1024);
            gload_lds16(descL + offA0 + 64 * K + k0, base + 12288 + wid * 1024);
            gload_lds16(wdH + offW0 + k0,            base + 16384 + wid * 1024);
            gload_lds16(wdH + offW0 + 64 * K + k0,   base + 20480 + wid * 1024);
            gload_lds16(wdL + offW0 + k0,            base + 24576 + wid * 1024);
            gload_lds16(wdL + offW0 + 64 * K + k0,   base + 28672 + wid * 1024);
        };

        f32x4 acc[4][4] = {};
        stage(lds, 0);
        stage(lds + 32768, 32);

        const int NT = K / 32;
        for (int t = 0; t < NT; ++t) {
            if (t < NT - 1) { WAIT_VM8; } else { WAIT_VM0; }
            __builtin_amdgcn_s_barrier();

            char* base = lds + (t & 1) * 32768;
            short8 ahf[4], alf[4], bhf[4], blf[4];
#pragma unroll
            for (int mi = 0; mi < 4; ++mi) {
                int r = wm * 64 + mi * 16 + fr;
                int o = r * 64 + ((fs ^ swz(r)) << 4);
                ahf[mi] = *reinterpret_cast<const short8*>(base + o);
                alf[mi] = *reinterpret_cast<const short8*>(base + 8192 + o);
            }
#pragma unroll
            for (int ni = 0; ni < 4; ++ni) {
                int c = wn * 64 + ni * 16 + fr;
                int o = c * 64 + ((fs ^ swz(c)) << 4);
                bhf[ni] = *reinterpret_cast<const short8*>(base + 16384 + o);
                blf[ni] = *reinterpret_cast<const short8*>(base + 24576 + o);
            }
            __builtin_amdgcn_s_setprio(1);
#pragma unroll
            for (int mi = 0; mi < 4; ++mi)
#pragma unroll
                for (int ni = 0; ni < 4; ++ni)
                    acc[mi][ni] = __builtin_amdgcn_mfma_f32_16x16x32_bf16(
                        ahf[mi], bhf[ni], acc[mi][ni], 0, 0, 0);
#pragma unroll
            for (int mi = 0; mi < 4; ++mi)
#pragma unroll
                for (int ni = 0; ni < 4; ++ni)
                    acc[mi][ni] = __builtin_amdgcn_mfma_f32_16x16x32_bf16(
                        ahf[mi], blf[ni], acc[mi][ni], 0, 0, 0);
#pragma unroll
            for (int mi = 0; mi < 4; ++mi)
#pragma unroll
                for (int ni = 0; ni < 4; ++ni)
                    acc[mi][ni] = __builtin_amdgcn_mfma_f32_16x16x32_bf16(
                        alf[mi], bhf[ni], acc[mi][ni], 0, 0, 0);
            __builtin_amdgcn_s_setprio(0);

            WAIT_LGKM0;
            __builtin_amdgcn_s_barrier();
            if (t + 2 < NT) stage(base, (t + 2) * 32);
        }

        float bv[4];
#pragma unroll
        for (int ni = 0; ni < 4; ++ni)
            bv[ni] = Wd_b[bcol + wn * 64 + ni * 16 + fr];

#pragma unroll
        for (int mi = 0; mi < 4; ++mi) {
#pragma unroll
            for (int reg = 0; reg < 4; ++reg) {
                int row = brow + wm * 64 + mi * 16 + fs * 4 + reg;
#pragma unroll
                for (int ni = 0; ni < 4; ++ni) {
                    int col = bcol + wn * 64 + ni * 16 + fr;
                    float v = acc[mi][ni][reg] + bv[ni];
                    unsigned short h = f2bf(v);
                    DprojH[(size_t)row * N + col] = h;
                    DprojL[(size_t)row * N + col] = f2bf(v - bf2f(h));
                }
            }
        }
    } else {
        // ---- ZW = Z @ out_w^T (plain bf16, bf16 out) ----
        auto stage = [&](char* base, int k0) {
            gload_lds16(Zb + offA0 + k0,           base + wid * 1024);
            gload_lds16(Zb + offA0 + 64 * K + k0,  base + 4096 + wid * 1024);
            gload_lds16(owb + offW0 + k0,          base + 8192 + wid * 1024);
            gload_lds16(owb + offW0 + 64 * K + k0, base + 12288 + wid * 1024);
        };

        f32x4 acc[4][4] = {};
        stage(lds, 0);
        stage(lds + 16384, 32);

        const int NT = K / 32;
        for (int t = 0; t < NT; ++t) {
            if (t < NT - 1) { WAIT_VM4; } else { WAIT_VM0; }
            __builtin_amdgcn_s_barrier();

            char* base = lds + (t & 1) * 16384;
            short8 a[4], bfr[4];
#pragma unroll
            for (int mi = 0; mi < 4; ++mi) {
                int r = wm * 64 + mi * 16 + fr;
                a[mi] = *reinterpret_cast<const short8*>(base + r * 64 + ((fs ^ swz(r)) << 4));
            }
#pragma unroll
            for (int ni = 0; ni < 4; ++ni) {
                int c = wn * 64 + ni * 16 + fr;
                bfr[ni] = *reinterpret_cast<const short8*>(base + 8192 + c * 64 + ((fs ^ swz(c)) << 4));
            }
            __builtin_amdgcn_s_setprio(1);
#pragma unroll
            for (int mi = 0; mi < 4; ++mi)
#pragma unroll
                for (int ni = 0; ni < 4; ++ni)
                    acc[mi][ni] = __builtin_amdgcn_mfma_f32_16x16x32_bf16(
                        a[mi], bfr[ni], acc[mi][ni], 0, 0, 0);
            __builtin_amdgcn_s_setprio(0);

            WAIT_LGKM0;
            __builtin_amdgcn_s_barrier();
            if (t + 2 < NT) stage(base, (t + 2) * 32);
        }

#pragma unroll
        for (int mi = 0; mi < 4; ++mi) {
#pragma unroll
            for (int reg = 0; reg < 4; ++reg) {
                int row = brow + wm * 64 + mi * 16 + fs * 4 + reg;
#pragma unroll
                for (int ni = 0; ni < 4; ++ni) {
                    int col = bcol + wn * 64 + ni * 16 + fr;
                    ZWb[(size_t)row * N + col] = f2bf(acc[mi][ni][reg]);
                }
            }
        }
    }
}

// ---------------------------------------------------------------------------
// Windowed split-bf16 logits, BM=128 x BN=64, counted-vmcnt pipeline (L=6).
__global__ __launch_bounds__(256) void k_logits_split(
    const unsigned short* __restrict__ Th, const unsigned short* __restrict__ Tl,
    const unsigned short* __restrict__ Dh, const unsigned short* __restrict__ Dl,
    const int* __restrict__ qp, float* __restrict__ logits)
{
    const int d = blockIdx.x + 16 * (blockIdx.y + 16 * blockIdx.z);
    const int logical = (d & 7) * 128 + (d >> 3);
    const int b    = logical >> 8;
    const int brow = ((logical >> 4) & 15) * 128;
    const int bcol = (logical & 15) * 64;

    const int start = qp[b], len = qp[b + 1] - start;
    if (bcol >= len) return;            // block-uniform: barrier-safe

    __shared__ __align__(16) char lds[2 * 24576];

    const int tid = threadIdx.x;
    const int ln  = tid & 63;
    const int wid = tid >> 6;
    const int fr  = ln & 15, fs = ln >> 4;
    const int srow = tid >> 2;
    const int sslt = tid & 3;

    const int kka = (sslt ^ swz(srow)) << 3;
    const size_t offA0 = ((size_t)b * LQ + brow + srow) * D_DIM + kka;
    int wr = start + bcol + srow; if (wr > NQ - 1) wr = NQ - 1;
    const size_t offW0 = (size_t)wr * D_DIM + kka;

    auto stage = [&](char* base, int k0) {
        gload_lds16(Th + offA0 + k0,              base + wid * 1024);
        gload_lds16(Th + offA0 + 64 * D_DIM + k0, base + 4096 + wid * 1024);
        gload_lds16(Tl + offA0 + k0,              base + 8192 + wid * 1024);
        gload_lds16(Tl + offA0 + 64 * D_DIM + k0, base + 12288 + wid * 1024);
        gload_lds16(Dh + offW0 + k0,              base + 16384 + wid * 1024);
        gload_lds16(Dl + offW0 + k0,              base + 20480 + wid * 1024);
    };

    f32x4 acc[2][4] = {};

    stage(lds, 0);
    stage(lds + 24576, 32);

    const int NT = D_DIM / 32;
    for (int t = 0; t < NT; ++t) {
        if (t < NT - 1) { WAIT_VM6; } else { WAIT_VM0; }
        __builtin_amdgcn_s_barrier();

        char* base = lds + (t & 1) * 24576;
        short8 ah[2], al[2], bh[4], bl[4];
#pragma unroll
        for (int mi = 0; mi < 2; ++mi) {
            int r = wid * 32 + mi * 16 + fr;
            int o = r * 64 + ((fs ^ swz(r)) << 4);
            ah[mi] = *reinterpret_cast<const short8*>(base + o);
            al[mi] = *reinterpret_cast<const short8*>(base + 8192 + o);
        }
#pragma unroll
        for (int ni = 0; ni < 4; ++ni) {
            int c = ni * 16 + fr;
            int o = c * 64 + ((fs ^ swz(c)) << 4);
            bh[ni] = *reinterpret_cast<const short8*>(base + 16384 + o);
            bl[ni] = *reinterpret_cast<const short8*>(base + 20480 + o);
        }
        __builtin_amdgcn_s_setprio(1);
#pragma unroll
        for (int mi = 0; mi < 2; ++mi)
#pragma unroll
            for (int ni = 0; ni < 4; ++ni)
                acc[mi][ni] = __builtin_amdgcn_mfma_f32_16x16x32_bf16(
                    ah[mi], bh[ni], acc[mi][ni], 0, 0, 0);
#pragma unroll
        for (int mi = 0; mi < 2; ++mi)
#pragma unroll
            for (int ni = 0; ni < 4; ++ni)
                acc[mi][ni] = __builtin_amdgcn_mfma_f32_16x16x32_bf16(
                    ah[mi], bl[ni], acc[mi][ni], 0, 0, 0);
#pragma unroll
        for (int mi = 0; mi < 2; ++mi)
#pragma unroll
            for (int ni = 0; ni < 4; ++ni)
                acc[mi][ni] = __builtin_amdgcn_mfma_f32_16x16x32_bf16(
                    al[mi], bh[ni], acc[mi][ni], 0, 0, 0);
        __builtin_amdgcn_s_setprio(0);

        WAIT_LGKM0;
        __builtin_amdgcn_s_barrier();
        if (t + 2 < NT) stage(base, (t + 2) * 32);
    }

#pragma unroll
    for (int mi = 0; mi < 2; ++mi) {
#pragma unroll
        for (int reg = 0; reg < 4; ++reg) {
            size_t row = (size_t)b * LQ + brow + wid * 32 + mi * 16 + fs * 4 + reg;
#pragma unroll
            for (int ni = 0; ni < 4; ++ni) {
                int col = bcol + ni * 16 + fr;
                logits[row * SMAX + col] = acc[mi][ni][reg];
            }
        }
    }
}

// ---------------------------------------------------------------------------
// Wave-per-row top-8 + softmax + gather of PRE-PROJECTED ZW rows + out_b,
// writing final output fp32 directly (out-GEMM eliminated by linearity).
__global__ __launch_bounds__(256) void k_topk_out(
    const float* __restrict__ logits, const unsigned short* __restrict__ ZW,
    const float* __restrict__ out_b, const int* __restrict__ qp,
    float* __restrict__ out)
{
    const int ln  = threadIdx.x & 63;
    const int row = blockIdx.x * 4 + (threadIdx.x >> 6);   // (b*L + l)
    const int b   = row >> 11;                              // L = 2048
    const int start = qp[b], len = qp[b + 1] - start;

    const float* lrow = logits + (size_t)row * SMAX;

    float v[16];
#pragma unroll
    for (int c = 0; c < 4; ++c) {
        float4 q = reinterpret_cast<const float4*>(lrow)[c * 64 + ln];
        int s0 = c * 256 + ln * 4;
        v[c * 4 + 0] = (s0 + 0 < len) ? q.x : -INFINITY;
        v[c * 4 + 1] = (s0 + 1 < len) ? q.y : -INFINITY;
        v[c * 4 + 2] = (s0 + 2 < len) ? q.z : -INFINITY;
        v[c * 4 + 3] = (s0 + 3 < len) ? q.w : -INFINITY;
    }

    float wv[TOPK]; int wi[TOPK];
#pragma unroll
    for (int it = 0; it < TOPK; ++it) {
        float bvv = v[0]; int bj = 0;
#pragma unroll
        for (int j = 1; j < 16; ++j)
            if (v[j] > bvv) { bvv = v[j]; bj = j; }
        int gidx = (bj >> 2) * 256 + ln * 4 + (bj & 3);
        float cv = bvv; int ci = gidx;
#pragma unroll
        for (int off = 32; off > 0; off >>= 1) {
            float ov = __shfl_xor(cv, off);
            int   oi = __shfl_xor(ci, off);
            if (ov > cv || (ov == cv && oi < ci)) { cv = ov; ci = oi; }
        }
        wv[it] = cv; wi[it] = ci;
#pragma unroll
        for (int j = 0; j < 16; ++j) {
            int sj = (j >> 2) * 256 + ln * 4 + (j & 3);
            if (sj == ci) v[j] = -INFINITY;
        }
    }

    float m = wv[0], denom = 0.f;
    float g[TOPK];
#pragma unroll
    for (int k = 0; k < TOPK; ++k) { g[k] = expf(wv[k] - m); denom += g[k]; }
    float inv = 1.f / denom;

    float4 acc[4];
#pragma unroll
    for (int c = 0; c < 4; ++c)
        acc[c] = reinterpret_cast<const float4*>(out_b)[c * 64 + ln];

#pragma unroll
    for (int k = 0; k < TOPK; ++k) {
        int si = wi[k] >= 0 ? wi[k] : 0;
        const ushort4v* zr = reinterpret_cast<const ushort4v*>(
            ZW + (size_t)(start + si) * D_DIM);
        float wgt = g[k] * inv;
#pragma unroll
        for (int c = 0; c < 4; ++c) {
            ushort4v z = zr[c * 64 + ln];
            acc[c].x = fmaf(wgt, bf2f(z[0]), acc[c].x);
            acc[c].y = fmaf(wgt, bf2f(z[1]), acc[c].y);
            acc[c].z = fmaf(wgt, bf2f(z[2]), acc[c].z);
            acc[c].w = fmaf(wgt, bf2f(z[3]), acc[c].w);
        }
    }
    float* orow = out + (size_t)row * D_DIM;
#pragma unroll
    for (int c = 0; c < 4; ++c)
        reinterpret_cast<float4*>(orow)[c * 64 + ln] = acc[c];
}

// ---------------------------------------------------------------------------
extern "C" void kernel_launch(void* const* d_in, const int* in_sizes, int n_in,
                              void* d_out, int out_size, void* d_ws, size_t ws_size,
                              hipStream_t stream) {
    const float* token_states = (const float*)d_in[0];
    const float* Z_sets       = (const float*)d_in[1];
    const float* desc_q       = (const float*)d_in[2];
    const int*   q_raw        = (const int*)d_in[3];
    const float* Wg_w  = (const float*)d_in[4];
    const float* Wg_b  = (const float*)d_in[5];
    const float* Wd_w  = (const float*)d_in[6];
    const float* Wd_b  = (const float*)d_in[7];
    const float* out_w = (const float*)d_in[8];
    const float* out_b = (const float*)d_in[9];
    float* out = (float*)d_out;

    const size_t NTOK = (size_t)BQ * LQ * D_DIM;   // 8388608
    const size_t NDES = (size_t)NQ * D_DIM;        // 2097152
    const size_t NW   = (size_t)D_DIM * D_DIM;     // 1048576

    char* ws = (char*)d_ws;
    int* qp = (int*)ws;
    unsigned short* tokenH = (unsigned short*)(ws + 256);
    unsigned short* tokenL = tokenH + NTOK;
    unsigned short* descH  = tokenL + NTOK;
    unsigned short* descL  = descH + NDES;
    unsigned short* wgH    = descL + NDES;
    unsigned short* wgL    = wgH + NW;
    unsigned short* wdH    = wgL + NW;
    unsigned short* wdL    = wdH + NW;
    unsigned short* owb    = wdL + NW;
    unsigned short* TprojH = owb + NW;
    unsigned short* TprojL = TprojH + NTOK;
    unsigned short* DprojH = TprojL + NTOK;
    unsigned short* DprojL = DprojH + NDES;
    unsigned short* Zb     = DprojL + NDES;        // [2048][1024] bf16
    unsigned short* ZWb    = Zb + NDES;            // [2048][1024] bf16
    float* logit          = (float*)tokenH;        // alias: token planes dead after Tproj GEMM

    // all conversions + qptrs in one launch: grid 7680
    k_cvt_all<<<7680, 256, 0, stream>>>(
        token_states, desc_q, Wg_w, Wd_w, out_w, Z_sets, q_raw,
        tokenH, tokenL, descH, descL, wgH, wgL, wdH, wdL, owb, Zb, qp);

    // Tproj = token @ Wg^T + b (split out): grid (8,64) = 512 = exactly 2/CU
    k_gemm_split<<<dim3(8, 64), 256, 0, stream>>>(
        tokenH, tokenL, wgH, wgL, Wg_b, TprojH, TprojL, BQ * LQ, D_DIM, D_DIM);

    // Dproj (split 3-pass) + ZW (plain bf16) merged: 256 blocks co-run
    k_dzw<<<256, 256, 0, stream>>>(
        descH, descL, wdH, wdL, Wd_b, DprojH, DprojL, Zb, owb, ZWb);

    // logits (fp32, windowed): grid (16,16,4) = 1024 blocks
    k_logits_split<<<dim3(SMAX / 64, LQ / 128, BQ), 256, 0, stream>>>(
        TprojH, TprojL, DprojH, DprojL, qp, logit);

    // top-8 + softmax + ZW gather + bias -> final output
    k_topk_out<<<(BQ * LQ) / 4, 256, 0, stream>>>(logit, ZWb, out_b, qp, out);
}

// Round 12
// 156.970 us; speedup vs baseline: 1.6228x; 1.1092x over previous
//
#include <hip/hip_runtime.h>
#include <hip/hip_bf16.h>
#include <math.h>

#define BQ    4
#define LQ    2048
#define D_DIM 1024
#define NQ    2048
#define SMAX  1024
#define TOPK  8

typedef __attribute__((ext_vector_type(8))) short          short8;
typedef __attribute__((ext_vector_type(8))) _Float16       half8;
typedef __attribute__((ext_vector_type(4))) float          f32x4;
typedef __attribute__((ext_vector_type(8))) unsigned short ushort8;
typedef __attribute__((ext_vector_type(4))) unsigned short ushort4v;

typedef __attribute__((address_space(3))) void as3_void;
typedef __attribute__((address_space(1))) void as1_void;

__device__ __forceinline__ void gload_lds16(const void* g, void* l) {
    __builtin_amdgcn_global_load_lds((const as1_void*)g, (as3_void*)l, 16, 0, 0);
}

__device__ __forceinline__ unsigned short f2bf(float f) {
    __hip_bfloat16 h = __float2bfloat16(f);
    return *reinterpret_cast<unsigned short*>(&h);
}
__device__ __forceinline__ float bf2f(unsigned short u) {
    unsigned int w = (unsigned int)u << 16;
    return *reinterpret_cast<float*>(&w);
}
__device__ __forceinline__ unsigned short f2h(float f) {
    _Float16 h = (_Float16)f;
    return *reinterpret_cast<unsigned short*>(&h);
}

// slot-XOR swizzle: conflict-free within each 8-consecutive-lane b128 group.
__device__ __forceinline__ int swz(int r) { return (r ^ (r >> 2)) & 3; }

#define WAIT_VM0   asm volatile("s_waitcnt vmcnt(0)" ::: "memory")
#define WAIT_VM3   asm volatile("s_waitcnt vmcnt(3)" ::: "memory")
#define WAIT_VM4   asm volatile("s_waitcnt vmcnt(4)" ::: "memory")
#define WAIT_VM8   asm volatile("s_waitcnt vmcnt(8)" ::: "memory")
#define WAIT_LGKM0 asm volatile("s_waitcnt lgkmcnt(0)" ::: "memory")

// ---------------------------------------------------------------------------
// One launch: all conversions + qptrs. Regions (2048 elems/block):
// [0,4096) token split | [4096,5120) desc split | [5120,5632) Wg split |
// [5632,6144) Wd split | [6144,6656) out_w plain | [6656,7680) Z plain.
__global__ __launch_bounds__(256) void k_cvt_all(
    const float* __restrict__ token_states, const float* __restrict__ desc_q,
    const float* __restrict__ Wg_w, const float* __restrict__ Wd_w,
    const float* __restrict__ out_w, const float* __restrict__ Z_sets,
    const int* __restrict__ q_raw,
    unsigned short* __restrict__ tokenH, unsigned short* __restrict__ tokenL,
    unsigned short* __restrict__ descH,  unsigned short* __restrict__ descL,
    unsigned short* __restrict__ wgH,    unsigned short* __restrict__ wgL,
    unsigned short* __restrict__ wdH,    unsigned short* __restrict__ wdL,
    unsigned short* __restrict__ owb,    unsigned short* __restrict__ Zb,
    int* __restrict__ qp)
{
    const int blk = blockIdx.x;
    if (blk == 0 && threadIdx.x == 0) {
        bool is64 = (q_raw[1] == 0);
        for (int i = 0; i <= BQ; ++i)
            qp[i] = is64 ? q_raw[2 * i] : q_raw[i];
    }

    const float* in; unsigned short *hi, *lo = nullptr; int local;
    if (blk < 4096)      { in = token_states; hi = tokenH; lo = tokenL; local = blk; }
    else if (blk < 5120) { in = desc_q; hi = descH; lo = descL; local = blk - 4096; }
    else if (blk < 5632) { in = Wg_w;   hi = wgH;   lo = wgL;   local = blk - 5120; }
    else if (blk < 6144) { in = Wd_w;   hi = wdH;   lo = wdL;   local = blk - 5632; }
    else if (blk < 6656) { in = out_w;  hi = owb;               local = blk - 6144; }
    else                 { in = Z_sets; hi = Zb;                local = blk - 6656; }

    int i = (local * 256 + threadIdx.x) * 8;
    float4 v0 = *reinterpret_cast<const float4*>(in + i);
    float4 v1 = *reinterpret_cast<const float4*>(in + i + 4);
    float x[8] = {v0.x, v0.y, v0.z, v0.w, v1.x, v1.y, v1.z, v1.w};
    ushort8 h8, l8;
#pragma unroll
    for (int k = 0; k < 8; ++k) {
        unsigned short h = f2bf(x[k]);
        h8[k] = h;
        l8[k] = f2bf(x[k] - bf2f(h));
    }
    *reinterpret_cast<ushort8*>(hi + i) = h8;
    if (lo) *reinterpret_cast<ushort8*>(lo + i) = l8;
}

// ---------------------------------------------------------------------------
// Split-bf16 GEMM (3-MFMA fp32 emulation), BM=128 x BN=128, BK=32,
// counted-vmcnt 2-deep pipeline, setprio. OUTPUT: single fp16 plane
// (downstream logits GEMM runs single-pass fp16 MFMA; fp16 storage rel
// 2^-12 keeps logit err ~2.6e-3 — validated error model, rounds 2/3/10).
__global__ __launch_bounds__(256) void k_gemm_split_f16out(
    const unsigned short* __restrict__ Ah, const unsigned short* __restrict__ Al,
    const unsigned short* __restrict__ Wh, const unsigned short* __restrict__ Wl,
    const float* __restrict__ bias, unsigned short* __restrict__ C,
    int M, int N, int K)
{
    __shared__ __align__(16) char lds[2 * 32768];

    const int nbx = gridDim.x;
    const int total = nbx * gridDim.y;
    const int d = blockIdx.x + nbx * blockIdx.y;
    const int logical = (d & 7) * (total >> 3) + (d >> 3);
    const int bcol = (logical % nbx) * 128;
    const int brow = (logical / nbx) * 128;

    const int tid = threadIdx.x;
    const int ln  = tid & 63;
    const int wid = tid >> 6;
    const int wm  = wid >> 1, wn = wid & 1;
    const int fr  = ln & 15, fs = ln >> 4;
    const int srow = tid >> 2;
    const int sslt = tid & 3;

    const int kk0 = (sslt ^ swz(srow)) << 3;
    const size_t offA0 = (size_t)(brow + srow) * K + kk0;
    const size_t offW0 = (size_t)(bcol + srow) * K + kk0;

    auto stage = [&](char* base, int k0) {
        gload_lds16(Ah + offA0 + k0,          base + wid * 1024);
        gload_lds16(Ah + offA0 + 64 * K + k0, base + 4096 + wid * 1024);
        gload_lds16(Al + offA0 + k0,          base + 8192 + wid * 1024);
        gload_lds16(Al + offA0 + 64 * K + k0, base + 12288 + wid * 1024);
        gload_lds16(Wh + offW0 + k0,          base + 16384 + wid * 1024);
        gload_lds16(Wh + offW0 + 64 * K + k0, base + 20480 + wid * 1024);
        gload_lds16(Wl + offW0 + k0,          base + 24576 + wid * 1024);
        gload_lds16(Wl + offW0 + 64 * K + k0, base + 28672 + wid * 1024);
    };

    f32x4 acc[4][4] = {};

    stage(lds, 0);
    stage(lds + 32768, 32);

    const int NT = K / 32;
    for (int t = 0; t < NT; ++t) {
        if (t < NT - 1) { WAIT_VM8; } else { WAIT_VM0; }
        __builtin_amdgcn_s_barrier();

        char* base = lds + (t & 1) * 32768;
        short8 ahf[4], alf[4], bhf[4], blf[4];
#pragma unroll
        for (int mi = 0; mi < 4; ++mi) {
            int r = wm * 64 + mi * 16 + fr;
            int o = r * 64 + ((fs ^ swz(r)) << 4);
            ahf[mi] = *reinterpret_cast<const short8*>(base + o);
            alf[mi] = *reinterpret_cast<const short8*>(base + 8192 + o);
        }
#pragma unroll
        for (int ni = 0; ni < 4; ++ni) {
            int c = wn * 64 + ni * 16 + fr;
            int o = c * 64 + ((fs ^ swz(c)) << 4);
            bhf[ni] = *reinterpret_cast<const short8*>(base + 16384 + o);
            blf[ni] = *reinterpret_cast<const short8*>(base + 24576 + o);
        }
        __builtin_amdgcn_s_setprio(1);
#pragma unroll
        for (int mi = 0; mi < 4; ++mi)
#pragma unroll
            for (int ni = 0; ni < 4; ++ni)
                acc[mi][ni] = __builtin_amdgcn_mfma_f32_16x16x32_bf16(
                    ahf[mi], bhf[ni], acc[mi][ni], 0, 0, 0);
#pragma unroll
        for (int mi = 0; mi < 4; ++mi)
#pragma unroll
            for (int ni = 0; ni < 4; ++ni)
                acc[mi][ni] = __builtin_amdgcn_mfma_f32_16x16x32_bf16(
                    ahf[mi], blf[ni], acc[mi][ni], 0, 0, 0);
#pragma unroll
        for (int mi = 0; mi < 4; ++mi)
#pragma unroll
            for (int ni = 0; ni < 4; ++ni)
                acc[mi][ni] = __builtin_amdgcn_mfma_f32_16x16x32_bf16(
                    alf[mi], bhf[ni], acc[mi][ni], 0, 0, 0);
        __builtin_amdgcn_s_setprio(0);

        WAIT_LGKM0;
        __builtin_amdgcn_s_barrier();
        if (t + 2 < NT) stage(base, (t + 2) * 32);
    }

    float bv[4];
#pragma unroll
    for (int ni = 0; ni < 4; ++ni)
        bv[ni] = bias[bcol + wn * 64 + ni * 16 + fr];

#pragma unroll
    for (int mi = 0; mi < 4; ++mi) {
#pragma unroll
        for (int reg = 0; reg < 4; ++reg) {
            int row = brow + wm * 64 + mi * 16 + fs * 4 + reg;
#pragma unroll
            for (int ni = 0; ni < 4; ++ni) {
                int col = bcol + wn * 64 + ni * 16 + fr;
                C[(size_t)row * N + col] = f2h(acc[mi][ni][reg] + bv[ni]);
            }
        }
    }
}

// ---------------------------------------------------------------------------
// Merged Dproj (split-bf16 3-pass, fp16 out) + ZW (plain bf16) launch.
// 256 blocks: even d -> Dproj tile, odd d -> ZW tile. Co-run across CUs.
__global__ __launch_bounds__(256) void k_dzw(
    const unsigned short* __restrict__ descH, const unsigned short* __restrict__ descL,
    const unsigned short* __restrict__ wdH,   const unsigned short* __restrict__ wdL,
    const float* __restrict__ Wd_b, unsigned short* __restrict__ Dproj16,
    const unsigned short* __restrict__ Zb, const unsigned short* __restrict__ owb,
    unsigned short* __restrict__ ZWb)
{
    constexpr int K = D_DIM, N = D_DIM;
    __shared__ __align__(16) char lds[2 * 32768];

    const int d = blockIdx.x;
    const int sub = d >> 1;
    const int bcol = (sub & 7) * 128;
    const int brow = (sub >> 3) * 128;

    const int tid = threadIdx.x;
    const int ln  = tid & 63;
    const int wid = tid >> 6;
    const int wm  = wid >> 1, wn = wid & 1;
    const int fr  = ln & 15, fs = ln >> 4;
    const int srow = tid >> 2;
    const int sslt = tid & 3;

    const int kk0 = (sslt ^ swz(srow)) << 3;
    const size_t offA0 = (size_t)(brow + srow) * K + kk0;
    const size_t offW0 = (size_t)(bcol + srow) * K + kk0;

    if ((d & 1) == 0) {
        // ---- Dproj: split 3-pass, fp16 out ----
        auto stage = [&](char* base, int k0) {
            gload_lds16(descH + offA0 + k0,          base + wid * 1024);
            gload_lds16(descH + offA0 + 64 * K + k0, base + 4096 + wid * 1024);
            gload_lds16(descL + offA0 + k0,          base + 8192 + wid * 1024);
            gload_lds16(descL + offA0 + 64 * K + k0, base + 12288 + wid * 1024);
            gload_lds16(wdH + offW0 + k0,            base + 16384 + wid * 1024);
            gload_lds16(wdH + offW0 + 64 * K + k0,   base + 20480 + wid * 1024);
            gload_lds16(wdL + offW0 + k0,            base + 24576 + wid * 1024);
            gload_lds16(wdL + offW0 + 64 * K + k0,   base + 28672 + wid * 1024);
        };

        f32x4 acc[4][4] = {};
        stage(lds, 0);
        stage(lds + 32768, 32);

        const int NT = K / 32;
        for (int t = 0; t < NT; ++t) {
            if (t < NT - 1) { WAIT_VM8; } else { WAIT_VM0; }
            __builtin_amdgcn_s_barrier();

            char* base = lds + (t & 1) * 32768;
            short8 ahf[4], alf[4], bhf[4], blf[4];
#pragma unroll
            for (int mi = 0; mi < 4; ++mi) {
                int r = wm * 64 + mi * 16 + fr;
                int o = r * 64 + ((fs ^ swz(r)) << 4);
                ahf[mi] = *reinterpret_cast<const short8*>(base + o);
                alf[mi] = *reinterpret_cast<const short8*>(base + 8192 + o);
            }
#pragma unroll
            for (int ni = 0; ni < 4; ++ni) {
                int c = wn * 64 + ni * 16 + fr;
                int o = c * 64 + ((fs ^ swz(c)) << 4);
                bhf[ni] = *reinterpret_cast<const short8*>(base + 16384 + o);
                blf[ni] = *reinterpret_cast<const short8*>(base + 24576 + o);
            }
            __builtin_amdgcn_s_setprio(1);
#pragma unroll
            for (int mi = 0; mi < 4; ++mi)
#pragma unroll
                for (int ni = 0; ni < 4; ++ni)
                    acc[mi][ni] = __builtin_amdgcn_mfma_f32_16x16x32_bf16(
                        ahf[mi], bhf[ni], acc[mi][ni], 0, 0, 0);
#pragma unroll
            for (int mi = 0; mi < 4; ++mi)
#pragma unroll
                for (int ni = 0; ni < 4; ++ni)
                    acc[mi][ni] = __builtin_amdgcn_mfma_f32_16x16x32_bf16(
                        ahf[mi], blf[ni], acc[mi][ni], 0, 0, 0);
#pragma unroll
            for (int mi = 0; mi < 4; ++mi)
#pragma unroll
                for (int ni = 0; ni < 4; ++ni)
                    acc[mi][ni] = __builtin_amdgcn_mfma_f32_16x16x32_bf16(
                        alf[mi], bhf[ni], acc[mi][ni], 0, 0, 0);
            __builtin_amdgcn_s_setprio(0);

            WAIT_LGKM0;
            __builtin_amdgcn_s_barrier();
            if (t + 2 < NT) stage(base, (t + 2) * 32);
        }

        float bv[4];
#pragma unroll
        for (int ni = 0; ni < 4; ++ni)
            bv[ni] = Wd_b[bcol + wn * 64 + ni * 16 + fr];

#pragma unroll
        for (int mi = 0; mi < 4; ++mi) {
#pragma unroll
            for (int reg = 0; reg < 4; ++reg) {
                int row = brow + wm * 64 + mi * 16 + fs * 4 + reg;
#pragma unroll
                for (int ni = 0; ni < 4; ++ni) {
                    int col = bcol + wn * 64 + ni * 16 + fr;
                    Dproj16[(size_t)row * N + col] = f2h(acc[mi][ni][reg] + bv[ni]);
                }
            }
        }
    } else {
        // ---- ZW = Z @ out_w^T (plain bf16, bf16 out) ----
        auto stage = [&](char* base, int k0) {
            gload_lds16(Zb + offA0 + k0,           base + wid * 1024);
            gload_lds16(Zb + offA0 + 64 * K + k0,  base + 4096 + wid * 1024);
            gload_lds16(owb + offW0 + k0,          base + 8192 + wid * 1024);
            gload_lds16(owb + offW0 + 64 * K + k0, base + 12288 + wid * 1024);
        };

        f32x4 acc[4][4] = {};
        stage(lds, 0);
        stage(lds + 16384, 32);

        const int NT = K / 32;
        for (int t = 0; t < NT; ++t) {
            if (t < NT - 1) { WAIT_VM4; } else { WAIT_VM0; }
            __builtin_amdgcn_s_barrier();

            char* base = lds + (t & 1) * 16384;
            short8 a[4], bfr[4];
#pragma unroll
            for (int mi = 0; mi < 4; ++mi) {
                int r = wm * 64 + mi * 16 + fr;
                a[mi] = *reinterpret_cast<const short8*>(base + r * 64 + ((fs ^ swz(r)) << 4));
            }
#pragma unroll
            for (int ni = 0; ni < 4; ++ni) {
                int c = wn * 64 + ni * 16 + fr;
                bfr[ni] = *reinterpret_cast<const short8*>(base + 8192 + c * 64 + ((fs ^ swz(c)) << 4));
            }
            __builtin_amdgcn_s_setprio(1);
#pragma unroll
            for (int mi = 0; mi < 4; ++mi)
#pragma unroll
                for (int ni = 0; ni < 4; ++ni)
                    acc[mi][ni] = __builtin_amdgcn_mfma_f32_16x16x32_bf16(
                        a[mi], bfr[ni], acc[mi][ni], 0, 0, 0);
            __builtin_amdgcn_s_setprio(0);

            WAIT_LGKM0;
            __builtin_amdgcn_s_barrier();
            if (t + 2 < NT) stage(base, (t + 2) * 32);
        }

#pragma unroll
        for (int mi = 0; mi < 4; ++mi) {
#pragma unroll
            for (int reg = 0; reg < 4; ++reg) {
                int row = brow + wm * 64 + mi * 16 + fs * 4 + reg;
#pragma unroll
                for (int ni = 0; ni < 4; ++ni) {
                    int col = bcol + wn * 64 + ni * 16 + fr;
                    ZWb[(size_t)row * N + col] = f2bf(acc[mi][ni][reg]);
                }
            }
        }
    }
}

// ---------------------------------------------------------------------------
// Windowed logits: SINGLE-PASS fp16 MFMA on fp16 Tproj/Dproj, FP32 output
// (fp16 logit storage was round 10's accuracy killer — logits reach |60|
// where fp16 ulp is 0.03; fp32 store keeps gate error at the 1e-3 level).
// BM=128 x BN=64, counted-vmcnt (L=3), setprio. grid (16,16,4).
__global__ __launch_bounds__(256) void k_logits_fp16(
    const unsigned short* __restrict__ T16, const unsigned short* __restrict__ D16,
    const int* __restrict__ qp, float* __restrict__ logits)
{
    const int d = blockIdx.x + 16 * (blockIdx.y + 16 * blockIdx.z);
    const int logical = (d & 7) * 128 + (d >> 3);
    const int b    = logical >> 8;
    const int brow = ((logical >> 4) & 15) * 128;
    const int bcol = (logical & 15) * 64;

    const int start = qp[b], len = qp[b + 1] - start;
    if (bcol >= len) return;            // block-uniform: barrier-safe

    __shared__ __align__(16) char lds[2 * 12288];

    const int tid = threadIdx.x;
    const int ln  = tid & 63;
    const int wid = tid >> 6;
    const int fr  = ln & 15, fs = ln >> 4;
    const int srow = tid >> 2;
    const int sslt = tid & 3;

    const int kka = (sslt ^ swz(srow)) << 3;
    const size_t offA0 = ((size_t)b * LQ + brow + srow) * D_DIM + kka;
    int wr = start + bcol + srow; if (wr > NQ - 1) wr = NQ - 1;
    const size_t offW0 = (size_t)wr * D_DIM + kka;

    auto stage = [&](char* base, int k0) {
        gload_lds16(T16 + offA0 + k0,              base + wid * 1024);
        gload_lds16(T16 + offA0 + 64 * D_DIM + k0, base + 4096 + wid * 1024);
        gload_lds16(D16 + offW0 + k0,              base + 8192 + wid * 1024);
    };

    f32x4 acc[2][4] = {};

    stage(lds, 0);
    stage(lds + 12288, 32);

    const int NT = D_DIM / 32;
    for (int t = 0; t < NT; ++t) {
        if (t < NT - 1) { WAIT_VM3; } else { WAIT_VM0; }
        __builtin_amdgcn_s_barrier();

        char* base = lds + (t & 1) * 12288;
        half8 a[2], bf[4];
#pragma unroll
        for (int mi = 0; mi < 2; ++mi) {
            int r = wid * 32 + mi * 16 + fr;
            a[mi] = *reinterpret_cast<const half8*>(base + r * 64 + ((fs ^ swz(r)) << 4));
        }
#pragma unroll
        for (int ni = 0; ni < 4; ++ni) {
            int c = ni * 16 + fr;
            bf[ni] = *reinterpret_cast<const half8*>(base + 8192 + c * 64 + ((fs ^ swz(c)) << 4));
        }
        __builtin_amdgcn_s_setprio(1);
#pragma unroll
        for (int mi = 0; mi < 2; ++mi)
#pragma unroll
            for (int ni = 0; ni < 4; ++ni)
                acc[mi][ni] = __builtin_amdgcn_mfma_f32_16x16x32_f16(
                    a[mi], bf[ni], acc[mi][ni], 0, 0, 0);
        __builtin_amdgcn_s_setprio(0);

        WAIT_LGKM0;
        __builtin_amdgcn_s_barrier();
        if (t + 2 < NT) stage(base, (t + 2) * 32);
    }

#pragma unroll
    for (int mi = 0; mi < 2; ++mi) {
#pragma unroll
        for (int reg = 0; reg < 4; ++reg) {
            size_t row = (size_t)b * LQ + brow + wid * 32 + mi * 16 + fs * 4 + reg;
#pragma unroll
            for (int ni = 0; ni < 4; ++ni) {
                int col = bcol + ni * 16 + fr;
                logits[row * SMAX + col] = acc[mi][ni][reg];
            }
        }
    }
}

// ---------------------------------------------------------------------------
// Wave-per-row top-8 + softmax + gather of PRE-PROJECTED ZW rows + out_b,
// writing final output fp32 directly (out-GEMM eliminated by linearity).
__global__ __launch_bounds__(256) void k_topk_out(
    const float* __restrict__ logits, const unsigned short* __restrict__ ZW,
    const float* __restrict__ out_b, const int* __restrict__ qp,
    float* __restrict__ out)
{
    const int ln  = threadIdx.x & 63;
    const int row = blockIdx.x * 4 + (threadIdx.x >> 6);   // (b*L + l)
    const int b   = row >> 11;                              // L = 2048
    const int start = qp[b], len = qp[b + 1] - start;

    const float* lrow = logits + (size_t)row * SMAX;

    float v[16];
#pragma unroll
    for (int c = 0; c < 4; ++c) {
        float4 q = reinterpret_cast<const float4*>(lrow)[c * 64 + ln];
        int s0 = c * 256 + ln * 4;
        v[c * 4 + 0] = (s0 + 0 < len) ? q.x : -INFINITY;
        v[c * 4 + 1] = (s0 + 1 < len) ? q.y : -INFINITY;
        v[c * 4 + 2] = (s0 + 2 < len) ? q.z : -INFINITY;
        v[c * 4 + 3] = (s0 + 3 < len) ? q.w : -INFINITY;
    }

    float wv[TOPK]; int wi[TOPK];
#pragma unroll
    for (int it = 0; it < TOPK; ++it) {
        float bvv = v[0]; int bj = 0;
#pragma unroll
        for (int j = 1; j < 16; ++j)
            if (v[j] > bvv) { bvv = v[j]; bj = j; }
        int gidx = (bj >> 2) * 256 + ln * 4 + (bj & 3);
        float cv = bvv; int ci = gidx;
#pragma unroll
        for (int off = 32; off > 0; off >>= 1) {
            float ov = __shfl_xor(cv, off);
            int   oi = __shfl_xor(ci, off);
            if (ov > cv || (ov == cv && oi < ci)) { cv = ov; ci = oi; }
        }
        wv[it] = cv; wi[it] = ci;
#pragma unroll
        for (int j = 0; j < 16; ++j) {
            int sj = (j >> 2) * 256 + ln * 4 + (j & 3);
            if (sj == ci) v[j] = -INFINITY;
        }
    }

    float m = wv[0], denom = 0.f;
    float g[TOPK];
#pragma unroll
    for (int k = 0; k < TOPK; ++k) { g[k] = expf(wv[k] - m); denom += g[k]; }
    float inv = 1.f / denom;

    float4 acc[4];
#pragma unroll
    for (int c = 0; c < 4; ++c)
        acc[c] = reinterpret_cast<const float4*>(out_b)[c * 64 + ln];

#pragma unroll
    for (int k = 0; k < TOPK; ++k) {
        int si = wi[k] >= 0 ? wi[k] : 0;
        const ushort4v* zr = reinterpret_cast<const ushort4v*>(
            ZW + (size_t)(start + si) * D_DIM);
        float wgt = g[k] * inv;
#pragma unroll
        for (int c = 0; c < 4; ++c) {
            ushort4v z = zr[c * 64 + ln];
            acc[c].x = fmaf(wgt, bf2f(z[0]), acc[c].x);
            acc[c].y = fmaf(wgt, bf2f(z[1]), acc[c].y);
            acc[c].z = fmaf(wgt, bf2f(z[2]), acc[c].z);
            acc[c].w = fmaf(wgt, bf2f(z[3]), acc[c].w);
        }
    }
    float* orow = out + (size_t)row * D_DIM;
#pragma unroll
    for (int c = 0; c < 4; ++c)
        reinterpret_cast<float4*>(orow)[c * 64 + ln] = acc[c];
}

// ---------------------------------------------------------------------------
extern "C" void kernel_launch(void* const* d_in, const int* in_sizes, int n_in,
                              void* d_out, int out_size, void* d_ws, size_t ws_size,
                              hipStream_t stream) {
    const float* token_states = (const float*)d_in[0];
    const float* Z_sets       = (const float*)d_in[1];
    const float* desc_q       = (const float*)d_in[2];
    const int*   q_raw        = (const int*)d_in[3];
    const float* Wg_w  = (const float*)d_in[4];
    const float* Wg_b  = (const float*)d_in[5];
    const float* Wd_w  = (const float*)d_in[6];
    const float* Wd_b  = (const float*)d_in[7];
    const float* out_w = (const float*)d_in[8];
    const float* out_b = (const float*)d_in[9];
    float* out = (float*)d_out;

    const size_t NTOK = (size_t)BQ * LQ * D_DIM;   // 8388608
    const size_t NDES = (size_t)NQ * D_DIM;        // 2097152
    const size_t NW   = (size_t)D_DIM * D_DIM;     // 1048576

    char* ws = (char*)d_ws;
    int* qp = (int*)ws;
    unsigned short* tokenH  = (unsigned short*)(ws + 256);
    unsigned short* tokenL  = tokenH + NTOK;
    unsigned short* descH   = tokenL + NTOK;
    unsigned short* descL   = descH + NDES;
    unsigned short* wgH     = descL + NDES;
    unsigned short* wgL     = wgH + NW;
    unsigned short* wdH     = wgL + NW;
    unsigned short* wdL     = wdH + NW;
    unsigned short* owb     = wdL + NW;
    unsigned short* Zb      = owb + NW;
    unsigned short* Tproj16 = Zb + NDES;           // [8192][1024] fp16
    unsigned short* Dproj16 = Tproj16 + NTOK;      // [2048][1024] fp16
    unsigned short* ZWb     = Dproj16 + NDES;      // [2048][1024] bf16
    float* logit = (float*)tokenH;  // 33.5 MB over tokenH+tokenL (dead after Tproj)

    // all conversions + qptrs in one launch: grid 7680
    k_cvt_all<<<7680, 256, 0, stream>>>(
        token_states, desc_q, Wg_w, Wd_w, out_w, Z_sets, q_raw,
        tokenH, tokenL, descH, descL, wgH, wgL, wdH, wdL, owb, Zb, qp);

    // Tproj = token @ Wg^T + b (split 3-pass, fp16 out): grid (8,64) = 512
    k_gemm_split_f16out<<<dim3(8, 64), 256, 0, stream>>>(
        tokenH, tokenL, wgH, wgL, Wg_b, Tproj16, BQ * LQ, D_DIM, D_DIM);

    // Dproj (split 3-pass, fp16 out) + ZW (plain bf16) merged: 256 blocks
    k_dzw<<<256, 256, 0, stream>>>(
        descH, descL, wdH, wdL, Wd_b, Dproj16, Zb, owb, ZWb);

    // logits (single-pass fp16 MFMA, fp32 out): grid (16,16,4)
    k_logits_fp16<<<dim3(SMAX / 64, LQ / 128, BQ), 256, 0, stream>>>(
        Tproj16, Dproj16, qp, logit);

    // top-8 + softmax + ZW gather + bias -> final output
    k_topk_out<<<(BQ * LQ) / 4, 256, 0, stream>>>(logit, ZWb, out_b, qp, out);
}

// Round 13
// 139.142 us; speedup vs baseline: 1.8307x; 1.1281x over previous
//
#include <hip/hip_runtime.h>
#include <hip/hip_bf16.h>
#include <math.h>

#define BQ    4
#define LQ    2048
#define D_DIM 1024
#define NQ    2048
#define SMAX  1024
#define TOPK  8

typedef __attribute__((ext_vector_type(8))) short          short8;
typedef __attribute__((ext_vector_type(8))) _Float16       half8;
typedef __attribute__((ext_vector_type(4))) float          f32x4;
typedef __attribute__((ext_vector_type(8))) unsigned short ushort8;
typedef __attribute__((ext_vector_type(4))) unsigned short ushort4v;

typedef __attribute__((address_space(3))) void as3_void;
typedef __attribute__((address_space(1))) void as1_void;

__device__ __forceinline__ void gload_lds16(const void* g, void* l) {
    __builtin_amdgcn_global_load_lds((const as1_void*)g, (as3_void*)l, 16, 0, 0);
}

__device__ __forceinline__ unsigned short f2bf(float f) {
    __hip_bfloat16 h = __float2bfloat16(f);
    return *reinterpret_cast<unsigned short*>(&h);
}
__device__ __forceinline__ float bf2f(unsigned short u) {
    unsigned int w = (unsigned int)u << 16;
    return *reinterpret_cast<float*>(&w);
}
__device__ __forceinline__ unsigned short f2h(float f) {
    _Float16 h = (_Float16)f;
    return *reinterpret_cast<unsigned short*>(&h);
}
__device__ __forceinline__ float h2f(unsigned short u) {
    _Float16 h = *reinterpret_cast<_Float16*>(&u);
    return (float)h;
}

// slot-XOR swizzle: conflict-free within each 8-consecutive-lane b128 group.
__device__ __forceinline__ int swz(int r) { return (r ^ (r >> 2)) & 3; }

#define WAIT_VM0   asm volatile("s_waitcnt vmcnt(0)" ::: "memory")
#define WAIT_VM3   asm volatile("s_waitcnt vmcnt(3)" ::: "memory")
#define WAIT_VM4   asm volatile("s_waitcnt vmcnt(4)" ::: "memory")
#define WAIT_VM6   asm volatile("s_waitcnt vmcnt(6)" ::: "memory")
#define WAIT_LGKM0 asm volatile("s_waitcnt lgkmcnt(0)" ::: "memory")

// ---------------------------------------------------------------------------
// One launch: all conversions + qptrs. Regions (2048 elems/block):
// [0,4096)    token -> fp16 hi/lo split
// [4096,5120) desc  -> fp16 hi/lo split
// [5120,5632) Wg    -> fp16 single
// [5632,6144) Wd    -> fp16 single
// [6144,6656) out_w -> bf16 single
// [6656,7680) Z     -> bf16 single
__global__ __launch_bounds__(256) void k_cvt_all(
    const float* __restrict__ token_states, const float* __restrict__ desc_q,
    const float* __restrict__ Wg_w, const float* __restrict__ Wd_w,
    const float* __restrict__ out_w, const float* __restrict__ Z_sets,
    const int* __restrict__ q_raw,
    unsigned short* __restrict__ tokenH, unsigned short* __restrict__ tokenL,
    unsigned short* __restrict__ descH,  unsigned short* __restrict__ descL,
    unsigned short* __restrict__ wgh,    unsigned short* __restrict__ wdh,
    unsigned short* __restrict__ owb,    unsigned short* __restrict__ Zb,
    int* __restrict__ qp)
{
    const int blk = blockIdx.x;
    if (blk == 0 && threadIdx.x == 0) {
        bool is64 = (q_raw[1] == 0);
        for (int i = 0; i <= BQ; ++i)
            qp[i] = is64 ? q_raw[2 * i] : q_raw[i];
    }

    const float* in; unsigned short *hi, *lo = nullptr; int local; bool fp16m = true;
    if (blk < 4096)      { in = token_states; hi = tokenH; lo = tokenL; local = blk; }
    else if (blk < 5120) { in = desc_q; hi = descH; lo = descL; local = blk - 4096; }
    else if (blk < 5632) { in = Wg_w;   hi = wgh;   local = blk - 5120; }
    else if (blk < 6144) { in = Wd_w;   hi = wdh;   local = blk - 5632; }
    else if (blk < 6656) { in = out_w;  hi = owb;   local = blk - 6144; fp16m = false; }
    else                 { in = Z_sets; hi = Zb;    local = blk - 6656; fp16m = false; }

    int i = (local * 256 + threadIdx.x) * 8;
    float4 v0 = *reinterpret_cast<const float4*>(in + i);
    float4 v1 = *reinterpret_cast<const float4*>(in + i + 4);
    float x[8] = {v0.x, v0.y, v0.z, v0.w, v1.x, v1.y, v1.z, v1.w};
    ushort8 h8, l8;
#pragma unroll
    for (int k = 0; k < 8; ++k) {
        if (fp16m) {
            unsigned short h = f2h(x[k]);
            h8[k] = h;
            l8[k] = f2h(x[k] - h2f(h));
        } else {
            h8[k] = f2bf(x[k]);
        }
    }
    *reinterpret_cast<ushort8*>(hi + i) = h8;
    if (lo) *reinterpret_cast<ushort8*>(lo + i) = l8;
}

// ---------------------------------------------------------------------------
// 2-pass fp16-split GEMM: C = (Ah+Al) @ Wh^T + bias  (A split fp16, W single
// fp16; dropped A*eps_W term is 2^-11-class -> invisible per round-12 calib).
// BM=128 x BN=128, BK=32, counted-vmcnt 2-deep pipeline (L=6), setprio.
// LDS/buf: Ah 8K | Al 8K | Wh 8K = 24 KB; x2 = 48 KB. OUTPUT: fp16 plane.
__global__ __launch_bounds__(256) void k_gemm_2p(
    const unsigned short* __restrict__ Ah, const unsigned short* __restrict__ Al,
    const unsigned short* __restrict__ Wh,
    const float* __restrict__ bias, unsigned short* __restrict__ C,
    int M, int N, int K)
{
    __shared__ __align__(16) char lds[2 * 24576];

    const int nbx = gridDim.x;
    const int total = nbx * gridDim.y;
    const int d = blockIdx.x + nbx * blockIdx.y;
    const int logical = (d & 7) * (total >> 3) + (d >> 3);
    const int bcol = (logical % nbx) * 128;
    const int brow = (logical / nbx) * 128;

    const int tid = threadIdx.x;
    const int ln  = tid & 63;
    const int wid = tid >> 6;
    const int wm  = wid >> 1, wn = wid & 1;
    const int fr  = ln & 15, fs = ln >> 4;
    const int srow = tid >> 2;
    const int sslt = tid & 3;

    const int kk0 = (sslt ^ swz(srow)) << 3;
    const size_t offA0 = (size_t)(brow + srow) * K + kk0;
    const size_t offW0 = (size_t)(bcol + srow) * K + kk0;

    auto stage = [&](char* base, int k0) {
        gload_lds16(Ah + offA0 + k0,          base + wid * 1024);
        gload_lds16(Ah + offA0 + 64 * K + k0, base + 4096 + wid * 1024);
        gload_lds16(Al + offA0 + k0,          base + 8192 + wid * 1024);
        gload_lds16(Al + offA0 + 64 * K + k0, base + 12288 + wid * 1024);
        gload_lds16(Wh + offW0 + k0,          base + 16384 + wid * 1024);
        gload_lds16(Wh + offW0 + 64 * K + k0, base + 20480 + wid * 1024);
    };

    f32x4 acc[4][4] = {};

    stage(lds, 0);
    stage(lds + 24576, 32);

    const int NT = K / 32;
    for (int t = 0; t < NT; ++t) {
        if (t < NT - 1) { WAIT_VM6; } else { WAIT_VM0; }
        __builtin_amdgcn_s_barrier();

        char* base = lds + (t & 1) * 24576;
        half8 ahf[4], alf[4], bhf[4];
#pragma unroll
        for (int mi = 0; mi < 4; ++mi) {
            int r = wm * 64 + mi * 16 + fr;
            int o = r * 64 + ((fs ^ swz(r)) << 4);
            ahf[mi] = *reinterpret_cast<const half8*>(base + o);
            alf[mi] = *reinterpret_cast<const half8*>(base + 8192 + o);
        }
#pragma unroll
        for (int ni = 0; ni < 4; ++ni) {
            int c = wn * 64 + ni * 16 + fr;
            int o = c * 64 + ((fs ^ swz(c)) << 4);
            bhf[ni] = *reinterpret_cast<const half8*>(base + 16384 + o);
        }
        __builtin_amdgcn_s_setprio(1);
#pragma unroll
        for (int mi = 0; mi < 4; ++mi)
#pragma unroll
            for (int ni = 0; ni < 4; ++ni)
                acc[mi][ni] = __builtin_amdgcn_mfma_f32_16x16x32_f16(
                    ahf[mi], bhf[ni], acc[mi][ni], 0, 0, 0);
#pragma unroll
        for (int mi = 0; mi < 4; ++mi)
#pragma unroll
            for (int ni = 0; ni < 4; ++ni)
                acc[mi][ni] = __builtin_amdgcn_mfma_f32_16x16x32_f16(
                    alf[mi], bhf[ni], acc[mi][ni], 0, 0, 0);
        __builtin_amdgcn_s_setprio(0);

        WAIT_LGKM0;
        __builtin_amdgcn_s_barrier();
        if (t + 2 < NT) stage(base, (t + 2) * 32);
    }

    float bv[4];
#pragma unroll
    for (int ni = 0; ni < 4; ++ni)
        bv[ni] = bias[bcol + wn * 64 + ni * 16 + fr];

#pragma unroll
    for (int mi = 0; mi < 4; ++mi) {
#pragma unroll
        for (int reg = 0; reg < 4; ++reg) {
            int row = brow + wm * 64 + mi * 16 + fs * 4 + reg;
#pragma unroll
            for (int ni = 0; ni < 4; ++ni) {
                int col = bcol + wn * 64 + ni * 16 + fr;
                C[(size_t)row * N + col] = f2h(acc[mi][ni][reg] + bv[ni]);
            }
        }
    }
}

// ---------------------------------------------------------------------------
// Merged Dproj (2-pass fp16-split, fp16 out) + ZW (plain bf16) launch.
// 256 blocks: even d -> Dproj tile, odd d -> ZW tile. Co-run across CUs.
__global__ __launch_bounds__(256) void k_dzw(
    const unsigned short* __restrict__ descH, const unsigned short* __restrict__ descL,
    const unsigned short* __restrict__ wdh,
    const float* __restrict__ Wd_b, unsigned short* __restrict__ Dproj16,
    const unsigned short* __restrict__ Zb, const unsigned short* __restrict__ owb,
    unsigned short* __restrict__ ZWb)
{
    constexpr int K = D_DIM, N = D_DIM;
    __shared__ __align__(16) char lds[2 * 24576];

    const int d = blockIdx.x;
    const int sub = d >> 1;
    const int bcol = (sub & 7) * 128;
    const int brow = (sub >> 3) * 128;

    const int tid = threadIdx.x;
    const int ln  = tid & 63;
    const int wid = tid >> 6;
    const int wm  = wid >> 1, wn = wid & 1;
    const int fr  = ln & 15, fs = ln >> 4;
    const int srow = tid >> 2;
    const int sslt = tid & 3;

    const int kk0 = (sslt ^ swz(srow)) << 3;
    const size_t offA0 = (size_t)(brow + srow) * K + kk0;
    const size_t offW0 = (size_t)(bcol + srow) * K + kk0;

    if ((d & 1) == 0) {
        // ---- Dproj: 2-pass fp16-split, fp16 out ----
        auto stage = [&](char* base, int k0) {
            gload_lds16(descH + offA0 + k0,          base + wid * 1024);
            gload_lds16(descH + offA0 + 64 * K + k0, base + 4096 + wid * 1024);
            gload_lds16(descL + offA0 + k0,          base + 8192 + wid * 1024);
            gload_lds16(descL + offA0 + 64 * K + k0, base + 12288 + wid * 1024);
            gload_lds16(wdh + offW0 + k0,            base + 16384 + wid * 1024);
            gload_lds16(wdh + offW0 + 64 * K + k0,   base + 20480 + wid * 1024);
        };

        f32x4 acc[4][4] = {};
        stage(lds, 0);
        stage(lds + 24576, 32);

        const int NT = K / 32;
        for (int t = 0; t < NT; ++t) {
            if (t < NT - 1) { WAIT_VM6; } else { WAIT_VM0; }
            __builtin_amdgcn_s_barrier();

            char* base = lds + (t & 1) * 24576;
            half8 ahf[4], alf[4], bhf[4];
#pragma unroll
            for (int mi = 0; mi < 4; ++mi) {
                int r = wm * 64 + mi * 16 + fr;
                int o = r * 64 + ((fs ^ swz(r)) << 4);
                ahf[mi] = *reinterpret_cast<const half8*>(base + o);
                alf[mi] = *reinterpret_cast<const half8*>(base + 8192 + o);
            }
#pragma unroll
            for (int ni = 0; ni < 4; ++ni) {
                int c = wn * 64 + ni * 16 + fr;
                int o = c * 64 + ((fs ^ swz(c)) << 4);
                bhf[ni] = *reinterpret_cast<const half8*>(base + 16384 + o);
            }
            __builtin_amdgcn_s_setprio(1);
#pragma unroll
            for (int mi = 0; mi < 4; ++mi)
#pragma unroll
                for (int ni = 0; ni < 4; ++ni)
                    acc[mi][ni] = __builtin_amdgcn_mfma_f32_16x16x32_f16(
                        ahf[mi], bhf[ni], acc[mi][ni], 0, 0, 0);
#pragma unroll
            for (int mi = 0; mi < 4; ++mi)
#pragma unroll
                for (int ni = 0; ni < 4; ++ni)
                    acc[mi][ni] = __builtin_amdgcn_mfma_f32_16x16x32_f16(
                        alf[mi], bhf[ni], acc[mi][ni], 0, 0, 0);
            __builtin_amdgcn_s_setprio(0);

            WAIT_LGKM0;
            __builtin_amdgcn_s_barrier();
            if (t + 2 < NT) stage(base, (t + 2) * 32);
        }

        float bv[4];
#pragma unroll
        for (int ni = 0; ni < 4; ++ni)
            bv[ni] = Wd_b[bcol + wn * 64 + ni * 16 + fr];

#pragma unroll
        for (int mi = 0; mi < 4; ++mi) {
#pragma unroll
            for (int reg = 0; reg < 4; ++reg) {
                int row = brow + wm * 64 + mi * 16 + fs * 4 + reg;
#pragma unroll
                for (int ni = 0; ni < 4; ++ni) {
                    int col = bcol + wn * 64 + ni * 16 + fr;
                    Dproj16[(size_t)row * N + col] = f2h(acc[mi][ni][reg] + bv[ni]);
                }
            }
        }
    } else {
        // ---- ZW = Z @ out_w^T (plain bf16, bf16 out) ----
        auto stage = [&](char* base, int k0) {
            gload_lds16(Zb + offA0 + k0,           base + wid * 1024);
            gload_lds16(Zb + offA0 + 64 * K + k0,  base + 4096 + wid * 1024);
            gload_lds16(owb + offW0 + k0,          base + 8192 + wid * 1024);
            gload_lds16(owb + offW0 + 64 * K + k0, base + 12288 + wid * 1024);
        };

        f32x4 acc[4][4] = {};
        stage(lds, 0);
        stage(lds + 24576, 32);

        const int NT = K / 32;
        for (int t = 0; t < NT; ++t) {
            if (t < NT - 1) { WAIT_VM4; } else { WAIT_VM0; }
            __builtin_amdgcn_s_barrier();

            char* base = lds + (t & 1) * 24576;
            short8 a[4], bfr[4];
#pragma unroll
            for (int mi = 0; mi < 4; ++mi) {
                int r = wm * 64 + mi * 16 + fr;
                a[mi] = *reinterpret_cast<const short8*>(base + r * 64 + ((fs ^ swz(r)) << 4));
            }
#pragma unroll
            for (int ni = 0; ni < 4; ++ni) {
                int c = wn * 64 + ni * 16 + fr;
                bfr[ni] = *reinterpret_cast<const short8*>(base + 8192 + c * 64 + ((fs ^ swz(c)) << 4));
            }
            __builtin_amdgcn_s_setprio(1);
#pragma unroll
            for (int mi = 0; mi < 4; ++mi)
#pragma unroll
                for (int ni = 0; ni < 4; ++ni)
                    acc[mi][ni] = __builtin_amdgcn_mfma_f32_16x16x32_bf16(
                        a[mi], bfr[ni], acc[mi][ni], 0, 0, 0);
            __builtin_amdgcn_s_setprio(0);

            WAIT_LGKM0;
            __builtin_amdgcn_s_barrier();
            if (t + 2 < NT) stage(base, (t + 2) * 32);
        }

#pragma unroll
        for (int mi = 0; mi < 4; ++mi) {
#pragma unroll
            for (int reg = 0; reg < 4; ++reg) {
                int row = brow + wm * 64 + mi * 16 + fs * 4 + reg;
#pragma unroll
                for (int ni = 0; ni < 4; ++ni) {
                    int col = bcol + wn * 64 + ni * 16 + fr;
                    ZWb[(size_t)row * N + col] = f2bf(acc[mi][ni][reg]);
                }
            }
        }
    }
}

// ---------------------------------------------------------------------------
// Windowed logits: SINGLE-PASS fp16 MFMA on fp16 Tproj/Dproj, FP32 output.
// BM=128 x BN=64, counted-vmcnt (L=3), setprio. grid (16,16,4).
__global__ __launch_bounds__(256) void k_logits_fp16(
    const unsigned short* __restrict__ T16, const unsigned short* __restrict__ D16,
    const int* __restrict__ qp, float* __restrict__ logits)
{
    const int d = blockIdx.x + 16 * (blockIdx.y + 16 * blockIdx.z);
    const int logical = (d & 7) * 128 + (d >> 3);
    const int b    = logical >> 8;
    const int brow = ((logical >> 4) & 15) * 128;
    const int bcol = (logical & 15) * 64;

    const int start = qp[b], len = qp[b + 1] - start;
    if (bcol >= len) return;            // block-uniform: barrier-safe

    __shared__ __align__(16) char lds[2 * 12288];

    const int tid = threadIdx.x;
    const int ln  = tid & 63;
    const int wid = tid >> 6;
    const int fr  = ln & 15, fs = ln >> 4;
    const int srow = tid >> 2;
    const int sslt = tid & 3;

    const int kka = (sslt ^ swz(srow)) << 3;
    const size_t offA0 = ((size_t)b * LQ + brow + srow) * D_DIM + kka;
    int wr = start + bcol + srow; if (wr > NQ - 1) wr = NQ - 1;
    const size_t offW0 = (size_t)wr * D_DIM + kka;

    auto stage = [&](char* base, int k0) {
        gload_lds16(T16 + offA0 + k0,              base + wid * 1024);
        gload_lds16(T16 + offA0 + 64 * D_DIM + k0, base + 4096 + wid * 1024);
        gload_lds16(D16 + offW0 + k0,              base + 8192 + wid * 1024);
    };

    f32x4 acc[2][4] = {};

    stage(lds, 0);
    stage(lds + 12288, 32);

    const int NT = D_DIM / 32;
    for (int t = 0; t < NT; ++t) {
        if (t < NT - 1) { WAIT_VM3; } else { WAIT_VM0; }
        __builtin_amdgcn_s_barrier();

        char* base = lds + (t & 1) * 12288;
        half8 a[2], bf[4];
#pragma unroll
        for (int mi = 0; mi < 2; ++mi) {
            int r = wid * 32 + mi * 16 + fr;
            a[mi] = *reinterpret_cast<const half8*>(base + r * 64 + ((fs ^ swz(r)) << 4));
        }
#pragma unroll
        for (int ni = 0; ni < 4; ++ni) {
            int c = ni * 16 + fr;
            bf[ni] = *reinterpret_cast<const half8*>(base + 8192 + c * 64 + ((fs ^ swz(c)) << 4));
        }
        __builtin_amdgcn_s_setprio(1);
#pragma unroll
        for (int mi = 0; mi < 2; ++mi)
#pragma unroll
            for (int ni = 0; ni < 4; ++ni)
                acc[mi][ni] = __builtin_amdgcn_mfma_f32_16x16x32_f16(
                    a[mi], bf[ni], acc[mi][ni], 0, 0, 0);
        __builtin_amdgcn_s_setprio(0);

        WAIT_LGKM0;
        __builtin_amdgcn_s_barrier();
        if (t + 2 < NT) stage(base, (t + 2) * 32);
    }

#pragma unroll
    for (int mi = 0; mi < 2; ++mi) {
#pragma unroll
        for (int reg = 0; reg < 4; ++reg) {
            size_t row = (size_t)b * LQ + brow + wid * 32 + mi * 16 + fs * 4 + reg;
#pragma unroll
            for (int ni = 0; ni < 4; ++ni) {
                int col = bcol + ni * 16 + fr;
                logits[row * SMAX + col] = acc[mi][ni][reg];
            }
        }
    }
}

// ---------------------------------------------------------------------------
// Wave-per-row top-8 + softmax + gather of PRE-PROJECTED ZW rows + out_b,
// writing final output fp32 directly (out-GEMM eliminated by linearity).
__global__ __launch_bounds__(256) void k_topk_out(
    const float* __restrict__ logits, const unsigned short* __restrict__ ZW,
    const float* __restrict__ out_b, const int* __restrict__ qp,
    float* __restrict__ out)
{
    const int ln  = threadIdx.x & 63;
    const int row = blockIdx.x * 4 + (threadIdx.x >> 6);   // (b*L + l)
    const int b   = row >> 11;                              // L = 2048
    const int start = qp[b], len = qp[b + 1] - start;

    const float* lrow = logits + (size_t)row * SMAX;

    float v[16];
#pragma unroll
    for (int c = 0; c < 4; ++c) {
        float4 q = reinterpret_cast<const float4*>(lrow)[c * 64 + ln];
        int s0 = c * 256 + ln * 4;
        v[c * 4 + 0] = (s0 + 0 < len) ? q.x : -INFINITY;
        v[c * 4 + 1] = (s0 + 1 < len) ? q.y : -INFINITY;
        v[c * 4 + 2] = (s0 + 2 < len) ? q.z : -INFINITY;
        v[c * 4 + 3] = (s0 + 3 < len) ? q.w : -INFINITY;
    }

    float wv[TOPK]; int wi[TOPK];
#pragma unroll
    for (int it = 0; it < TOPK; ++it) {
        float bvv = v[0]; int bj = 0;
#pragma unroll
        for (int j = 1; j < 16; ++j)
            if (v[j] > bvv) { bvv = v[j]; bj = j; }
        int gidx = (bj >> 2) * 256 + ln * 4 + (bj & 3);
        float cv = bvv; int ci = gidx;
#pragma unroll
        for (int off = 32; off > 0; off >>= 1) {
            float ov = __shfl_xor(cv, off);
            int   oi = __shfl_xor(ci, off);
            if (ov > cv || (ov == cv && oi < ci)) { cv = ov; ci = oi; }
        }
        wv[it] = cv; wi[it] = ci;
#pragma unroll
        for (int j = 0; j < 16; ++j) {
            int sj = (j >> 2) * 256 + ln * 4 + (j & 3);
            if (sj == ci) v[j] = -INFINITY;
        }
    }

    float m = wv[0], denom = 0.f;
    float g[TOPK];
#pragma unroll
    for (int k = 0; k < TOPK; ++k) { g[k] = expf(wv[k] - m); denom += g[k]; }
    float inv = 1.f / denom;

    float4 acc[4];
#pragma unroll
    for (int c = 0; c < 4; ++c)
        acc[c] = reinterpret_cast<const float4*>(out_b)[c * 64 + ln];

#pragma unroll
    for (int k = 0; k < TOPK; ++k) {
        int si = wi[k] >= 0 ? wi[k] : 0;
        const ushort4v* zr = reinterpret_cast<const ushort4v*>(
            ZW + (size_t)(start + si) * D_DIM);
        float wgt = g[k] * inv;
#pragma unroll
        for (int c = 0; c < 4; ++c) {
            ushort4v z = zr[c * 64 + ln];
            acc[c].x = fmaf(wgt, bf2f(z[0]), acc[c].x);
            acc[c].y = fmaf(wgt, bf2f(z[1]), acc[c].y);
            acc[c].z = fmaf(wgt, bf2f(z[2]), acc[c].z);
            acc[c].w = fmaf(wgt, bf2f(z[3]), acc[c].w);
        }
    }
    float* orow = out + (size_t)row * D_DIM;
#pragma unroll
    for (int c = 0; c < 4; ++c)
        reinterpret_cast<float4*>(orow)[c * 64 + ln] = acc[c];
}

// ---------------------------------------------------------------------------
extern "C" void kernel_launch(void* const* d_in, const int* in_sizes, int n_in,
                              void* d_out, int out_size, void* d_ws, size_t ws_size,
                              hipStream_t stream) {
    const float* token_states = (const float*)d_in[0];
    const float* Z_sets       = (const float*)d_in[1];
    const float* desc_q       = (const float*)d_in[2];
    const int*   q_raw        = (const int*)d_in[3];
    const float* Wg_w  = (const float*)d_in[4];
    const float* Wg_b  = (const float*)d_in[5];
    const float* Wd_w  = (const float*)d_in[6];
    const float* Wd_b  = (const float*)d_in[7];
    const float* out_w = (const float*)d_in[8];
    const float* out_b = (const float*)d_in[9];
    float* out = (float*)d_out;

    const size_t NTOK = (size_t)BQ * LQ * D_DIM;   // 8388608
    const size_t NDES = (size_t)NQ * D_DIM;        // 2097152
    const size_t NW   = (size_t)D_DIM * D_DIM;     // 1048576

    char* ws = (char*)d_ws;
    int* qp = (int*)ws;
    unsigned short* tokenH  = (unsigned short*)(ws + 256);   // fp16
    unsigned short* tokenL  = tokenH + NTOK;                 // fp16
    unsigned short* descH   = tokenL + NTOK;                 // fp16
    unsigned short* descL   = descH + NDES;                  // fp16
    unsigned short* wgh     = descL + NDES;                  // fp16 single
    unsigned short* wdh     = wgh + NW;                      // fp16 single
    unsigned short* owb     = wdh + NW;                      // bf16
    unsigned short* Zb      = owb + NW;                      // bf16
    unsigned short* Tproj16 = Zb + NDES;                     // fp16 [8192][1024]
    unsigned short* Dproj16 = Tproj16 + NTOK;                // fp16 [2048][1024]
    unsigned short* ZWb     = Dproj16 + NDES;                // bf16 [2048][1024]
    float* logit = (float*)tokenH;  // 33.5 MB over tokenH+tokenL (dead after Tproj)

    // all conversions + qptrs in one launch: grid 7680
    k_cvt_all<<<7680, 256, 0, stream>>>(
        token_states, desc_q, Wg_w, Wd_w, out_w, Z_sets, q_raw,
        tokenH, tokenL, descH, descL, wgh, wdh, owb, Zb, qp);

    // Tproj = token @ Wg^T + b (2-pass fp16-split, fp16 out): grid (8,64)
    k_gemm_2p<<<dim3(8, 64), 256, 0, stream>>>(
        tokenH, tokenL, wgh, Wg_b, Tproj16, BQ * LQ, D_DIM, D_DIM);

    // Dproj (2-pass fp16-split, fp16 out) + ZW (plain bf16) merged: 256 blocks
    k_dzw<<<256, 256, 0, stream>>>(
        descH, descL, wdh, Wd_b, Dproj16, Zb, owb, ZWb);

    // logits (single-pass fp16 MFMA, fp32 out): grid (16,16,4)
    k_logits_fp16<<<dim3(SMAX / 64, LQ / 128, BQ), 256, 0, stream>>>(
        Tproj16, Dproj16, qp, logit);

    // top-8 + softmax + ZW gather + bias -> final output
    k_topk_out<<<(BQ * LQ) / 4, 256, 0, stream>>>(logit, ZWb, out_b, qp, out);
}

// Round 15
// 133.041 us; speedup vs baseline: 1.9147x; 1.0459x over previous
//
#include <hip/hip_runtime.h>
#include <hip/hip_bf16.h>
#include <math.h>

#define BQ    4
#define LQ    2048
#define D_DIM 1024
#define NQ    2048
#define SMAX  1024
#define TOPK  8

typedef __attribute__((ext_vector_type(8))) short          short8;
typedef __attribute__((ext_vector_type(8))) _Float16       half8;
typedef __attribute__((ext_vector_type(4))) float          f32x4;
typedef __attribute__((ext_vector_type(8))) unsigned short ushort8;
typedef __attribute__((ext_vector_type(4))) unsigned short ushort4v;

typedef __attribute__((address_space(3))) void as3_void;
typedef __attribute__((address_space(1))) void as1_void;

__device__ __forceinline__ void gload_lds16(const void* g, void* l) {
    __builtin_amdgcn_global_load_lds((const as1_void*)g, (as3_void*)l, 16, 0, 0);
}

__device__ __forceinline__ unsigned short f2bf(float f) {
    __hip_bfloat16 h = __float2bfloat16(f);
    return *reinterpret_cast<unsigned short*>(&h);
}
__device__ __forceinline__ float bf2f(unsigned short u) {
    unsigned int w = (unsigned int)u << 16;
    return *reinterpret_cast<float*>(&w);
}
__device__ __forceinline__ unsigned short f2h(float f) {
    _Float16 h = (_Float16)f;
    return *reinterpret_cast<unsigned short*>(&h);
}
__device__ __forceinline__ float h2f(unsigned short u) {
    _Float16 h = *reinterpret_cast<_Float16*>(&u);
    return (float)h;
}

// slot-XOR swizzle: conflict-free within each 8-consecutive-lane b128 group.
__device__ __forceinline__ int swz(int r) { return (r ^ (r >> 2)) & 3; }

#define WAIT_VM0   asm volatile("s_waitcnt vmcnt(0)" ::: "memory")
#define WAIT_VM3   asm volatile("s_waitcnt vmcnt(3)" ::: "memory")
#define WAIT_VM4   asm volatile("s_waitcnt vmcnt(4)" ::: "memory")
#define WAIT_VM6   asm volatile("s_waitcnt vmcnt(6)" ::: "memory")
#define WAIT_LGKM0 asm volatile("s_waitcnt lgkmcnt(0)" ::: "memory")

// ---------------------------------------------------------------------------
// One launch: all conversions + qptrs. Regions (2048 elems/block):
// [0,4096)    token -> fp16 hi/lo split   (A must stay split: round-14 lesson)
// [4096,5120) desc  -> fp16 hi/lo split
// [5120,5632) Wg    -> fp16 single        (W single fp16 validated round 13)
// [5632,6144) Wd    -> fp16 single
// [6144,6656) out_w -> bf16               [6656,7680) Z -> bf16
__global__ __launch_bounds__(256) void k_cvt_all(
    const float* __restrict__ token_states, const float* __restrict__ desc_q,
    const float* __restrict__ Wg_w, const float* __restrict__ Wd_w,
    const float* __restrict__ out_w, const float* __restrict__ Z_sets,
    const int* __restrict__ q_raw,
    unsigned short* __restrict__ tokenH, unsigned short* __restrict__ tokenL,
    unsigned short* __restrict__ descH,  unsigned short* __restrict__ descL,
    unsigned short* __restrict__ wgh,    unsigned short* __restrict__ wdh,
    unsigned short* __restrict__ owb,    unsigned short* __restrict__ Zb,
    int* __restrict__ qp)
{
    const int blk = blockIdx.x;
    if (blk == 0 && threadIdx.x == 0) {
        bool is64 = (q_raw[1] == 0);
        for (int i = 0; i <= BQ; ++i)
            qp[i] = is64 ? q_raw[2 * i] : q_raw[i];
    }

    const float* in; unsigned short *hi, *lo = nullptr; int local; bool fp16m = true;
    if (blk < 4096)      { in = token_states; hi = tokenH; lo = tokenL; local = blk; }
    else if (blk < 5120) { in = desc_q; hi = descH; lo = descL; local = blk - 4096; }
    else if (blk < 5632) { in = Wg_w;   hi = wgh;   local = blk - 5120; }
    else if (blk < 6144) { in = Wd_w;   hi = wdh;   local = blk - 5632; }
    else if (blk < 6656) { in = out_w;  hi = owb;   local = blk - 6144; fp16m = false; }
    else                 { in = Z_sets; hi = Zb;    local = blk - 6656; fp16m = false; }

    int i = (local * 256 + threadIdx.x) * 8;
    float4 v0 = *reinterpret_cast<const float4*>(in + i);
    float4 v1 = *reinterpret_cast<const float4*>(in + i + 4);
    float x[8] = {v0.x, v0.y, v0.z, v0.w, v1.x, v1.y, v1.z, v1.w};
    ushort8 h8, l8;
#pragma unroll
    for (int k = 0; k < 8; ++k) {
        if (fp16m) {
            unsigned short h = f2h(x[k]);
            h8[k] = h;
            l8[k] = f2h(x[k] - h2f(h));
        } else {
            h8[k] = f2bf(x[k]);
        }
    }
    *reinterpret_cast<ushort8*>(hi + i) = h8;
    if (lo) *reinterpret_cast<ushort8*>(lo + i) = l8;
}

// ---------------------------------------------------------------------------
// FUSED projection launch: 768 blocks, 3/CU co-resident.
//   blocks [0,512)   : Tproj = token @ Wg^T + b   (2-pass fp16-split)
//   blocks [512,768) : even -> Dproj tile (2-pass fp16-split)
//                      odd  -> ZW = Z @ out_w^T tile (plain bf16)
// All three GEMMs are independent; co-residency fills Tproj's idle issue
// slots with dzw work instead of running dzw on a half-idle machine after.
// LDS: 2 x 24 KB double buffer (ZW path uses 16 KB of each).
__global__ __launch_bounds__(256) void k_proj_dzw(
    const unsigned short* __restrict__ tokenH, const unsigned short* __restrict__ tokenL,
    const unsigned short* __restrict__ wgh, const float* __restrict__ Wg_b,
    unsigned short* __restrict__ Tproj16,
    const unsigned short* __restrict__ descH, const unsigned short* __restrict__ descL,
    const unsigned short* __restrict__ wdh, const float* __restrict__ Wd_b,
    unsigned short* __restrict__ Dproj16,
    const unsigned short* __restrict__ Zb, const unsigned short* __restrict__ owb,
    unsigned short* __restrict__ ZWb)
{
    constexpr int K = D_DIM, N = D_DIM;
    __shared__ __align__(16) char lds[2 * 24576];

    const int tid = threadIdx.x;
    const int ln  = tid & 63;
    const int wid = tid >> 6;
    const int wm  = wid >> 1, wn = wid & 1;
    const int fr  = ln & 15, fs = ln >> 4;
    const int srow = tid >> 2;
    const int sslt = tid & 3;
    const int kk0 = (sslt ^ swz(srow)) << 3;

    const int d0 = blockIdx.x;

    // work selection (block-uniform)
    const unsigned short *Ah, *Al, *Wp;
    const float* bias;
    unsigned short* C;
    int brow, bcol;
    bool split2p;
    if (d0 < 512) {
        // Tproj, XCD-chunked swizzle over its 512-block sub-grid
        const int logical = (d0 & 7) * 64 + (d0 >> 3);
        bcol = (logical & 7) * 128;
        brow = (logical >> 3) * 128;
        Ah = tokenH; Al = tokenL; Wp = wgh; bias = Wg_b; C = Tproj16;
        split2p = true;
    } else {
        const int d = d0 - 512;
        const int sub = d >> 1;
        bcol = (sub & 7) * 128;
        brow = (sub >> 3) * 128;
        if ((d & 1) == 0) {
            Ah = descH; Al = descL; Wp = wdh; bias = Wd_b; C = Dproj16;
            split2p = true;
        } else {
            split2p = false;
        }
    }

    if (split2p) {
        // ---- 2-pass fp16-split GEMM: C = (Ah+Al) @ Wp^T + bias, fp16 out ----
        const size_t offA0 = (size_t)(brow + srow) * K + kk0;
        const size_t offW0 = (size_t)(bcol + srow) * K + kk0;

        auto stage = [&](char* base, int k0) {
            gload_lds16(Ah + offA0 + k0,          base + wid * 1024);
            gload_lds16(Ah + offA0 + 64 * K + k0, base + 4096 + wid * 1024);
            gload_lds16(Al + offA0 + k0,          base + 8192 + wid * 1024);
            gload_lds16(Al + offA0 + 64 * K + k0, base + 12288 + wid * 1024);
            gload_lds16(Wp + offW0 + k0,          base + 16384 + wid * 1024);
            gload_lds16(Wp + offW0 + 64 * K + k0, base + 20480 + wid * 1024);
        };

        f32x4 acc[4][4] = {};
        stage(lds, 0);
        stage(lds + 24576, 32);

        const int NT = K / 32;
        for (int t = 0; t < NT; ++t) {
            if (t < NT - 1) { WAIT_VM6; } else { WAIT_VM0; }
            __builtin_amdgcn_s_barrier();

            char* base = lds + (t & 1) * 24576;
            half8 ahf[4], alf[4], bhf[4];
#pragma unroll
            for (int mi = 0; mi < 4; ++mi) {
                int r = wm * 64 + mi * 16 + fr;
                int o = r * 64 + ((fs ^ swz(r)) << 4);
                ahf[mi] = *reinterpret_cast<const half8*>(base + o);
                alf[mi] = *reinterpret_cast<const half8*>(base + 8192 + o);
            }
#pragma unroll
            for (int ni = 0; ni < 4; ++ni) {
                int c = wn * 64 + ni * 16 + fr;
                int o = c * 64 + ((fs ^ swz(c)) << 4);
                bhf[ni] = *reinterpret_cast<const half8*>(base + 16384 + o);
            }
            __builtin_amdgcn_s_setprio(1);
#pragma unroll
            for (int mi = 0; mi < 4; ++mi)
#pragma unroll
                for (int ni = 0; ni < 4; ++ni)
                    acc[mi][ni] = __builtin_amdgcn_mfma_f32_16x16x32_f16(
                        ahf[mi], bhf[ni], acc[mi][ni], 0, 0, 0);
#pragma unroll
            for (int mi = 0; mi < 4; ++mi)
#pragma unroll
                for (int ni = 0; ni < 4; ++ni)
                    acc[mi][ni] = __builtin_amdgcn_mfma_f32_16x16x32_f16(
                        alf[mi], bhf[ni], acc[mi][ni], 0, 0, 0);
            __builtin_amdgcn_s_setprio(0);

            WAIT_LGKM0;
            __builtin_amdgcn_s_barrier();
            if (t + 2 < NT) stage(base, (t + 2) * 32);
        }

        float bv[4];
#pragma unroll
        for (int ni = 0; ni < 4; ++ni)
            bv[ni] = bias[bcol + wn * 64 + ni * 16 + fr];

#pragma unroll
        for (int mi = 0; mi < 4; ++mi) {
#pragma unroll
            for (int reg = 0; reg < 4; ++reg) {
                int row = brow + wm * 64 + mi * 16 + fs * 4 + reg;
#pragma unroll
                for (int ni = 0; ni < 4; ++ni) {
                    int col = bcol + wn * 64 + ni * 16 + fr;
                    C[(size_t)row * N + col] = f2h(acc[mi][ni][reg] + bv[ni]);
                }
            }
        }
    } else {
        // ---- ZW = Z @ out_w^T (plain bf16, bf16 out) ----
        const size_t offA0 = (size_t)(brow + srow) * K + kk0;
        const size_t offW0 = (size_t)(bcol + srow) * K + kk0;

        auto stage = [&](char* base, int k0) {
            gload_lds16(Zb + offA0 + k0,           base + wid * 1024);
            gload_lds16(Zb + offA0 + 64 * K + k0,  base + 4096 + wid * 1024);
            gload_lds16(owb + offW0 + k0,          base + 8192 + wid * 1024);
            gload_lds16(owb + offW0 + 64 * K + k0, base + 12288 + wid * 1024);
        };

        f32x4 acc[4][4] = {};
        stage(lds, 0);
        stage(lds + 24576, 32);

        const int NT = K / 32;
        for (int t = 0; t < NT; ++t) {
            if (t < NT - 1) { WAIT_VM4; } else { WAIT_VM0; }
            __builtin_amdgcn_s_barrier();

            char* base = lds + (t & 1) * 24576;
            short8 a[4], b[4];
#pragma unroll
            for (int mi = 0; mi < 4; ++mi) {
                int r = wm * 64 + mi * 16 + fr;
                a[mi] = *reinterpret_cast<const short8*>(base + r * 64 + ((fs ^ swz(r)) << 4));
            }
#pragma unroll
            for (int ni = 0; ni < 4; ++ni) {
                int c = wn * 64 + ni * 16 + fr;
                b[ni] = *reinterpret_cast<const short8*>(base + 8192 + c * 64 + ((fs ^ swz(c)) << 4));
            }
            __builtin_amdgcn_s_setprio(1);
#pragma unroll
            for (int mi = 0; mi < 4; ++mi)
#pragma unroll
                for (int ni = 0; ni < 4; ++ni)
                    acc[mi][ni] = __builtin_amdgcn_mfma_f32_16x16x32_bf16(
                        a[mi], b[ni], acc[mi][ni], 0, 0, 0);
            __builtin_amdgcn_s_setprio(0);

            WAIT_LGKM0;
            __builtin_amdgcn_s_barrier();
            if (t + 2 < NT) stage(base, (t + 2) * 32);
        }

#pragma unroll
        for (int mi = 0; mi < 4; ++mi) {
#pragma unroll
            for (int reg = 0; reg < 4; ++reg) {
                int row = brow + wm * 64 + mi * 16 + fs * 4 + reg;
#pragma unroll
                for (int ni = 0; ni < 4; ++ni) {
                    int col = bcol + wn * 64 + ni * 16 + fr;
                    ZWb[(size_t)row * N + col] = f2bf(acc[mi][ni][reg]);
                }
            }
        }
    }
}

// ---------------------------------------------------------------------------
// Windowed logits: SINGLE-PASS fp16 MFMA on fp16 Tproj/Dproj, FP32 output.
// BM=128 x BN=64, counted-vmcnt (L=3), setprio. grid (16,16,4).
__global__ __launch_bounds__(256) void k_logits_fp16(
    const unsigned short* __restrict__ T16, const unsigned short* __restrict__ D16,
    const int* __restrict__ qp, float* __restrict__ logits)
{
    const int d = blockIdx.x + 16 * (blockIdx.y + 16 * blockIdx.z);
    const int logical = (d & 7) * 128 + (d >> 3);
    const int b    = logical >> 8;
    const int brow = ((logical >> 4) & 15) * 128;
    const int bcol = (logical & 15) * 64;

    const int start = qp[b], len = qp[b + 1] - start;
    if (bcol >= len) return;            // block-uniform: barrier-safe

    __shared__ __align__(16) char lds[2 * 12288];

    const int tid = threadIdx.x;
    const int ln  = tid & 63;
    const int wid = tid >> 6;
    const int fr  = ln & 15, fs = ln >> 4;
    const int srow = tid >> 2;
    const int sslt = tid & 3;

    const int kka = (sslt ^ swz(srow)) << 3;
    const size_t offA0 = ((size_t)b * LQ + brow + srow) * D_DIM + kka;
    int wr = start + bcol + srow; if (wr > NQ - 1) wr = NQ - 1;
    const size_t offW0 = (size_t)wr * D_DIM + kka;

    auto stage = [&](char* base, int k0) {
        gload_lds16(T16 + offA0 + k0,              base + wid * 1024);
        gload_lds16(T16 + offA0 + 64 * D_DIM + k0, base + 4096 + wid * 1024);
        gload_lds16(D16 + offW0 + k0,              base + 8192 + wid * 1024);
    };

    f32x4 acc[2][4] = {};

    stage(lds, 0);
    stage(lds + 12288, 32);

    const int NT = D_DIM / 32;
    for (int t = 0; t < NT; ++t) {
        if (t < NT - 1) { WAIT_VM3; } else { WAIT_VM0; }
        __builtin_amdgcn_s_barrier();

        char* base = lds + (t & 1) * 12288;
        half8 a[2], bf[4];
#pragma unroll
        for (int mi = 0; mi < 2; ++mi) {
            int r = wid * 32 + mi * 16 + fr;
            a[mi] = *reinterpret_cast<const half8*>(base + r * 64 + ((fs ^ swz(r)) << 4));
        }
#pragma unroll
        for (int ni = 0; ni < 4; ++ni) {
            int c = ni * 16 + fr;
            bf[ni] = *reinterpret_cast<const half8*>(base + 8192 + c * 64 + ((fs ^ swz(c)) << 4));
        }
        __builtin_amdgcn_s_setprio(1);
#pragma unroll
        for (int mi = 0; mi < 2; ++mi)
#pragma unroll
            for (int ni = 0; ni < 4; ++ni)
                acc[mi][ni] = __builtin_amdgcn_mfma_f32_16x16x32_f16(
                    a[mi], bf[ni], acc[mi][ni], 0, 0, 0);
        __builtin_amdgcn_s_setprio(0);

        WAIT_LGKM0;
        __builtin_amdgcn_s_barrier();
        if (t + 2 < NT) stage(base, (t + 2) * 32);
    }

#pragma unroll
    for (int mi = 0; mi < 2; ++mi) {
#pragma unroll
        for (int reg = 0; reg < 4; ++reg) {
            size_t row = (size_t)b * LQ + brow + wid * 32 + mi * 16 + fs * 4 + reg;
#pragma unroll
            for (int ni = 0; ni < 4; ++ni) {
                int col = bcol + ni * 16 + fr;
                logits[row * SMAX + col] = acc[mi][ni][reg];
            }
        }
    }
}

// ---------------------------------------------------------------------------
// Wave-per-row top-8 + softmax + gather of PRE-PROJECTED ZW rows + out_b,
// writing final output fp32 directly (out-GEMM eliminated by linearity).
__global__ __launch_bounds__(256) void k_topk_out(
    const float* __restrict__ logits, const unsigned short* __restrict__ ZW,
    const float* __restrict__ out_b, const int* __restrict__ qp,
    float* __restrict__ out)
{
    const int ln  = threadIdx.x & 63;
    const int row = blockIdx.x * 4 + (threadIdx.x >> 6);   // (b*L + l)
    const int b   = row >> 11;                              // L = 2048
    const int start = qp[b], len = qp[b + 1] - start;

    const float* lrow = logits + (size_t)row * SMAX;

    float v[16];
#pragma unroll
    for (int c = 0; c < 4; ++c) {
        float4 q = reinterpret_cast<const float4*>(lrow)[c * 64 + ln];
        int s0 = c * 256 + ln * 4;
        v[c * 4 + 0] = (s0 + 0 < len) ? q.x : -INFINITY;
        v[c * 4 + 1] = (s0 + 1 < len) ? q.y : -INFINITY;
        v[c * 4 + 2] = (s0 + 2 < len) ? q.z : -INFINITY;
        v[c * 4 + 3] = (s0 + 3 < len) ? q.w : -INFINITY;
    }

    float wv[TOPK]; int wi[TOPK];
#pragma unroll
    for (int it = 0; it < TOPK; ++it) {
        float bvv = v[0]; int bj = 0;
#pragma unroll
        for (int j = 1; j < 16; ++j)
            if (v[j] > bvv) { bvv = v[j]; bj = j; }
        int gidx = (bj >> 2) * 256 + ln * 4 + (bj & 3);
        float cv = bvv; int ci = gidx;
#pragma unroll
        for (int off = 32; off > 0; off >>= 1) {
            float ov = __shfl_xor(cv, off);
            int   oi = __shfl_xor(ci, off);
            if (ov > cv || (ov == cv && oi < ci)) { cv = ov; ci = oi; }
        }
        wv[it] = cv; wi[it] = ci;
#pragma unroll
        for (int j = 0; j < 16; ++j) {
            int sj = (j >> 2) * 256 + ln * 4 + (j & 3);
            if (sj == ci) v[j] = -INFINITY;
        }
    }

    float m = wv[0], denom = 0.f;
    float g[TOPK];
#pragma unroll
    for (int k = 0; k < TOPK; ++k) { g[k] = expf(wv[k] - m); denom += g[k]; }
    float inv = 1.f / denom;

    float4 acc[4];
#pragma unroll
    for (int c = 0; c < 4; ++c)
        acc[c] = reinterpret_cast<const float4*>(out_b)[c * 64 + ln];

#pragma unroll
    for (int k = 0; k < TOPK; ++k) {
        int si = wi[k] >= 0 ? wi[k] : 0;
        const ushort4v* zr = reinterpret_cast<const ushort4v*>(
            ZW + (size_t)(start + si) * D_DIM);
        float wgt = g[k] * inv;
#pragma unroll
        for (int c = 0; c < 4; ++c) {
            ushort4v z = zr[c * 64 + ln];
            acc[c].x = fmaf(wgt, bf2f(z[0]), acc[c].x);
            acc[c].y = fmaf(wgt, bf2f(z[1]), acc[c].y);
            acc[c].z = fmaf(wgt, bf2f(z[2]), acc[c].z);
            acc[c].w = fmaf(wgt, bf2f(z[3]), acc[c].w);
        }
    }
    float* orow = out + (size_t)row * D_DIM;
#pragma unroll
    for (int c = 0; c < 4; ++c)
        reinterpret_cast<float4*>(orow)[c * 64 + ln] = acc[c];
}

// ---------------------------------------------------------------------------
extern "C" void kernel_launch(void* const* d_in, const int* in_sizes, int n_in,
                              void* d_out, int out_size, void* d_ws, size_t ws_size,
                              hipStream_t stream) {
    const float* token_states = (const float*)d_in[0];
    const float* Z_sets       = (const float*)d_in[1];
    const float* desc_q       = (const float*)d_in[2];
    const int*   q_raw        = (const int*)d_in[3];
    const float* Wg_w  = (const float*)d_in[4];
    const float* Wg_b  = (const float*)d_in[5];
    const float* Wd_w  = (const float*)d_in[6];
    const float* Wd_b  = (const float*)d_in[7];
    const float* out_w = (const float*)d_in[8];
    const float* out_b = (const float*)d_in[9];
    float* out = (float*)d_out;

    const size_t NTOK = (size_t)BQ * LQ * D_DIM;   // 8388608
    const size_t NDES = (size_t)NQ * D_DIM;        // 2097152
    const size_t NW   = (size_t)D_DIM * D_DIM;     // 1048576

    char* ws = (char*)d_ws;
    int* qp = (int*)ws;
    unsigned short* tokenH  = (unsigned short*)(ws + 256);   // fp16
    unsigned short* tokenL  = tokenH + NTOK;                 // fp16
    unsigned short* descH   = tokenL + NTOK;                 // fp16
    unsigned short* descL   = descH + NDES;                  // fp16
    unsigned short* wgh     = descL + NDES;                  // fp16 single
    unsigned short* wdh     = wgh + NW;                      // fp16 single
    unsigned short* owb     = wdh + NW;                      // bf16
    unsigned short* Zb      = owb + NW;                      // bf16
    unsigned short* Tproj16 = Zb + NDES;                     // fp16 [8192][1024]
    unsigned short* Dproj16 = Tproj16 + NTOK;                // fp16 [2048][1024]
    unsigned short* ZWb     = Dproj16 + NDES;                // bf16 [2048][1024]
    float* logit = (float*)tokenH;  // 33.5 MB over tokenH+tokenL (dead after proj)

    // all conversions + qptrs in one launch: grid 7680
    k_cvt_all<<<7680, 256, 0, stream>>>(
        token_states, desc_q, Wg_w, Wd_w, out_w, Z_sets, q_raw,
        tokenH, tokenL, descH, descL, wgh, wdh, owb, Zb, qp);

    // FUSED Tproj + Dproj + ZW: 768 blocks = 3/CU co-resident
    k_proj_dzw<<<768, 256, 0, stream>>>(
        tokenH, tokenL, wgh, Wg_b, Tproj16,
        descH, descL, wdh, Wd_b, Dproj16,
        Zb, owb, ZWb);

    // logits (single-pass fp16 MFMA, fp32 out): grid (16,16,4)
    k_logits_fp16<<<dim3(SMAX / 64, LQ / 128, BQ), 256, 0, stream>>>(
        Tproj16, Dproj16, qp, logit);

    // top-8 + softmax + ZW gather + bias -> final output
    k_topk_out<<<(BQ * LQ) / 4, 256, 0, stream>>>(logit, ZWb, out_b, qp, out);
}